// Round 1
// 2464.589 us; speedup vs baseline: 2.1620x; 2.1620x over previous
//
#include <hip/hip_runtime.h>
#include <hip/hip_bf16.h>
#include <math.h>

typedef __hip_bfloat16 bf16;
typedef __attribute__((ext_vector_type(8))) short bf16x8v;
typedef __attribute__((ext_vector_type(4))) float f32x4v;

static constexpr int NB = 8, TT = 10, HH = 16, WW = 16, CC = 512;
static constexpr int NHEAD = 8, HIDN = 2048;
static constexpr int MTOK = NB * TT * HH * WW;          // 20480 tokens
static constexpr size_t MC = (size_t)MTOK * CC;         // 10485760
static constexpr float LNEPS = 1e-5f;
static constexpr float ATTSCALE = 0.125f;               // 1/sqrt(64)

static __device__ __forceinline__ float gelu_f(float x) {
    return 0.5f * x * (1.0f + erff(x * 0.70710678118654752f));
}

// ---------------- ws-too-small diagnostic ----------------
__global__ __launch_bounds__(256) void k_fill(float* __restrict__ out, float v, size_t n)
{
    size_t i = (size_t)blockIdx.x * 256 + threadIdx.x;
    if (i < n) out[i] = v;
}

// ---------------- fused LayerNorm (+permute, +pos); X fp32, dst bf16 ----------------
__global__ __launch_bounds__(64) void k_ln2(const float* __restrict__ X, bf16* __restrict__ dstA,
                                            bf16* __restrict__ dstB,
                                            const float* __restrict__ g, const float* __restrict__ b,
                                            const float* __restrict__ pos, int posoff, int mode)
{
    int m = blockIdx.x;
    int lane = threadIdx.x;
    const float* row = X + (size_t)m * CC;
    float v[8], s = 0.f, s2 = 0.f;
#pragma unroll
    for (int i = 0; i < 8; ++i) { v[i] = row[lane + i * 64]; s += v[i]; s2 += v[i] * v[i]; }
#pragma unroll
    for (int msk = 1; msk < 64; msk <<= 1) { s += __shfl_xor(s, msk); s2 += __shfl_xor(s2, msk); }
    float mean = s * (1.f / 512.f);
    float var  = fmaxf(s2 * (1.f / 512.f) - mean * mean, 0.f);
    float rr = rsqrtf(var + LNEPS);

    int r, pr = 0;
    if (mode == 0) { r = m; }
    else if (mode == 1) {
        int nt = m >> 8, hw = m & 255, h = hw >> 4, w = hw & 15;
        int l = (h & 7) * 8 + (w & 7);
        r = l * 320 + nt * 4 + (h >> 3) * 2 + (w >> 3);
        pr = l;
    } else if (mode == 3) {
        int n = m / 2560, rem = m - n * 2560;
        int t = rem >> 8;
        r = t * 2048 + n * 256 + (rem & 255);
        pr = t;
    } else {
        int n = m / 2560, rem = m - n * 2560;
        int t = rem >> 8, hw = rem & 255, h = hw >> 4, w = hw & 15;
        int ij = (h & 7) * 8 + (w & 7);
        r = (t * 64 + ij) * 32 + n * 4 + (h >> 3) * 2 + (w >> 3);
        pr = t * 64 + ij;
    }
#pragma unroll
    for (int i = 0; i < 8; ++i) {
        int c = lane + i * 64;
        float y = (v[i] - mean) * rr * g[c] + b[c];
        if (dstA) dstA[(size_t)r * CC + c] = __float2bfloat16(y);
        if (dstB) dstB[(size_t)r * CC + c] = __float2bfloat16(y + pos[(size_t)(posoff + pr) * CC + c]);
    }
}

// ---------------- gather-permute of fp32 `memory` into ts layout (+optional pos) ----------------
__global__ __launch_bounds__(256) void k_permmem(const float* __restrict__ in, bf16* __restrict__ out,
                                                 const float* __restrict__ pos, int posoff)
{
    size_t id = (size_t)blockIdx.x * 256 + threadIdx.x;
    if (id >= MC) return;
    int c = (int)(id & 511);
    int r = (int)(id >> 9);
    int b = r & 31, s = r >> 5;
    int t = s >> 6, ij = s & 63;
    int i = ij >> 3, j = ij & 7;
    int n = b >> 2, qh = (b >> 1) & 1, qw = b & 1;
    int m = (n * 10 + t) * 256 + (qh * 8 + i) * 16 + qw * 8 + j;
    float v = in[(size_t)m * CC + c];
    if (pos) v += pos[(size_t)(posoff + t * 64 + ij) * CC + c];
    out[id] = __float2bfloat16(v);
}

// ---------------- reverse permute + residual add into fp32 X ----------------
__global__ __launch_bounds__(256) void k_unperm_add(float* __restrict__ X, const bf16* __restrict__ Tb, int mode)
{
    size_t id = (size_t)blockIdx.x * 256 + threadIdx.x;
    if (id >= MC) return;
    int c = (int)(id & 511);
    int m = (int)(id >> 9);
    int r;
    if (mode == 1) {
        int nt = m >> 8, hw = m & 255;
        int h = hw >> 4, w = hw & 15;
        r = ((h & 7) * 8 + (w & 7)) * 320 + nt * 4 + (h >> 3) * 2 + (w >> 3);
    } else if (mode == 3) {
        int n = m / 2560, rem = m - n * 2560;
        r = (rem >> 8) * 2048 + n * 256 + (rem & 255);
    } else {
        int n = m / 2560, rem = m - n * 2560;
        int t = rem >> 8, hw = rem & 255;
        int h = hw >> 4, w = hw & 15;
        r = (t * 64 + (h & 7) * 8 + (w & 7)) * 32 + n * 4 + (h >> 3) * 2 + (w >> 3);
    }
    X[id] += (float)Tb[(size_t)r * CC + c];
}

__global__ __launch_bounds__(256) void k_add(float* __restrict__ X, const bf16* __restrict__ Y, size_t n)
{
    size_t i = (size_t)blockIdx.x * 256 + threadIdx.x;
    if (i < n) X[i] += (float)Y[i];
}

// ---------------- final residual add: FLOAT32 output ----------------
__global__ __launch_bounds__(256) void k_final(const float* __restrict__ X, const bf16* __restrict__ F,
                                               float* __restrict__ out, size_t n)
{
    size_t i = (size_t)blockIdx.x * 256 + threadIdx.x;
    if (i < n) out[i] = X[i] + (float)F[i];
}

// ---------------- MFMA GEMM: C = A(bf16, M x K) @ W(fp32, Nc x K)^T + bias; out bf16 ----------------
// 128x128 tile, BK=32, 4 waves each computing a 64x64 quadrant via 16 x mfma_f32_16x16x32_bf16.
// EPI 0: bias.  1: bias+BN+GELU.  3: bias+GELU.
template<int EPI>
__global__ __launch_bounds__(256) void k_mgemm(const bf16* __restrict__ A, const float* __restrict__ Wt,
                                               const float* __restrict__ bias, bf16* __restrict__ Cout,
                                               int Nc, int K,
                                               const float* __restrict__ bng, const float* __restrict__ bnb,
                                               const float* __restrict__ bnm, const float* __restrict__ bnv)
{
    __shared__ short As[128][40];   // [m][k], +8 pad
    __shared__ short Bs[128][40];   // [n][k], +8 pad
    int bm = blockIdx.y * 128, bn = blockIdx.x * 128;
    int tid = threadIdx.x;
    int lane = tid & 63, wave = tid >> 6;
    int wm = (wave & 1) * 64, wn = (wave >> 1) * 64;
    int fr = lane & 15;      // frag row (A) / col (B,D)
    int fq = lane >> 4;      // quad: k-offset fq*8 (A,B), row-offset fq*4 (D)

    f32x4v acc[4][4];
#pragma unroll
    for (int i = 0; i < 4; ++i)
#pragma unroll
        for (int j = 0; j < 4; ++j) acc[i][j] = (f32x4v){0.f, 0.f, 0.f, 0.f};

    for (int k0 = 0; k0 < K; k0 += 32) {
#pragma unroll
        for (int i = 0; i < 2; ++i) {
            int v = tid * 2 + i;                 // 0..511
            int m = v >> 2, kk = (v & 3) * 8;
            *(uint4*)&As[m][kk] = *(const uint4*)&A[(size_t)(bm + m) * K + k0 + kk];
            float4 w0 = *(const float4*)&Wt[(size_t)(bn + m) * K + k0 + kk];
            float4 w1 = *(const float4*)&Wt[(size_t)(bn + m) * K + k0 + kk + 4];
            union { bf16 h[8]; uint4 u; } t;
            t.h[0] = __float2bfloat16(w0.x); t.h[1] = __float2bfloat16(w0.y);
            t.h[2] = __float2bfloat16(w0.z); t.h[3] = __float2bfloat16(w0.w);
            t.h[4] = __float2bfloat16(w1.x); t.h[5] = __float2bfloat16(w1.y);
            t.h[6] = __float2bfloat16(w1.z); t.h[7] = __float2bfloat16(w1.w);
            *(uint4*)&Bs[m][kk] = t.u;
        }
        __syncthreads();
        bf16x8v af[4], bfr[4];
#pragma unroll
        for (int mi = 0; mi < 4; ++mi) af[mi]  = *(bf16x8v*)&As[wm + mi * 16 + fr][fq * 8];
#pragma unroll
        for (int ni = 0; ni < 4; ++ni) bfr[ni] = *(bf16x8v*)&Bs[wn + ni * 16 + fr][fq * 8];
#pragma unroll
        for (int mi = 0; mi < 4; ++mi)
#pragma unroll
            for (int ni = 0; ni < 4; ++ni)
                acc[mi][ni] = __builtin_amdgcn_mfma_f32_16x16x32_bf16(af[mi], bfr[ni], acc[mi][ni], 0, 0, 0);
        __syncthreads();
    }

#pragma unroll
    for (int mi = 0; mi < 4; ++mi)
#pragma unroll
        for (int ni = 0; ni < 4; ++ni)
#pragma unroll
            for (int r = 0; r < 4; ++r) {
                int m = bm + wm + mi * 16 + fq * 4 + r;
                int n = bn + wn + ni * 16 + fr;
                float v = acc[mi][ni][r] + bias[n];
                if constexpr (EPI == 1) {
                    v = (v - bnm[n]) * rsqrtf(bnv[n] + LNEPS) * bng[n] + bnb[n];
                    v = gelu_f(v);
                }
                if constexpr (EPI == 3) v = gelu_f(v);
                Cout[(size_t)m * Nc + n] = __float2bfloat16(v);
            }
}

// ---------------- elementwise dwconv3x3 + BN2 + GELU over a 4096-token chunk ----------------
__global__ __launch_bounds__(256) void k_dwc(const bf16* __restrict__ H1c, bf16* __restrict__ H2c,
                                             const float* __restrict__ dww, const float* __restrict__ dwb,
                                             const float* __restrict__ g2, const float* __restrict__ b2,
                                             const float* __restrict__ m2, const float* __restrict__ v2)
{
    size_t id = (size_t)blockIdx.x * 256 + threadIdx.x;
    if (id >= (size_t)4096 * HIDN) return;
    int k = (int)(id & 2047);
    int lm = (int)(id >> 11);
    int p = lm >> 8, hw = lm & 255, h = hw >> 4, w = hw & 15;
    float a = dwb[k];
#pragma unroll
    for (int dh = -1; dh <= 1; ++dh) {
        int h2 = h + dh;
        if (h2 < 0 || h2 > 15) continue;
#pragma unroll
        for (int dw = -1; dw <= 1; ++dw) {
            int w2 = w + dw;
            if (w2 < 0 || w2 > 15) continue;
            a += (float)H1c[(((size_t)p * 16 + h2) * 16 + w2) * HIDN + k]
               * dww[k * 9 + (dh + 1) * 3 + (dw + 1)];
        }
    }
    float xn = (a - m2[k]) * rsqrtf(v2[k] + LNEPS) * g2[k] + b2[k];
    H2c[id] = __float2bfloat16(gelu_f(xn));
}

// ---------------- generic MHA core (scalar; used only for tiny T=10 temporal attn) ----------------
__global__ __launch_bounds__(256) void k_attn(const bf16* __restrict__ Q, const bf16* __restrict__ K,
                                              const bf16* __restrict__ V, bf16* __restrict__ O,
                                              int L, int S, int Bc)
{
    __shared__ float sQ[16][68];
    __shared__ float sK[32][68];
    __shared__ float sV[32][68];
    __shared__ float sS[16][640];
    __shared__ float sRed[16][17];
    int b = blockIdx.x / NHEAD;
    int h = blockIdx.x - b * NHEAD;
    int ql0 = blockIdx.y * 16;
    int tid = threadIdx.x;
    int qi = tid >> 4, g = tid & 15;
    int SCv = (S + 31) & ~31;

    for (int t = tid; t < 16 * 64; t += 256) {
        int r = t >> 6, d = t & 63;
        int l = ql0 + r;
        sQ[r][d] = (l < L) ? (float)Q[((size_t)l * Bc + b) * CC + h * 64 + d] : 0.f;
    }
    __syncthreads();

    for (int s0 = 0; s0 < S; s0 += 32) {
        for (int t = tid; t < 32 * 64; t += 256) {
            int r = t >> 6, d = t & 63;
            int s = s0 + r;
            sK[r][d] = (s < S) ? (float)K[((size_t)s * Bc + b) * CC + h * 64 + d] : 0.f;
        }
        __syncthreads();
#pragma unroll
        for (int half = 0; half < 2; ++half) {
            int si = half * 16 + g;
            int s = s0 + si;
            float acc = 0.f;
#pragma unroll
            for (int d = 0; d < 64; ++d) acc += sQ[qi][d] * sK[si][d];
            sS[qi][s] = (s < S) ? acc * ATTSCALE : -60.f;
        }
        __syncthreads();
    }

    float pm = -60.f;
    for (int s = g; s < SCv; s += 16) pm = fmaxf(pm, sS[qi][s]);
    sRed[qi][g] = pm;
    __syncthreads();
    float mx = sRed[qi][0];
#pragma unroll
    for (int t = 1; t < 16; ++t) mx = fmaxf(mx, sRed[qi][t]);
    __syncthreads();
    float ps = 0.f;
    for (int s = g; s < SCv; s += 16) {
        float e = expf(sS[qi][s] - mx);
        sS[qi][s] = e;
        ps += e;
    }
    sRed[qi][g] = ps;
    __syncthreads();
    float sum = 0.f;
#pragma unroll
    for (int t = 0; t < 16; ++t) sum += sRed[qi][t];
    float inv = 1.f / fmaxf(sum, 1e-20f);

    float o0 = 0.f, o1 = 0.f, o2 = 0.f, o3 = 0.f;
    for (int s0 = 0; s0 < S; s0 += 32) {
        __syncthreads();
        for (int t = tid; t < 32 * 64; t += 256) {
            int r = t >> 6, d = t & 63;
            int s = s0 + r;
            sV[r][d] = (s < S) ? (float)V[((size_t)s * Bc + b) * CC + h * 64 + d] : 0.f;
        }
        __syncthreads();
#pragma unroll
        for (int si = 0; si < 32; ++si) {
            float w = sS[qi][s0 + si];
            o0 += w * sV[si][g * 4 + 0];
            o1 += w * sV[si][g * 4 + 1];
            o2 += w * sV[si][g * 4 + 2];
            o3 += w * sV[si][g * 4 + 3];
        }
    }
    int l = ql0 + qi;
    if (l < L) {
        bf16* op = O + ((size_t)l * Bc + b) * CC + h * 64 + g * 4;
        op[0] = __float2bfloat16(o0 * inv);
        op[1] = __float2bfloat16(o1 * inv);
        op[2] = __float2bfloat16(o2 * inv);
        op[3] = __float2bfloat16(o3 * inv);
    }
}

// ---------------- MFMA flash attention: requires L%64==0, S%64==0, d=64 ----------------
// grid.x = Bc*NHEAD (b*8+h), grid.y = L/64. 256 threads = 4 waves, wave w owns q rows w*16..w*16+15.
// Fragment layout mirrors k_mgemm (proven): A[m=lane&15][k=(lane>>4)*8+j], B'[n=lane&15][k],
// D: col=lane&15, row=(lane>>4)*4+reg.
__global__ __launch_bounds__(256) void k_fattn(const bf16* __restrict__ Q, const bf16* __restrict__ K,
                                               const bf16* __restrict__ V, bf16* __restrict__ O,
                                               int L, int S, int Bc)
{
    __shared__ short sK[64][72];        // [s][d] bf16, stride 72 (144 B: bank stride 4 -> 2-way max)
    __shared__ short sVt[64][72];       // [d][s] bf16 (V transposed during staging)
    __shared__ short sP[4][16][40];     // per-wave P bounce: [wave][q(0..15)][s(0..63)] bf16

    int b = blockIdx.x >> 3;
    int h = blockIdx.x & 7;
    int q0 = blockIdx.y * 64;
    int tid = threadIdx.x;
    int wv = tid >> 6;
    int lane = tid & 63;
    int fr = lane & 15;                 // frag row (A rows / B rows / D col)
    int fq = lane >> 4;                 // frag quad: k-off fq*8; D row-off fq*4

    // --- Q fragments held in registers for the whole block ---
    const bf16* qp = Q + ((size_t)(q0 + wv * 16 + fr) * Bc + b) * CC + h * 64 + fq * 8;
    bf16x8v qf0 = *(const bf16x8v*)qp;          // k = 0..31 chunk (this lane's 8)
    bf16x8v qf1 = *(const bf16x8v*)(qp + 32);   // k = 32..63 chunk

    f32x4v oacc[4];                     // d-subtiles nt2: col d = nt2*16+fr, row q = fq*4+r
#pragma unroll
    for (int i = 0; i < 4; ++i) oacc[i] = (f32x4v){0.f, 0.f, 0.f, 0.f};
    float m_run[4] = {-1e30f, -1e30f, -1e30f, -1e30f};
    float l_run[4] = {0.f, 0.f, 0.f, 0.f};

    // staging index precompute
    int ks = tid >> 2, kd0 = (tid & 3) * 16;        // K: row s=ks, 2x16B at d=kd0,kd0+8
    int vd0 = (tid & 7) * 8, vs2 = (tid >> 3) * 2;  // V: 8 d, s-pair (vs2, vs2+1)

    for (int s0 = 0; s0 < S; s0 += 64) {
        __syncthreads();    // previous tile fully consumed before restaging
        // --- stage K tile [64 s][64 d] ---
        {
            const bf16* kp = K + ((size_t)(s0 + ks) * Bc + b) * CC + h * 64 + kd0;
            *(uint4*)&sK[ks][kd0]     = *(const uint4*)kp;
            *(uint4*)&sK[ks][kd0 + 8] = *(const uint4*)(kp + 8);
        }
        // --- stage V tile transposed -> sVt[d][s] ---
        {
            const bf16* vp0 = V + ((size_t)(s0 + vs2) * Bc + b) * CC + h * 64 + vd0;
            const bf16* vp1 = vp0 + (size_t)Bc * CC;
            uint4 va = *(const uint4*)vp0;
            uint4 vb = *(const uint4*)vp1;
            const ushort* as = (const ushort*)&va;
            const ushort* bs = (const ushort*)&vb;
#pragma unroll
            for (int j = 0; j < 8; ++j)
                *(uint*)&sVt[vd0 + j][vs2] = (uint)as[j] | ((uint)bs[j] << 16);
        }
        __syncthreads();

        // --- QK^T: S-tile fragment sc[nt][r] = S[q=fq*4+r][s=nt*16+fr] ---
        f32x4v sc[4];
#pragma unroll
        for (int nt = 0; nt < 4; ++nt) {
            bf16x8v k0 = *(bf16x8v*)&sK[nt * 16 + fr][fq * 8];
            bf16x8v k1 = *(bf16x8v*)&sK[nt * 16 + fr][32 + fq * 8];
            f32x4v z = (f32x4v){0.f, 0.f, 0.f, 0.f};
            z = __builtin_amdgcn_mfma_f32_16x16x32_bf16(qf0, k0, z, 0, 0, 0);
            z = __builtin_amdgcn_mfma_f32_16x16x32_bf16(qf1, k1, z, 0, 0, 0);
            sc[nt] = z;
        }

        // --- online softmax (per lane: 4 q rows; row spread over 16 lanes sharing fq) ---
        short (*sPw)[40] = sP[wv];
#pragma unroll
        for (int r = 0; r < 4; ++r) {
            float mx = fmaxf(fmaxf(sc[0][r], sc[1][r]), fmaxf(sc[2][r], sc[3][r])) * ATTSCALE;
#pragma unroll
            for (int msk = 1; msk < 16; msk <<= 1) mx = fmaxf(mx, __shfl_xor(mx, msk));
            float mnew = fmaxf(m_run[r], mx);
            float alpha = __expf(m_run[r] - mnew);
            m_run[r] = mnew;
            float rs = 0.f;
#pragma unroll
            for (int nt = 0; nt < 4; ++nt) {
                float p = __expf(sc[nt][r] * ATTSCALE - mnew);
                union { bf16 hh; ushort uu; } cv;
                cv.hh = __float2bfloat16(p);
                rs += __bfloat162float(cv.hh);           // denominator matches bf16 P fed to PV
                sPw[fq * 4 + r][fr + 16 * nt] = (short)cv.uu;
            }
#pragma unroll
            for (int msk = 1; msk < 16; msk <<= 1) rs += __shfl_xor(rs, msk);
            l_run[r] = l_run[r] * alpha + rs;
#pragma unroll
            for (int nt2 = 0; nt2 < 4; ++nt2) oacc[nt2][r] *= alpha;
        }
        __syncthreads();    // publish sP (wave-local, but block barrier is the safe fence)

        // --- PV: A = P[q(0..15)][s], B' = V^T[d][s] -> oacc[q][d] ---
        bf16x8v pa0 = *(bf16x8v*)&sPw[fr][fq * 8];
        bf16x8v pa1 = *(bf16x8v*)&sPw[fr][32 + fq * 8];
#pragma unroll
        for (int nt2 = 0; nt2 < 4; ++nt2) {
            bf16x8v v0 = *(bf16x8v*)&sVt[nt2 * 16 + fr][fq * 8];
            bf16x8v v1 = *(bf16x8v*)&sVt[nt2 * 16 + fr][32 + fq * 8];
            oacc[nt2] = __builtin_amdgcn_mfma_f32_16x16x32_bf16(pa0, v0, oacc[nt2], 0, 0, 0);
            oacc[nt2] = __builtin_amdgcn_mfma_f32_16x16x32_bf16(pa1, v1, oacc[nt2], 0, 0, 0);
        }
    }

    // --- epilogue: O[q][d] = oacc / l ---
#pragma unroll
    for (int r = 0; r < 4; ++r) {
        float inv = 1.f / fmaxf(l_run[r], 1e-20f);
        bf16* op = O + ((size_t)(q0 + wv * 16 + fq * 4 + r) * Bc + b) * CC + h * 64 + fr;
#pragma unroll
        for (int nt2 = 0; nt2 < 4; ++nt2)
            op[nt2 * 16] = __float2bfloat16(oacc[nt2][r] * inv);
    }
}

extern "C" void kernel_launch(void* const* d_in, const int* in_sizes, int n_in,
                              void* d_out, int out_size, void* d_ws, size_t ws_size,
                              hipStream_t stream)
{
    const float* query        = (const float*)d_in[0];
    const float* memory       = (const float*)d_in[1];
    const float* pos_local    = (const float*)d_in[2];
    const float* pos_temporal = (const float*)d_in[3];
    const float* pos_ts       = (const float*)d_in[4];
    const float* ln_g[5] = {(const float*)d_in[5], (const float*)d_in[7], (const float*)d_in[9], (const float*)d_in[11], (const float*)d_in[13]};
    const float* ln_b[5] = {(const float*)d_in[6], (const float*)d_in[8], (const float*)d_in[10], (const float*)d_in[12], (const float*)d_in[14]};
    const float* sa_w_in  = (const float*)d_in[15]; const float* sa_b_in  = (const float*)d_in[16];
    const float* sa_w_out = (const float*)d_in[17]; const float* sa_b_out = (const float*)d_in[18];
    const float* ta_w_in  = (const float*)d_in[19]; const float* ta_b_in  = (const float*)d_in[20];
    const float* ta_w_out = (const float*)d_in[21]; const float* ta_b_out = (const float*)d_in[22];
    const float* ca_w_in  = (const float*)d_in[23]; const float* ca_b_in  = (const float*)d_in[24];
    const float* ca_w_out = (const float*)d_in[25]; const float* ca_b_out = (const float*)d_in[26];
    const float* fc1_w = (const float*)d_in[27]; const float* fc1_b = (const float*)d_in[28];
    const float* dw_w  = (const float*)d_in[29]; const float* dw_b  = (const float*)d_in[30];
    const float* fc2_w = (const float*)d_in[31]; const float* fc2_b = (const float*)d_in[32];
    const float* bn1g = (const float*)d_in[33], *bn1b = (const float*)d_in[34], *bn1m = (const float*)d_in[35], *bn1v = (const float*)d_in[36];
    const float* bn2g = (const float*)d_in[37], *bn2b = (const float*)d_in[38], *bn2m = (const float*)d_in[39], *bn2v = (const float*)d_in[40];
    const float* bn3g = (const float*)d_in[41], *bn3b = (const float*)d_in[42], *bn3m = (const float*)d_in[43], *bn3v = (const float*)d_in[44];
    const float* lin1_w = (const float*)d_in[45]; const float* lin1_b = (const float*)d_in[46];
    const float* lin2_w = (const float*)d_in[47]; const float* lin2_b = (const float*)d_in[48];

    dim3 blk(256);
    int gMC = (int)(MC / 256);

    size_t need = MC * 4 + 4 * MC * 2;
    if (ws_size < need) {
        k_fill<<<gMC, blk, 0, stream>>>((float*)d_out, 700.f, MC);
        return;
    }
    float* X = (float*)d_ws;
    bf16* B0 = (bf16*)((char*)d_ws + MC * 4);
    bf16* B1 = B0 + MC;
    bf16* B2 = B1 + MC;
    bf16* B3 = B2 + MC;
    const float* nulf = nullptr;
    bf16* nulm = nullptr;

    hipMemcpyAsync(X, query, MC * sizeof(float), hipMemcpyDeviceToDevice, stream);

    // ---- stage 1: spatial window MHSA (L=S=64, Bc=320) ----
    k_ln2<<<MTOK, 64, 0, stream>>>(X, B0, B1, ln_g[0], ln_b[0], pos_local, 0, 1);
    k_mgemm<0><<<dim3(4, 160), blk, 0, stream>>>(B1, sa_w_in, sa_b_in, B2, 512, 512, nulf, nulf, nulf, nulf);
    k_mgemm<0><<<dim3(4, 160), blk, 0, stream>>>(B1, sa_w_in + 512 * 512, sa_b_in + 512, B3, 512, 512, nulf, nulf, nulf, nulf);
    k_mgemm<0><<<dim3(4, 160), blk, 0, stream>>>(B0, sa_w_in + 2 * 512 * 512, sa_b_in + 1024, B1, 512, 512, nulf, nulf, nulf, nulf);
    k_fattn<<<dim3(320 * NHEAD, 1), blk, 0, stream>>>(B2, B3, B1, B0, 64, 64, 320);
    k_mgemm<0><<<dim3(4, 160), blk, 0, stream>>>(B0, sa_w_out, sa_b_out, B2, 512, 512, nulf, nulf, nulf, nulf);
    k_unperm_add<<<gMC, blk, 0, stream>>>(X, B2, 1);

    // ---- stage 2: MlpDWBN, chunked over 16-plane slabs ----
    k_ln2<<<MTOK, 64, 0, stream>>>(X, B0, nulm, ln_g[1], ln_b[1], nulf, 0, 0);
    for (int c = 0; c < 5; ++c) {
        int off = c * 4096;
        k_mgemm<1><<<dim3(16, 32), blk, 0, stream>>>(B0 + (size_t)off * CC, fc1_w, fc1_b, B1, 2048, 512,
                                                     bn1g, bn1b, bn1m, bn1v);
        k_dwc<<<32768, blk, 0, stream>>>(B1, B3, dw_w, dw_b, bn2g, bn2b, bn2m, bn2v);
        k_mgemm<1><<<dim3(4, 32), blk, 0, stream>>>(B3, fc2_w, fc2_b, B2 + (size_t)off * CC, 512, 2048,
                                                    bn3g, bn3b, bn3m, bn3v);
    }
    k_add<<<gMC, blk, 0, stream>>>(X, B2, MC);

    // ---- stage 3: temporal MHSA (T=10: scalar path) ----
    k_ln2<<<MTOK, 64, 0, stream>>>(X, B0, B1, ln_g[2], ln_b[2], pos_temporal, 0, 3);
    k_mgemm<0><<<dim3(4, 160), blk, 0, stream>>>(B1, ta_w_in, ta_b_in, B2, 512, 512, nulf, nulf, nulf, nulf);
    k_mgemm<0><<<dim3(4, 160), blk, 0, stream>>>(B1, ta_w_in + 512 * 512, ta_b_in + 512, B3, 512, 512, nulf, nulf, nulf, nulf);
    k_mgemm<0><<<dim3(4, 160), blk, 0, stream>>>(B0, ta_w_in + 2 * 512 * 512, ta_b_in + 1024, B1, 512, 512, nulf, nulf, nulf, nulf);
    k_attn<<<dim3(2048 * NHEAD, 1), blk, 0, stream>>>(B2, B3, B1, B0, 10, 10, 2048);
    k_mgemm<0><<<dim3(4, 160), blk, 0, stream>>>(B0, ta_w_out, ta_b_out, B2, 512, 512, nulf, nulf, nulf, nulf);
    k_unperm_add<<<gMC, blk, 0, stream>>>(X, B2, 3);

    // ---- stage 4: temporal-spatial cross-attention (L=S=640, Bc=32: MFMA flash) ----
    k_ln2<<<MTOK, 64, 0, stream>>>(X, nulm, B1, ln_g[3], ln_b[3], pos_ts, 640, 4);
    k_mgemm<0><<<dim3(4, 160), blk, 0, stream>>>(B1, ca_w_in, ca_b_in, B2, 512, 512, nulf, nulf, nulf, nulf);
    k_permmem<<<gMC, blk, 0, stream>>>(memory, B1, pos_ts, 0);
    k_mgemm<0><<<dim3(4, 160), blk, 0, stream>>>(B1, ca_w_in + 512 * 512, ca_b_in + 512, B3, 512, 512, nulf, nulf, nulf, nulf);
    k_permmem<<<gMC, blk, 0, stream>>>(memory, B1, nulf, 0);
    k_mgemm<0><<<dim3(4, 160), blk, 0, stream>>>(B1, ca_w_in + 2 * 512 * 512, ca_b_in + 1024, B0, 512, 512, nulf, nulf, nulf, nulf);
    k_fattn<<<dim3(32 * NHEAD, 10), blk, 0, stream>>>(B2, B3, B0, B1, 640, 640, 32);
    k_mgemm<0><<<dim3(4, 160), blk, 0, stream>>>(B1, ca_w_out, ca_b_out, B2, 512, 512, nulf, nulf, nulf, nulf);
    k_unperm_add<<<gMC, blk, 0, stream>>>(X, B2, 4);

    // ---- stage 5: final FFN, chunked ----
    k_ln2<<<MTOK, 64, 0, stream>>>(X, B0, nulm, ln_g[4], ln_b[4], nulf, 0, 0);
    for (int c = 0; c < 5; ++c) {
        int off = c * 4096;
        k_mgemm<3><<<dim3(16, 32), blk, 0, stream>>>(B0 + (size_t)off * CC, lin1_w, lin1_b, B1, 2048, 512,
                                                     nulf, nulf, nulf, nulf);
        k_mgemm<0><<<dim3(4, 32), blk, 0, stream>>>(B1, lin2_w, lin2_b, B2 + (size_t)off * CC, 512, 2048,
                                                    nulf, nulf, nulf, nulf);
    }
    k_final<<<gMC, blk, 0, stream>>>(X, B2, (float*)d_out, MC);
}

// Round 2
// 2103.222 us; speedup vs baseline: 2.5335x; 1.1718x over previous
//
#include <hip/hip_runtime.h>
#include <hip/hip_bf16.h>
#include <math.h>

typedef __hip_bfloat16 bf16;
typedef __attribute__((ext_vector_type(8))) short bf16x8v;
typedef __attribute__((ext_vector_type(4))) float f32x4v;

static constexpr int NB = 8, TT = 10, HH = 16, WW = 16, CC = 512;
static constexpr int NHEAD = 8, HIDN = 2048;
static constexpr int MTOK = NB * TT * HH * WW;          // 20480 tokens
static constexpr size_t MC = (size_t)MTOK * CC;         // 10485760
static constexpr float LNEPS = 1e-5f;
static constexpr float ATTSCALE = 0.125f;               // 1/sqrt(64)
static constexpr size_t WTOT = 7340032;                 // total weight elems pre-converted to bf16

static __device__ __forceinline__ float gelu_f(float x) {
    return 0.5f * x * (1.0f + erff(x * 0.70710678118654752f));
}

// ---------------- ws-too-small diagnostic ----------------
__global__ __launch_bounds__(256) void k_fill(float* __restrict__ out, float v, size_t n)
{
    size_t i = (size_t)blockIdx.x * 256 + threadIdx.x;
    if (i < n) out[i] = v;
}

// ---------------- one-shot fp32 -> bf16 weight conversion (28 segments of 262144) ----------------
__global__ __launch_bounds__(256) void k_cvtw(bf16* __restrict__ out,
    const float* __restrict__ p0, const float* __restrict__ p1, const float* __restrict__ p2,
    const float* __restrict__ p3, const float* __restrict__ p4, const float* __restrict__ p5,
    const float* __restrict__ p6, const float* __restrict__ p7, const float* __restrict__ p8,
    const float* __restrict__ p9)
{
    size_t id = (size_t)blockIdx.x * 256 + threadIdx.x;
    if (id >= WTOT) return;
    int sid = (int)(id >> 18);                 // /262144
    const float* base; size_t lo;
    if (sid < 3)       { base = p0; lo = id; }
    else if (sid < 4)  { base = p1; lo = id - (size_t)3  * 262144; }
    else if (sid < 7)  { base = p2; lo = id - (size_t)4  * 262144; }
    else if (sid < 8)  { base = p3; lo = id - (size_t)7  * 262144; }
    else if (sid < 11) { base = p4; lo = id - (size_t)8  * 262144; }
    else if (sid < 12) { base = p5; lo = id - (size_t)11 * 262144; }
    else if (sid < 16) { base = p6; lo = id - (size_t)12 * 262144; }
    else if (sid < 20) { base = p7; lo = id - (size_t)16 * 262144; }
    else if (sid < 24) { base = p8; lo = id - (size_t)20 * 262144; }
    else               { base = p9; lo = id - (size_t)24 * 262144; }
    out[id] = __float2bfloat16(base[lo]);
}

// ---------------- fused LayerNorm (+permute, +pos); X fp32, dst bf16 ----------------
__global__ __launch_bounds__(64) void k_ln2(const float* __restrict__ X, bf16* __restrict__ dstA,
                                            bf16* __restrict__ dstB,
                                            const float* __restrict__ g, const float* __restrict__ b,
                                            const float* __restrict__ pos, int posoff, int mode)
{
    int m = blockIdx.x;
    int lane = threadIdx.x;
    const float* row = X + (size_t)m * CC;
    float v[8], s = 0.f, s2 = 0.f;
#pragma unroll
    for (int i = 0; i < 8; ++i) { v[i] = row[lane + i * 64]; s += v[i]; s2 += v[i] * v[i]; }
#pragma unroll
    for (int msk = 1; msk < 64; msk <<= 1) { s += __shfl_xor(s, msk); s2 += __shfl_xor(s2, msk); }
    float mean = s * (1.f / 512.f);
    float var  = fmaxf(s2 * (1.f / 512.f) - mean * mean, 0.f);
    float rr = rsqrtf(var + LNEPS);

    int r, pr = 0;
    if (mode == 0) { r = m; }
    else if (mode == 1) {
        int nt = m >> 8, hw = m & 255, h = hw >> 4, w = hw & 15;
        int l = (h & 7) * 8 + (w & 7);
        r = l * 320 + nt * 4 + (h >> 3) * 2 + (w >> 3);
        pr = l;
    } else if (mode == 3) {
        int n = m / 2560, rem = m - n * 2560;
        int t = rem >> 8;
        r = t * 2048 + n * 256 + (rem & 255);
        pr = t;
    } else {
        int n = m / 2560, rem = m - n * 2560;
        int t = rem >> 8, hw = rem & 255, h = hw >> 4, w = hw & 15;
        int ij = (h & 7) * 8 + (w & 7);
        r = (t * 64 + ij) * 32 + n * 4 + (h >> 3) * 2 + (w >> 3);
        pr = t * 64 + ij;
    }
#pragma unroll
    for (int i = 0; i < 8; ++i) {
        int c = lane + i * 64;
        float y = (v[i] - mean) * rr * g[c] + b[c];
        if (dstA) dstA[(size_t)r * CC + c] = __float2bfloat16(y);
        if (dstB) dstB[(size_t)r * CC + c] = __float2bfloat16(y + pos[(size_t)(posoff + pr) * CC + c]);
    }
}

// ---------------- gather-permute of fp32 `memory` into ts layout (+optional pos) ----------------
__global__ __launch_bounds__(256) void k_permmem(const float* __restrict__ in, bf16* __restrict__ out,
                                                 const float* __restrict__ pos, int posoff)
{
    size_t id = (size_t)blockIdx.x * 256 + threadIdx.x;
    if (id >= MC) return;
    int c = (int)(id & 511);
    int r = (int)(id >> 9);
    int b = r & 31, s = r >> 5;
    int t = s >> 6, ij = s & 63;
    int i = ij >> 3, j = ij & 7;
    int n = b >> 2, qh = (b >> 1) & 1, qw = b & 1;
    int m = (n * 10 + t) * 256 + (qh * 8 + i) * 16 + qw * 8 + j;
    float v = in[(size_t)m * CC + c];
    if (pos) v += pos[(size_t)(posoff + t * 64 + ij) * CC + c];
    out[id] = __float2bfloat16(v);
}

// ---------------- reverse permute + residual add into fp32 X ----------------
__global__ __launch_bounds__(256) void k_unperm_add(float* __restrict__ X, const bf16* __restrict__ Tb, int mode)
{
    size_t id = (size_t)blockIdx.x * 256 + threadIdx.x;
    if (id >= MC) return;
    int c = (int)(id & 511);
    int m = (int)(id >> 9);
    int r;
    if (mode == 1) {
        int nt = m >> 8, hw = m & 255;
        int h = hw >> 4, w = hw & 15;
        r = ((h & 7) * 8 + (w & 7)) * 320 + nt * 4 + (h >> 3) * 2 + (w >> 3);
    } else if (mode == 3) {
        int n = m / 2560, rem = m - n * 2560;
        r = (rem >> 8) * 2048 + n * 256 + (rem & 255);
    } else {
        int n = m / 2560, rem = m - n * 2560;
        int t = rem >> 8, hw = rem & 255;
        int h = hw >> 4, w = hw & 15;
        r = (t * 64 + (h & 7) * 8 + (w & 7)) * 32 + n * 4 + (h >> 3) * 2 + (w >> 3);
    }
    X[id] += (float)Tb[(size_t)r * CC + c];
}

__global__ __launch_bounds__(256) void k_add(float* __restrict__ X, const bf16* __restrict__ Y, size_t n)
{
    size_t i = (size_t)blockIdx.x * 256 + threadIdx.x;
    if (i < n) X[i] += (float)Y[i];
}

// ---------------- final residual add: FLOAT32 output ----------------
__global__ __launch_bounds__(256) void k_final(const float* __restrict__ X, const bf16* __restrict__ F,
                                               float* __restrict__ out, size_t n)
{
    size_t i = (size_t)blockIdx.x * 256 + threadIdx.x;
    if (i < n) out[i] = X[i] + (float)F[i];
}

// ---------------- MFMA GEMM: C = A(bf16, M x K) @ W(Nc x K)^T + bias; out bf16 ----------------
// 128x128 tile, BK=32, 4 waves each computing a 64x64 quadrant via 16 x mfma_f32_16x16x32_bf16.
// WB16: weights pre-converted bf16 (uint4 copy staging). else fp32 + in-loop convert.
// EPI 0: bias.  1: bias+BN+GELU.  3: bias+GELU.
template<int EPI, bool WB16>
__global__ __launch_bounds__(256) void k_mgemm(const bf16* __restrict__ A, const float* __restrict__ Wf,
                                               const bf16* __restrict__ Wb,
                                               const float* __restrict__ bias, bf16* __restrict__ Cout,
                                               int Nc, int K,
                                               const float* __restrict__ bng, const float* __restrict__ bnb,
                                               const float* __restrict__ bnm, const float* __restrict__ bnv)
{
    __shared__ short As[128][40];   // [m][k], +8 pad
    __shared__ short Bs[128][40];   // [n][k], +8 pad
    int bm = blockIdx.y * 128, bn = blockIdx.x * 128;
    int tid = threadIdx.x;
    int lane = tid & 63, wave = tid >> 6;
    int wm = (wave & 1) * 64, wn = (wave >> 1) * 64;
    int fr = lane & 15;      // frag row (A) / col (B,D)
    int fq = lane >> 4;      // quad: k-offset fq*8 (A,B), row-offset fq*4 (D)

    f32x4v acc[4][4];
#pragma unroll
    for (int i = 0; i < 4; ++i)
#pragma unroll
        for (int j = 0; j < 4; ++j) acc[i][j] = (f32x4v){0.f, 0.f, 0.f, 0.f};

    for (int k0 = 0; k0 < K; k0 += 32) {
#pragma unroll
        for (int i = 0; i < 2; ++i) {
            int v = tid * 2 + i;                 // 0..511
            int m = v >> 2, kk = (v & 3) * 8;
            *(uint4*)&As[m][kk] = *(const uint4*)&A[(size_t)(bm + m) * K + k0 + kk];
            if constexpr (WB16) {
                *(uint4*)&Bs[m][kk] = *(const uint4*)&Wb[(size_t)(bn + m) * K + k0 + kk];
            } else {
                float4 w0 = *(const float4*)&Wf[(size_t)(bn + m) * K + k0 + kk];
                float4 w1 = *(const float4*)&Wf[(size_t)(bn + m) * K + k0 + kk + 4];
                union { bf16 h[8]; uint4 u; } t;
                t.h[0] = __float2bfloat16(w0.x); t.h[1] = __float2bfloat16(w0.y);
                t.h[2] = __float2bfloat16(w0.z); t.h[3] = __float2bfloat16(w0.w);
                t.h[4] = __float2bfloat16(w1.x); t.h[5] = __float2bfloat16(w1.y);
                t.h[6] = __float2bfloat16(w1.z); t.h[7] = __float2bfloat16(w1.w);
                *(uint4*)&Bs[m][kk] = t.u;
            }
        }
        __syncthreads();
        bf16x8v af[4], bfr[4];
#pragma unroll
        for (int mi = 0; mi < 4; ++mi) af[mi]  = *(bf16x8v*)&As[wm + mi * 16 + fr][fq * 8];
#pragma unroll
        for (int ni = 0; ni < 4; ++ni) bfr[ni] = *(bf16x8v*)&Bs[wn + ni * 16 + fr][fq * 8];
#pragma unroll
        for (int mi = 0; mi < 4; ++mi)
#pragma unroll
            for (int ni = 0; ni < 4; ++ni)
                acc[mi][ni] = __builtin_amdgcn_mfma_f32_16x16x32_bf16(af[mi], bfr[ni], acc[mi][ni], 0, 0, 0);
        __syncthreads();
    }

#pragma unroll
    for (int mi = 0; mi < 4; ++mi)
#pragma unroll
        for (int ni = 0; ni < 4; ++ni)
#pragma unroll
            for (int r = 0; r < 4; ++r) {
                int m = bm + wm + mi * 16 + fq * 4 + r;
                int n = bn + wn + ni * 16 + fr;
                float v = acc[mi][ni][r] + bias[n];
                if constexpr (EPI == 1) {
                    v = (v - bnm[n]) * rsqrtf(bnv[n] + LNEPS) * bng[n] + bnb[n];
                    v = gelu_f(v);
                }
                if constexpr (EPI == 3) v = gelu_f(v);
                Cout[(size_t)m * Nc + n] = __float2bfloat16(v);
            }
}

// ---------------- elementwise dwconv3x3 + BN2 + GELU over a 4096-token chunk ----------------
__global__ __launch_bounds__(256) void k_dwc(const bf16* __restrict__ H1c, bf16* __restrict__ H2c,
                                             const float* __restrict__ dww, const float* __restrict__ dwb,
                                             const float* __restrict__ g2, const float* __restrict__ b2,
                                             const float* __restrict__ m2, const float* __restrict__ v2)
{
    size_t id = (size_t)blockIdx.x * 256 + threadIdx.x;
    if (id >= (size_t)4096 * HIDN) return;
    int k = (int)(id & 2047);
    int lm = (int)(id >> 11);
    int p = lm >> 8, hw = lm & 255, h = hw >> 4, w = hw & 15;
    float a = dwb[k];
#pragma unroll
    for (int dh = -1; dh <= 1; ++dh) {
        int h2 = h + dh;
        if (h2 < 0 || h2 > 15) continue;
#pragma unroll
        for (int dw = -1; dw <= 1; ++dw) {
            int w2 = w + dw;
            if (w2 < 0 || w2 > 15) continue;
            a += (float)H1c[(((size_t)p * 16 + h2) * 16 + w2) * HIDN + k]
               * dww[k * 9 + (dh + 1) * 3 + (dw + 1)];
        }
    }
    float xn = (a - m2[k]) * rsqrtf(v2[k] + LNEPS) * g2[k] + b2[k];
    H2c[id] = __float2bfloat16(gelu_f(xn));
}

// ---------------- generic scalar MHA core, templated on max S (LDS sizing -> occupancy) ----------------
template<int SMAX>
__global__ __launch_bounds__(256) void k_attn(const bf16* __restrict__ Q, const bf16* __restrict__ K,
                                              const bf16* __restrict__ V, bf16* __restrict__ O,
                                              int L, int S, int Bc)
{
    __shared__ float sQ[16][68];
    __shared__ float sK[32][68];
    __shared__ float sV[32][68];
    __shared__ float sS[16][SMAX + 1];
    __shared__ float sRed[16][17];
    int b = blockIdx.x / NHEAD;
    int h = blockIdx.x - b * NHEAD;
    int ql0 = blockIdx.y * 16;
    int tid = threadIdx.x;
    int qi = tid >> 4, g = tid & 15;
    int SCv = (S + 31) & ~31;

    for (int t = tid; t < 16 * 64; t += 256) {
        int r = t >> 6, d = t & 63;
        int l = ql0 + r;
        sQ[r][d] = (l < L) ? (float)Q[((size_t)l * Bc + b) * CC + h * 64 + d] : 0.f;
    }
    __syncthreads();

    for (int s0 = 0; s0 < S; s0 += 32) {
        for (int t = tid; t < 32 * 64; t += 256) {
            int r = t >> 6, d = t & 63;
            int s = s0 + r;
            sK[r][d] = (s < S) ? (float)K[((size_t)s * Bc + b) * CC + h * 64 + d] : 0.f;
        }
        __syncthreads();
#pragma unroll
        for (int half = 0; half < 2; ++half) {
            int si = half * 16 + g;
            int s = s0 + si;
            float acc = 0.f;
#pragma unroll
            for (int d = 0; d < 64; ++d) acc += sQ[qi][d] * sK[si][d];
            sS[qi][s] = (s < S) ? acc * ATTSCALE : -60.f;
        }
        __syncthreads();
    }

    float pm = -60.f;
    for (int s = g; s < SCv; s += 16) pm = fmaxf(pm, sS[qi][s]);
    sRed[qi][g] = pm;
    __syncthreads();
    float mx = sRed[qi][0];
#pragma unroll
    for (int t = 1; t < 16; ++t) mx = fmaxf(mx, sRed[qi][t]);
    __syncthreads();
    float ps = 0.f;
    for (int s = g; s < SCv; s += 16) {
        float e = expf(sS[qi][s] - mx);
        sS[qi][s] = e;
        ps += e;
    }
    sRed[qi][g] = ps;
    __syncthreads();
    float sum = 0.f;
#pragma unroll
    for (int t = 0; t < 16; ++t) sum += sRed[qi][t];
    float inv = 1.f / fmaxf(sum, 1e-20f);

    float o0 = 0.f, o1 = 0.f, o2 = 0.f, o3 = 0.f;
    for (int s0 = 0; s0 < S; s0 += 32) {
        __syncthreads();
        for (int t = tid; t < 32 * 64; t += 256) {
            int r = t >> 6, d = t & 63;
            int s = s0 + r;
            sV[r][d] = (s < S) ? (float)V[((size_t)s * Bc + b) * CC + h * 64 + d] : 0.f;
        }
        __syncthreads();
#pragma unroll
        for (int si = 0; si < 32; ++si) {
            float w = sS[qi][s0 + si];
            o0 += w * sV[si][g * 4 + 0];
            o1 += w * sV[si][g * 4 + 1];
            o2 += w * sV[si][g * 4 + 2];
            o3 += w * sV[si][g * 4 + 3];
        }
    }
    int l = ql0 + qi;
    if (l < L) {
        bf16* op = O + ((size_t)l * Bc + b) * CC + h * 64 + g * 4;
        op[0] = __float2bfloat16(o0 * inv);
        op[1] = __float2bfloat16(o1 * inv);
        op[2] = __float2bfloat16(o2 * inv);
        op[3] = __float2bfloat16(o3 * inv);
    }
}

// ---------------- MFMA flash attention: requires L%64==0, S%64==0, d=64 ----------------
// grid.x = Bc*NHEAD (b*8+h), grid.y = L/64. 256 threads = 4 waves, wave w owns q rows w*16..w*16+15.
__global__ __launch_bounds__(256) void k_fattn(const bf16* __restrict__ Q, const bf16* __restrict__ K,
                                               const bf16* __restrict__ V, bf16* __restrict__ O,
                                               int L, int S, int Bc)
{
    __shared__ short sK[64][72];        // [s][d] bf16, stride 72
    __shared__ short sVt[64][72];       // [d][s] bf16 (V transposed during staging)
    __shared__ short sP[4][16][40];     // per-wave P bounce: [wave][q(0..15)][s(0..63)] bf16

    int b = blockIdx.x >> 3;
    int h = blockIdx.x & 7;
    int q0 = blockIdx.y * 64;
    int tid = threadIdx.x;
    int wv = tid >> 6;
    int lane = tid & 63;
    int fr = lane & 15;                 // frag row (A rows / B rows / D col)
    int fq = lane >> 4;                 // frag quad: k-off fq*8; D row-off fq*4

    const bf16* qp = Q + ((size_t)(q0 + wv * 16 + fr) * Bc + b) * CC + h * 64 + fq * 8;
    bf16x8v qf0 = *(const bf16x8v*)qp;          // k = 0..31 chunk
    bf16x8v qf1 = *(const bf16x8v*)(qp + 32);   // k = 32..63 chunk

    f32x4v oacc[4];
#pragma unroll
    for (int i = 0; i < 4; ++i) oacc[i] = (f32x4v){0.f, 0.f, 0.f, 0.f};
    float m_run[4] = {-1e30f, -1e30f, -1e30f, -1e30f};
    float l_run[4] = {0.f, 0.f, 0.f, 0.f};

    int ks = tid >> 2, kd0 = (tid & 3) * 16;        // K: row s=ks, 2x16B at d=kd0,kd0+8
    int vd0 = (tid & 7) * 8, vs2 = (tid >> 3) * 2;  // V: 8 d, s-pair (vs2, vs2+1)

    for (int s0 = 0; s0 < S; s0 += 64) {
        __syncthreads();
        {
            const bf16* kp = K + ((size_t)(s0 + ks) * Bc + b) * CC + h * 64 + kd0;
            *(uint4*)&sK[ks][kd0]     = *(const uint4*)kp;
            *(uint4*)&sK[ks][kd0 + 8] = *(const uint4*)(kp + 8);
        }
        {
            const bf16* vp0 = V + ((size_t)(s0 + vs2) * Bc + b) * CC + h * 64 + vd0;
            const bf16* vp1 = vp0 + (size_t)Bc * CC;
            uint4 va = *(const uint4*)vp0;
            uint4 vb = *(const uint4*)vp1;
            const ushort* as = (const ushort*)&va;
            const ushort* bs = (const ushort*)&vb;
#pragma unroll
            for (int j = 0; j < 8; ++j)
                *(uint*)&sVt[vd0 + j][vs2] = (uint)as[j] | ((uint)bs[j] << 16);
        }
        __syncthreads();

        f32x4v sc[4];
#pragma unroll
        for (int nt = 0; nt < 4; ++nt) {
            bf16x8v k0 = *(bf16x8v*)&sK[nt * 16 + fr][fq * 8];
            bf16x8v k1 = *(bf16x8v*)&sK[nt * 16 + fr][32 + fq * 8];
            f32x4v z = (f32x4v){0.f, 0.f, 0.f, 0.f};
            z = __builtin_amdgcn_mfma_f32_16x16x32_bf16(qf0, k0, z, 0, 0, 0);
            z = __builtin_amdgcn_mfma_f32_16x16x32_bf16(qf1, k1, z, 0, 0, 0);
            sc[nt] = z;
        }

        short (*sPw)[40] = sP[wv];
#pragma unroll
        for (int r = 0; r < 4; ++r) {
            float mx = fmaxf(fmaxf(sc[0][r], sc[1][r]), fmaxf(sc[2][r], sc[3][r])) * ATTSCALE;
#pragma unroll
            for (int msk = 1; msk < 16; msk <<= 1) mx = fmaxf(mx, __shfl_xor(mx, msk));
            float mnew = fmaxf(m_run[r], mx);
            float alpha = __expf(m_run[r] - mnew);
            m_run[r] = mnew;
            float rs = 0.f;
#pragma unroll
            for (int nt = 0; nt < 4; ++nt) {
                float p = __expf(sc[nt][r] * ATTSCALE - mnew);
                union { bf16 hh; ushort uu; } cv;
                cv.hh = __float2bfloat16(p);
                rs += __bfloat162float(cv.hh);
                sPw[fq * 4 + r][fr + 16 * nt] = (short)cv.uu;
            }
#pragma unroll
            for (int msk = 1; msk < 16; msk <<= 1) rs += __shfl_xor(rs, msk);
            l_run[r] = l_run[r] * alpha + rs;
#pragma unroll
            for (int nt2 = 0; nt2 < 4; ++nt2) oacc[nt2][r] *= alpha;
        }
        __syncthreads();

        bf16x8v pa0 = *(bf16x8v*)&sPw[fr][fq * 8];
        bf16x8v pa1 = *(bf16x8v*)&sPw[fr][32 + fq * 8];
#pragma unroll
        for (int nt2 = 0; nt2 < 4; ++nt2) {
            bf16x8v v0 = *(bf16x8v*)&sVt[nt2 * 16 + fr][fq * 8];
            bf16x8v v1 = *(bf16x8v*)&sVt[nt2 * 16 + fr][32 + fq * 8];
            oacc[nt2] = __builtin_amdgcn_mfma_f32_16x16x32_bf16(pa0, v0, oacc[nt2], 0, 0, 0);
            oacc[nt2] = __builtin_amdgcn_mfma_f32_16x16x32_bf16(pa1, v1, oacc[nt2], 0, 0, 0);
        }
    }

#pragma unroll
    for (int r = 0; r < 4; ++r) {
        float inv = 1.f / fmaxf(l_run[r], 1e-20f);
        bf16* op = O + ((size_t)(q0 + wv * 16 + fq * 4 + r) * Bc + b) * CC + h * 64 + fr;
#pragma unroll
        for (int nt2 = 0; nt2 < 4; ++nt2)
            op[nt2 * 16] = __float2bfloat16(oacc[nt2][r] * inv);
    }
}

// ---------------- host-side GEMM dispatcher ----------------
static void launch_gemm(int epi, bool wb16, dim3 grid,
                        const bf16* A, const float* Wf, const bf16* Wb,
                        const float* bias, bf16* C, int Nc, int K,
                        const float* g, const float* b, const float* m, const float* v,
                        hipStream_t s)
{
    dim3 blk(256);
    if (wb16) {
        switch (epi) {
        case 0: k_mgemm<0, true><<<grid, blk, 0, s>>>(A, Wf, Wb, bias, C, Nc, K, g, b, m, v); break;
        case 1: k_mgemm<1, true><<<grid, blk, 0, s>>>(A, Wf, Wb, bias, C, Nc, K, g, b, m, v); break;
        default: k_mgemm<3, true><<<grid, blk, 0, s>>>(A, Wf, Wb, bias, C, Nc, K, g, b, m, v); break;
        }
    } else {
        switch (epi) {
        case 0: k_mgemm<0, false><<<grid, blk, 0, s>>>(A, Wf, Wb, bias, C, Nc, K, g, b, m, v); break;
        case 1: k_mgemm<1, false><<<grid, blk, 0, s>>>(A, Wf, Wb, bias, C, Nc, K, g, b, m, v); break;
        default: k_mgemm<3, false><<<grid, blk, 0, s>>>(A, Wf, Wb, bias, C, Nc, K, g, b, m, v); break;
        }
    }
}

extern "C" void kernel_launch(void* const* d_in, const int* in_sizes, int n_in,
                              void* d_out, int out_size, void* d_ws, size_t ws_size,
                              hipStream_t stream)
{
    const float* query        = (const float*)d_in[0];
    const float* memory       = (const float*)d_in[1];
    const float* pos_local    = (const float*)d_in[2];
    const float* pos_temporal = (const float*)d_in[3];
    const float* pos_ts       = (const float*)d_in[4];
    const float* ln_g[5] = {(const float*)d_in[5], (const float*)d_in[7], (const float*)d_in[9], (const float*)d_in[11], (const float*)d_in[13]};
    const float* ln_b[5] = {(const float*)d_in[6], (const float*)d_in[8], (const float*)d_in[10], (const float*)d_in[12], (const float*)d_in[14]};
    const float* sa_w_in  = (const float*)d_in[15]; const float* sa_b_in  = (const float*)d_in[16];
    const float* sa_w_out = (const float*)d_in[17]; const float* sa_b_out = (const float*)d_in[18];
    const float* ta_w_in  = (const float*)d_in[19]; const float* ta_b_in  = (const float*)d_in[20];
    const float* ta_w_out = (const float*)d_in[21]; const float* ta_b_out = (const float*)d_in[22];
    const float* ca_w_in  = (const float*)d_in[23]; const float* ca_b_in  = (const float*)d_in[24];
    const float* ca_w_out = (const float*)d_in[25]; const float* ca_b_out = (const float*)d_in[26];
    const float* fc1_w = (const float*)d_in[27]; const float* fc1_b = (const float*)d_in[28];
    const float* dw_w  = (const float*)d_in[29]; const float* dw_b  = (const float*)d_in[30];
    const float* fc2_w = (const float*)d_in[31]; const float* fc2_b = (const float*)d_in[32];
    const float* bn1g = (const float*)d_in[33], *bn1b = (const float*)d_in[34], *bn1m = (const float*)d_in[35], *bn1v = (const float*)d_in[36];
    const float* bn2g = (const float*)d_in[37], *bn2b = (const float*)d_in[38], *bn2m = (const float*)d_in[39], *bn2v = (const float*)d_in[40];
    const float* bn3g = (const float*)d_in[41], *bn3b = (const float*)d_in[42], *bn3m = (const float*)d_in[43], *bn3v = (const float*)d_in[44];
    const float* lin1_w = (const float*)d_in[45]; const float* lin1_b = (const float*)d_in[46];
    const float* lin2_w = (const float*)d_in[47]; const float* lin2_b = (const float*)d_in[48];

    dim3 blk(256);
    int gMC = (int)(MC / 256);

    size_t need_small = MC * 4 + 4 * MC * 2;
    size_t need_big   = need_small + WTOT * 2;
    if (ws_size < need_small) {
        k_fill<<<gMC, blk, 0, stream>>>((float*)d_out, 700.f, MC);
        return;
    }
    bool wb16 = (ws_size >= need_big);

    float* X = (float*)d_ws;
    bf16* B0 = (bf16*)((char*)d_ws + MC * 4);
    bf16* B1 = B0 + MC;
    bf16* B2 = B1 + MC;
    bf16* B3 = B2 + MC;
    bf16* WB = B3 + MC;
    const float* nulf = nullptr;
    bf16* nulm = nullptr;

    // bf16 weight views (valid only when wb16)
    bf16* wb_sa_in  = WB + 0;
    bf16* wb_sa_out = WB + 786432;
    bf16* wb_ta_in  = WB + 1048576;
    bf16* wb_ta_out = WB + 1835008;
    bf16* wb_ca_in  = WB + 2097152;
    bf16* wb_ca_out = WB + 2883584;
    bf16* wb_fc1    = WB + 3145728;
    bf16* wb_fc2    = WB + 4194304;
    bf16* wb_lin1   = WB + 5242880;
    bf16* wb_lin2   = WB + 6291456;

    if (wb16) {
        k_cvtw<<<(int)((WTOT + 255) / 256), blk, 0, stream>>>(WB,
            sa_w_in, sa_w_out, ta_w_in, ta_w_out, ca_w_in, ca_w_out,
            fc1_w, fc2_w, lin1_w, lin2_w);
    }

    hipMemcpyAsync(X, query, MC * sizeof(float), hipMemcpyDeviceToDevice, stream);

    // ---- stage 1: spatial window MHSA (L=S=64, Bc=320) ----
    k_ln2<<<MTOK, 64, 0, stream>>>(X, B0, B1, ln_g[0], ln_b[0], pos_local, 0, 1);
    launch_gemm(0, wb16, dim3(4, 160), B1, sa_w_in,                wb_sa_in,          sa_b_in,        B2, 512, 512, nulf, nulf, nulf, nulf, stream);
    launch_gemm(0, wb16, dim3(4, 160), B1, sa_w_in + 262144,       wb_sa_in + 262144, sa_b_in + 512,  B3, 512, 512, nulf, nulf, nulf, nulf, stream);
    launch_gemm(0, wb16, dim3(4, 160), B0, sa_w_in + 524288,       wb_sa_in + 524288, sa_b_in + 1024, B1, 512, 512, nulf, nulf, nulf, nulf, stream);
    k_fattn<<<dim3(320 * NHEAD, 1), blk, 0, stream>>>(B2, B3, B1, B0, 64, 64, 320);
    launch_gemm(0, wb16, dim3(4, 160), B0, sa_w_out, wb_sa_out, sa_b_out, B2, 512, 512, nulf, nulf, nulf, nulf, stream);
    k_unperm_add<<<gMC, blk, 0, stream>>>(X, B2, 1);

    // ---- stage 2: MlpDWBN, chunked over 16-plane slabs ----
    k_ln2<<<MTOK, 64, 0, stream>>>(X, B0, nulm, ln_g[1], ln_b[1], nulf, 0, 0);
    for (int c = 0; c < 5; ++c) {
        int off = c * 4096;
        launch_gemm(1, wb16, dim3(16, 32), B0 + (size_t)off * CC, fc1_w, wb_fc1, fc1_b, B1, 2048, 512,
                    bn1g, bn1b, bn1m, bn1v, stream);
        k_dwc<<<32768, blk, 0, stream>>>(B1, B3, dw_w, dw_b, bn2g, bn2b, bn2m, bn2v);
        launch_gemm(1, wb16, dim3(4, 32), B3, fc2_w, wb_fc2, fc2_b, B2 + (size_t)off * CC, 512, 2048,
                    bn3g, bn3b, bn3m, bn3v, stream);
    }
    k_add<<<gMC, blk, 0, stream>>>(X, B2, MC);

    // ---- stage 3: temporal MHSA (T=10: scalar path, small-S LDS) ----
    k_ln2<<<MTOK, 64, 0, stream>>>(X, B0, B1, ln_g[2], ln_b[2], pos_temporal, 0, 3);
    launch_gemm(0, wb16, dim3(4, 160), B1, ta_w_in,          wb_ta_in,          ta_b_in,        B2, 512, 512, nulf, nulf, nulf, nulf, stream);
    launch_gemm(0, wb16, dim3(4, 160), B1, ta_w_in + 262144, wb_ta_in + 262144, ta_b_in + 512,  B3, 512, 512, nulf, nulf, nulf, nulf, stream);
    launch_gemm(0, wb16, dim3(4, 160), B0, ta_w_in + 524288, wb_ta_in + 524288, ta_b_in + 1024, B1, 512, 512, nulf, nulf, nulf, nulf, stream);
    k_attn<32><<<dim3(2048 * NHEAD, 1), blk, 0, stream>>>(B2, B3, B1, B0, 10, 10, 2048);
    launch_gemm(0, wb16, dim3(4, 160), B0, ta_w_out, wb_ta_out, ta_b_out, B2, 512, 512, nulf, nulf, nulf, nulf, stream);
    k_unperm_add<<<gMC, blk, 0, stream>>>(X, B2, 3);

    // ---- stage 4: temporal-spatial cross-attention (L=S=640, Bc=32: MFMA flash) ----
    k_ln2<<<MTOK, 64, 0, stream>>>(X, nulm, B1, ln_g[3], ln_b[3], pos_ts, 640, 4);
    launch_gemm(0, wb16, dim3(4, 160), B1, ca_w_in, wb_ca_in, ca_b_in, B2, 512, 512, nulf, nulf, nulf, nulf, stream);
    k_permmem<<<gMC, blk, 0, stream>>>(memory, B1, pos_ts, 0);
    launch_gemm(0, wb16, dim3(4, 160), B1, ca_w_in + 262144, wb_ca_in + 262144, ca_b_in + 512, B3, 512, 512, nulf, nulf, nulf, nulf, stream);
    k_permmem<<<gMC, blk, 0, stream>>>(memory, B1, nulf, 0);
    launch_gemm(0, wb16, dim3(4, 160), B1, ca_w_in + 524288, wb_ca_in + 524288, ca_b_in + 1024, B0, 512, 512, nulf, nulf, nulf, nulf, stream);
    k_fattn<<<dim3(32 * NHEAD, 10), blk, 0, stream>>>(B2, B3, B0, B1, 640, 640, 32);
    launch_gemm(0, wb16, dim3(4, 160), B1, ca_w_out, wb_ca_out, ca_b_out, B2, 512, 512, nulf, nulf, nulf, nulf, stream);
    k_unperm_add<<<gMC, blk, 0, stream>>>(X, B2, 4);

    // ---- stage 5: final FFN, chunked ----
    k_ln2<<<MTOK, 64, 0, stream>>>(X, B0, nulm, ln_g[4], ln_b[4], nulf, 0, 0);
    for (int c = 0; c < 5; ++c) {
        int off = c * 4096;
        launch_gemm(3, wb16, dim3(16, 32), B0 + (size_t)off * CC, lin1_w, wb_lin1, lin1_b, B1, 2048, 512,
                    nulf, nulf, nulf, nulf, stream);
        launch_gemm(0, wb16, dim3(4, 32), B1, lin2_w, wb_lin2, lin2_b, B2 + (size_t)off * CC, 512, 2048,
                    nulf, nulf, nulf, nulf, stream);
    }
    k_final<<<gMC, blk, 0, stream>>>(X, B2, (float*)d_out, MC);
}

// Round 3
// 1913.030 us; speedup vs baseline: 2.7854x; 1.0994x over previous
//
#include <hip/hip_runtime.h>
#include <hip/hip_bf16.h>
#include <math.h>

typedef __hip_bfloat16 bf16;
typedef unsigned int u32;
typedef __attribute__((ext_vector_type(8))) short bf16x8v;
typedef __attribute__((ext_vector_type(4))) float f32x4v;

static constexpr int NB = 8, TT = 10, HH = 16, WW = 16, CC = 512;
static constexpr int NHEAD = 8, HIDN = 2048;
static constexpr int MTOK = NB * TT * HH * WW;          // 20480 tokens
static constexpr size_t MC = (size_t)MTOK * CC;         // 10485760
static constexpr float LNEPS = 1e-5f;
static constexpr float ATTSCALE = 0.125f;               // 1/sqrt(64)
static constexpr size_t WTOT = 7340032;                 // total weight elems pre-converted to bf16

static __device__ __forceinline__ float gelu_f(float x) {
    return 0.5f * x * (1.0f + erff(x * 0.70710678118654752f));
}

// direct global->LDS async copy, 16B per lane; LDS dest = wave-uniform base + lane*16
static __device__ __forceinline__ void gl_lds16(const void* g, void* l)
{
    __builtin_amdgcn_global_load_lds((const __attribute__((address_space(1))) u32*)g,
                                     (__attribute__((address_space(3))) u32*)l, 16, 0, 0);
}

// ---------------- ws-too-small diagnostic ----------------
__global__ __launch_bounds__(256) void k_fill(float* __restrict__ out, float v, size_t n)
{
    size_t i = (size_t)blockIdx.x * 256 + threadIdx.x;
    if (i < n) out[i] = v;
}

// ---------------- one-shot fp32 -> bf16 weight conversion (28 segments of 262144) ----------------
__global__ __launch_bounds__(256) void k_cvtw(bf16* __restrict__ out,
    const float* __restrict__ p0, const float* __restrict__ p1, const float* __restrict__ p2,
    const float* __restrict__ p3, const float* __restrict__ p4, const float* __restrict__ p5,
    const float* __restrict__ p6, const float* __restrict__ p7, const float* __restrict__ p8,
    const float* __restrict__ p9)
{
    size_t id = (size_t)blockIdx.x * 256 + threadIdx.x;
    if (id >= WTOT) return;
    int sid = (int)(id >> 18);                 // /262144
    const float* base; size_t lo;
    if (sid < 3)       { base = p0; lo = id; }
    else if (sid < 4)  { base = p1; lo = id - (size_t)3  * 262144; }
    else if (sid < 7)  { base = p2; lo = id - (size_t)4  * 262144; }
    else if (sid < 8)  { base = p3; lo = id - (size_t)7  * 262144; }
    else if (sid < 11) { base = p4; lo = id - (size_t)8  * 262144; }
    else if (sid < 12) { base = p5; lo = id - (size_t)11 * 262144; }
    else if (sid < 16) { base = p6; lo = id - (size_t)12 * 262144; }
    else if (sid < 20) { base = p7; lo = id - (size_t)16 * 262144; }
    else if (sid < 24) { base = p8; lo = id - (size_t)20 * 262144; }
    else               { base = p9; lo = id - (size_t)24 * 262144; }
    out[id] = __float2bfloat16(base[lo]);
}

// ---------------- fused LayerNorm (+permute, +pos); X fp32, dst bf16 ----------------
__global__ __launch_bounds__(64) void k_ln2(const float* __restrict__ X, bf16* __restrict__ dstA,
                                            bf16* __restrict__ dstB,
                                            const float* __restrict__ g, const float* __restrict__ b,
                                            const float* __restrict__ pos, int posoff, int mode)
{
    int m = blockIdx.x;
    int lane = threadIdx.x;
    const float* row = X + (size_t)m * CC;
    float v[8], s = 0.f, s2 = 0.f;
#pragma unroll
    for (int i = 0; i < 8; ++i) { v[i] = row[lane + i * 64]; s += v[i]; s2 += v[i] * v[i]; }
#pragma unroll
    for (int msk = 1; msk < 64; msk <<= 1) { s += __shfl_xor(s, msk); s2 += __shfl_xor(s2, msk); }
    float mean = s * (1.f / 512.f);
    float var  = fmaxf(s2 * (1.f / 512.f) - mean * mean, 0.f);
    float rr = rsqrtf(var + LNEPS);

    int r, pr = 0;
    if (mode == 0) { r = m; }
    else if (mode == 1) {
        int nt = m >> 8, hw = m & 255, h = hw >> 4, w = hw & 15;
        int l = (h & 7) * 8 + (w & 7);
        r = l * 320 + nt * 4 + (h >> 3) * 2 + (w >> 3);
        pr = l;
    } else if (mode == 3) {
        int n = m / 2560, rem = m - n * 2560;
        int t = rem >> 8;
        r = t * 2048 + n * 256 + (rem & 255);
        pr = t;
    } else {
        int n = m / 2560, rem = m - n * 2560;
        int t = rem >> 8, hw = rem & 255, h = hw >> 4, w = hw & 15;
        int ij = (h & 7) * 8 + (w & 7);
        r = (t * 64 + ij) * 32 + n * 4 + (h >> 3) * 2 + (w >> 3);
        pr = t * 64 + ij;
    }
#pragma unroll
    for (int i = 0; i < 8; ++i) {
        int c = lane + i * 64;
        float y = (v[i] - mean) * rr * g[c] + b[c];
        if (dstA) dstA[(size_t)r * CC + c] = __float2bfloat16(y);
        if (dstB) dstB[(size_t)r * CC + c] = __float2bfloat16(y + pos[(size_t)(posoff + pr) * CC + c]);
    }
}

// ---------------- gather-permute of fp32 `memory` into ts layout (+optional pos) ----------------
__global__ __launch_bounds__(256) void k_permmem(const float* __restrict__ in, bf16* __restrict__ out,
                                                 const float* __restrict__ pos, int posoff)
{
    size_t id = (size_t)blockIdx.x * 256 + threadIdx.x;
    if (id >= MC) return;
    int c = (int)(id & 511);
    int r = (int)(id >> 9);
    int b = r & 31, s = r >> 5;
    int t = s >> 6, ij = s & 63;
    int i = ij >> 3, j = ij & 7;
    int n = b >> 2, qh = (b >> 1) & 1, qw = b & 1;
    int m = (n * 10 + t) * 256 + (qh * 8 + i) * 16 + qw * 8 + j;
    float v = in[(size_t)m * CC + c];
    if (pos) v += pos[(size_t)(posoff + t * 64 + ij) * CC + c];
    out[id] = __float2bfloat16(v);
}

// ---------------- reverse permute + residual add into fp32 X ----------------
__global__ __launch_bounds__(256) void k_unperm_add(float* __restrict__ X, const bf16* __restrict__ Tb, int mode)
{
    size_t id = (size_t)blockIdx.x * 256 + threadIdx.x;
    if (id >= MC) return;
    int c = (int)(id & 511);
    int m = (int)(id >> 9);
    int r;
    if (mode == 1) {
        int nt = m >> 8, hw = m & 255;
        int h = hw >> 4, w = hw & 15;
        r = ((h & 7) * 8 + (w & 7)) * 320 + nt * 4 + (h >> 3) * 2 + (w >> 3);
    } else if (mode == 3) {
        int n = m / 2560, rem = m - n * 2560;
        r = (rem >> 8) * 2048 + n * 256 + (rem & 255);
    } else {
        int n = m / 2560, rem = m - n * 2560;
        int t = rem >> 8, hw = rem & 255;
        int h = hw >> 4, w = hw & 15;
        r = (t * 64 + (h & 7) * 8 + (w & 7)) * 32 + n * 4 + (h >> 3) * 2 + (w >> 3);
    }
    X[id] += (float)Tb[(size_t)r * CC + c];
}

__global__ __launch_bounds__(256) void k_add(float* __restrict__ X, const bf16* __restrict__ Y, size_t n)
{
    size_t i = (size_t)blockIdx.x * 256 + threadIdx.x;
    if (i < n) X[i] += (float)Y[i];
}

// ---------------- final residual add: FLOAT32 output ----------------
__global__ __launch_bounds__(256) void k_final(const float* __restrict__ X, const bf16* __restrict__ F,
                                               float* __restrict__ out, size_t n)
{
    size_t i = (size_t)blockIdx.x * 256 + threadIdx.x;
    if (i < n) out[i] = X[i] + (float)F[i];
}

// ---------------- MFMA GEMM: C = A(bf16, M x K) @ W(Nc x K)^T + bias; out bf16 ----------------
// 128x128 tile, BK=32, 4 waves each computing a 64x64 quadrant via 16 x mfma_f32_16x16x32_bf16.
// WB16=true: bf16 weights, staging via global_load_lds width-16 into linear [128][32] LDS.
// WB16=false: fp32 weights, register staging + in-loop convert, padded [128][40] LDS.
// EPI 0: bias.  1: bias+BN+GELU.  3: bias+GELU.
template<int EPI, bool WB16>
__global__ __launch_bounds__(256) void k_mgemm(const bf16* __restrict__ A, const float* __restrict__ Wf,
                                               const bf16* __restrict__ Wb,
                                               const float* __restrict__ bias, bf16* __restrict__ Cout,
                                               int Nc, int K,
                                               const float* __restrict__ bng, const float* __restrict__ bnb,
                                               const float* __restrict__ bnm, const float* __restrict__ bnv)
{
    __shared__ short smem[WB16 ? 2 * 128 * 32 : 2 * 128 * 40];
    constexpr int LDW = WB16 ? 32 : 40;           // LDS row stride (shorts)
    short* As = smem;
    short* Bs = smem + 128 * LDW;

    int bm = blockIdx.y * 128, bn = blockIdx.x * 128;
    int tid = threadIdx.x;
    int lane = tid & 63, wave = tid >> 6;
    int wm = (wave & 1) * 64, wn = (wave >> 1) * 64;
    int fr = lane & 15;      // frag row (A) / col (B,D)
    int fq = lane >> 4;      // quad: k-offset fq*8 (A,B), row-offset fq*4 (D)

    f32x4v acc[4][4];
#pragma unroll
    for (int i = 0; i < 4; ++i)
#pragma unroll
        for (int j = 0; j < 4; ++j) acc[i][j] = (f32x4v){0.f, 0.f, 0.f, 0.f};

    if constexpr (WB16) {
        // wave w stages rows w*32..w*32+31 of both tiles; lane covers 8 elems at
        // row = w*32 + i*16 + (lane>>2), col = (lane&3)*8  (matches LDS linear order)
        int srow = wave * 32 + (lane >> 2);
        int scol = (lane & 3) * 8;
        const bf16* aptr = A  + (size_t)(bm + srow) * K + scol;
        const bf16* bptr = Wb + (size_t)(bn + srow) * K + scol;
        const size_t row16 = (size_t)16 * K;
        short* asl = &As[wave * 1024];
        short* bsl = &Bs[wave * 1024];

        for (int k0 = 0; k0 < K; k0 += 32) {
            gl_lds16(aptr + k0,         asl);
            gl_lds16(aptr + row16 + k0, asl + 512);
            gl_lds16(bptr + k0,         bsl);
            gl_lds16(bptr + row16 + k0, bsl + 512);
            __syncthreads();            // drains vmcnt -> LDS tiles complete
            bf16x8v af[4], bfr[4];
#pragma unroll
            for (int mi = 0; mi < 4; ++mi) af[mi]  = *(bf16x8v*)&As[(wm + mi * 16 + fr) * 32 + fq * 8];
#pragma unroll
            for (int ni = 0; ni < 4; ++ni) bfr[ni] = *(bf16x8v*)&Bs[(wn + ni * 16 + fr) * 32 + fq * 8];
#pragma unroll
            for (int mi = 0; mi < 4; ++mi)
#pragma unroll
                for (int ni = 0; ni < 4; ++ni)
                    acc[mi][ni] = __builtin_amdgcn_mfma_f32_16x16x32_bf16(af[mi], bfr[ni], acc[mi][ni], 0, 0, 0);
            __syncthreads();
        }
    } else {
        for (int k0 = 0; k0 < K; k0 += 32) {
#pragma unroll
            for (int i = 0; i < 2; ++i) {
                int v = tid * 2 + i;                 // 0..511
                int m = v >> 2, kk = (v & 3) * 8;
                *(uint4*)&As[m * LDW + kk] = *(const uint4*)&A[(size_t)(bm + m) * K + k0 + kk];
                float4 w0 = *(const float4*)&Wf[(size_t)(bn + m) * K + k0 + kk];
                float4 w1 = *(const float4*)&Wf[(size_t)(bn + m) * K + k0 + kk + 4];
                union { bf16 h[8]; uint4 u; } t;
                t.h[0] = __float2bfloat16(w0.x); t.h[1] = __float2bfloat16(w0.y);
                t.h[2] = __float2bfloat16(w0.z); t.h[3] = __float2bfloat16(w0.w);
                t.h[4] = __float2bfloat16(w1.x); t.h[5] = __float2bfloat16(w1.y);
                t.h[6] = __float2bfloat16(w1.z); t.h[7] = __float2bfloat16(w1.w);
                *(uint4*)&Bs[m * LDW + kk] = t.u;
            }
            __syncthreads();
            bf16x8v af[4], bfr[4];
#pragma unroll
            for (int mi = 0; mi < 4; ++mi) af[mi]  = *(bf16x8v*)&As[(wm + mi * 16 + fr) * LDW + fq * 8];
#pragma unroll
            for (int ni = 0; ni < 4; ++ni) bfr[ni] = *(bf16x8v*)&Bs[(wn + ni * 16 + fr) * LDW + fq * 8];
#pragma unroll
            for (int mi = 0; mi < 4; ++mi)
#pragma unroll
                for (int ni = 0; ni < 4; ++ni)
                    acc[mi][ni] = __builtin_amdgcn_mfma_f32_16x16x32_bf16(af[mi], bfr[ni], acc[mi][ni], 0, 0, 0);
            __syncthreads();
        }
    }

#pragma unroll
    for (int mi = 0; mi < 4; ++mi)
#pragma unroll
        for (int ni = 0; ni < 4; ++ni)
#pragma unroll
            for (int r = 0; r < 4; ++r) {
                int m = bm + wm + mi * 16 + fq * 4 + r;
                int n = bn + wn + ni * 16 + fr;
                float v = acc[mi][ni][r] + bias[n];
                if constexpr (EPI == 1) {
                    v = (v - bnm[n]) * rsqrtf(bnv[n] + LNEPS) * bng[n] + bnb[n];
                    v = gelu_f(v);
                }
                if constexpr (EPI == 3) v = gelu_f(v);
                Cout[(size_t)m * Nc + n] = __float2bfloat16(v);
            }
}

// ---------------- elementwise dwconv3x3 + BN2 + GELU over an ntok-token chunk ----------------
__global__ __launch_bounds__(256) void k_dwc(const bf16* __restrict__ H1c, bf16* __restrict__ H2c,
                                             const float* __restrict__ dww, const float* __restrict__ dwb,
                                             const float* __restrict__ g2, const float* __restrict__ b2,
                                             const float* __restrict__ m2, const float* __restrict__ v2,
                                             int ntok)
{
    size_t id = (size_t)blockIdx.x * 256 + threadIdx.x;
    if (id >= (size_t)ntok * HIDN) return;
    int k = (int)(id & 2047);
    int lm = (int)(id >> 11);
    int p = lm >> 8, hw = lm & 255, h = hw >> 4, w = hw & 15;
    float a = dwb[k];
#pragma unroll
    for (int dh = -1; dh <= 1; ++dh) {
        int h2 = h + dh;
        if (h2 < 0 || h2 > 15) continue;
#pragma unroll
        for (int dw = -1; dw <= 1; ++dw) {
            int w2 = w + dw;
            if (w2 < 0 || w2 > 15) continue;
            a += (float)H1c[(((size_t)p * 16 + h2) * 16 + w2) * HIDN + k]
               * dww[k * 9 + (dh + 1) * 3 + (dw + 1)];
        }
    }
    float xn = (a - m2[k]) * rsqrtf(v2[k] + LNEPS) * g2[k] + b2[k];
    H2c[id] = __float2bfloat16(gelu_f(xn));
}

// ---------------- generic scalar MHA core, templated on max S (LDS sizing -> occupancy) ----------------
template<int SMAX>
__global__ __launch_bounds__(256) void k_attn(const bf16* __restrict__ Q, const bf16* __restrict__ K,
                                              const bf16* __restrict__ V, bf16* __restrict__ O,
                                              int L, int S, int Bc)
{
    __shared__ float sQ[16][68];
    __shared__ float sK[32][68];
    __shared__ float sV[32][68];
    __shared__ float sS[16][SMAX + 1];
    __shared__ float sRed[16][17];
    int b = blockIdx.x / NHEAD;
    int h = blockIdx.x - b * NHEAD;
    int ql0 = blockIdx.y * 16;
    int tid = threadIdx.x;
    int qi = tid >> 4, g = tid & 15;
    int SCv = (S + 31) & ~31;

    for (int t = tid; t < 16 * 64; t += 256) {
        int r = t >> 6, d = t & 63;
        int l = ql0 + r;
        sQ[r][d] = (l < L) ? (float)Q[((size_t)l * Bc + b) * CC + h * 64 + d] : 0.f;
    }
    __syncthreads();

    for (int s0 = 0; s0 < S; s0 += 32) {
        for (int t = tid; t < 32 * 64; t += 256) {
            int r = t >> 6, d = t & 63;
            int s = s0 + r;
            sK[r][d] = (s < S) ? (float)K[((size_t)s * Bc + b) * CC + h * 64 + d] : 0.f;
        }
        __syncthreads();
#pragma unroll
        for (int half = 0; half < 2; ++half) {
            int si = half * 16 + g;
            int s = s0 + si;
            float acc = 0.f;
#pragma unroll
            for (int d = 0; d < 64; ++d) acc += sQ[qi][d] * sK[si][d];
            sS[qi][s] = (s < S) ? acc * ATTSCALE : -60.f;
        }
        __syncthreads();
    }

    float pm = -60.f;
    for (int s = g; s < SCv; s += 16) pm = fmaxf(pm, sS[qi][s]);
    sRed[qi][g] = pm;
    __syncthreads();
    float mx = sRed[qi][0];
#pragma unroll
    for (int t = 1; t < 16; ++t) mx = fmaxf(mx, sRed[qi][t]);
    __syncthreads();
    float ps = 0.f;
    for (int s = g; s < SCv; s += 16) {
        float e = expf(sS[qi][s] - mx);
        sS[qi][s] = e;
        ps += e;
    }
    sRed[qi][g] = ps;
    __syncthreads();
    float sum = 0.f;
#pragma unroll
    for (int t = 0; t < 16; ++t) sum += sRed[qi][t];
    float inv = 1.f / fmaxf(sum, 1e-20f);

    float o0 = 0.f, o1 = 0.f, o2 = 0.f, o3 = 0.f;
    for (int s0 = 0; s0 < S; s0 += 32) {
        __syncthreads();
        for (int t = tid; t < 32 * 64; t += 256) {
            int r = t >> 6, d = t & 63;
            int s = s0 + r;
            sV[r][d] = (s < S) ? (float)V[((size_t)s * Bc + b) * CC + h * 64 + d] : 0.f;
        }
        __syncthreads();
#pragma unroll
        for (int si = 0; si < 32; ++si) {
            float w = sS[qi][s0 + si];
            o0 += w * sV[si][g * 4 + 0];
            o1 += w * sV[si][g * 4 + 1];
            o2 += w * sV[si][g * 4 + 2];
            o3 += w * sV[si][g * 4 + 3];
        }
    }
    int l = ql0 + qi;
    if (l < L) {
        bf16* op = O + ((size_t)l * Bc + b) * CC + h * 64 + g * 4;
        op[0] = __float2bfloat16(o0 * inv);
        op[1] = __float2bfloat16(o1 * inv);
        op[2] = __float2bfloat16(o2 * inv);
        op[3] = __float2bfloat16(o3 * inv);
    }
}

// ---------------- MFMA flash attention: requires L%64==0, S%64==0, d=64 ----------------
// grid.x = Bc*NHEAD (b*8+h), grid.y = L/64. 256 threads = 4 waves, wave w owns q rows w*16..w*16+15.
// sVt swizzle: off(d,s) = d*64 + (s ^ ((((d>>3)^(d&7))&7)<<3)) -- writes 8-way -> 2-way conflict.
__global__ __launch_bounds__(256) void k_fattn(const bf16* __restrict__ Q, const bf16* __restrict__ K,
                                               const bf16* __restrict__ V, bf16* __restrict__ O,
                                               int L, int S, int Bc)
{
    __shared__ short sK[64][72];        // [s][d] bf16, stride 72
    __shared__ short sVt[64 * 64];      // [d][s] bf16, swizzled (see above)
    __shared__ short sP[4][16][40];     // per-wave P bounce: [wave][q(0..15)][s(0..63)] bf16

    int b = blockIdx.x >> 3;
    int h = blockIdx.x & 7;
    int q0 = blockIdx.y * 64;
    int tid = threadIdx.x;
    int wv = tid >> 6;
    int lane = tid & 63;
    int fr = lane & 15;                 // frag row (A rows / B rows / D col)
    int fq = lane >> 4;                 // frag quad: k-off fq*8; D row-off fq*4

    const bf16* qp = Q + ((size_t)(q0 + wv * 16 + fr) * Bc + b) * CC + h * 64 + fq * 8;
    bf16x8v qf0 = *(const bf16x8v*)qp;          // k = 0..31 chunk
    bf16x8v qf1 = *(const bf16x8v*)(qp + 32);   // k = 32..63 chunk

    f32x4v oacc[4];
#pragma unroll
    for (int i = 0; i < 4; ++i) oacc[i] = (f32x4v){0.f, 0.f, 0.f, 0.f};
    float m_run[4] = {-1e30f, -1e30f, -1e30f, -1e30f};
    float l_run[4] = {0.f, 0.f, 0.f, 0.f};

    int ks = tid >> 2, kd0 = (tid & 3) * 16;        // K: row s=ks, 2x16B at d=kd0,kd0+8
    int vd0 = (tid & 7) * 8, vs2 = (tid >> 3) * 2;  // V: 8 d, s-pair (vs2, vs2+1)

    for (int s0 = 0; s0 < S; s0 += 64) {
        __syncthreads();
        {
            const bf16* kp = K + ((size_t)(s0 + ks) * Bc + b) * CC + h * 64 + kd0;
            *(uint4*)&sK[ks][kd0]     = *(const uint4*)kp;
            *(uint4*)&sK[ks][kd0 + 8] = *(const uint4*)(kp + 8);
        }
        {
            const bf16* vp0 = V + ((size_t)(s0 + vs2) * Bc + b) * CC + h * 64 + vd0;
            const bf16* vp1 = vp0 + (size_t)Bc * CC;
            uint4 va = *(const uint4*)vp0;
            uint4 vb = *(const uint4*)vp1;
            const ushort* as = (const ushort*)&va;
            const ushort* bs = (const ushort*)&vb;
#pragma unroll
            for (int j = 0; j < 8; ++j) {
                int dd = vd0 + j;
                int sw = vs2 ^ (((( dd >> 3) ^ (dd & 7)) & 7) << 3);
                *(uint*)&sVt[dd * 64 + sw] = (uint)as[j] | ((uint)bs[j] << 16);
            }
        }
        __syncthreads();

        f32x4v sc[4];
#pragma unroll
        for (int nt = 0; nt < 4; ++nt) {
            bf16x8v k0 = *(bf16x8v*)&sK[nt * 16 + fr][fq * 8];
            bf16x8v k1 = *(bf16x8v*)&sK[nt * 16 + fr][32 + fq * 8];
            f32x4v z = (f32x4v){0.f, 0.f, 0.f, 0.f};
            z = __builtin_amdgcn_mfma_f32_16x16x32_bf16(qf0, k0, z, 0, 0, 0);
            z = __builtin_amdgcn_mfma_f32_16x16x32_bf16(qf1, k1, z, 0, 0, 0);
            sc[nt] = z;
        }

        short (*sPw)[40] = sP[wv];
#pragma unroll
        for (int r = 0; r < 4; ++r) {
            float mx = fmaxf(fmaxf(sc[0][r], sc[1][r]), fmaxf(sc[2][r], sc[3][r])) * ATTSCALE;
#pragma unroll
            for (int msk = 1; msk < 16; msk <<= 1) mx = fmaxf(mx, __shfl_xor(mx, msk));
            float mnew = fmaxf(m_run[r], mx);
            float alpha = __expf(m_run[r] - mnew);
            m_run[r] = mnew;
            float rs = 0.f;
#pragma unroll
            for (int nt = 0; nt < 4; ++nt) {
                float p = __expf(sc[nt][r] * ATTSCALE - mnew);
                union { bf16 hh; ushort uu; } cv;
                cv.hh = __float2bfloat16(p);
                rs += __bfloat162float(cv.hh);
                sPw[fq * 4 + r][fr + 16 * nt] = (short)cv.uu;
            }
#pragma unroll
            for (int msk = 1; msk < 16; msk <<= 1) rs += __shfl_xor(rs, msk);
            l_run[r] = l_run[r] * alpha + rs;
#pragma unroll
            for (int nt2 = 0; nt2 < 4; ++nt2) oacc[nt2][r] *= alpha;
        }
        __syncthreads();

        bf16x8v pa0 = *(bf16x8v*)&sPw[fr][fq * 8];
        bf16x8v pa1 = *(bf16x8v*)&sPw[fr][32 + fq * 8];
#pragma unroll
        for (int nt2 = 0; nt2 < 4; ++nt2) {
            int vr = nt2 * 16 + fr;
            int vx = (((vr >> 3) ^ (vr & 7)) & 7) << 3;
            bf16x8v v0 = *(bf16x8v*)&sVt[vr * 64 + ((fq * 8) ^ vx)];
            bf16x8v v1 = *(bf16x8v*)&sVt[vr * 64 + ((32 + fq * 8) ^ vx)];
            oacc[nt2] = __builtin_amdgcn_mfma_f32_16x16x32_bf16(pa0, v0, oacc[nt2], 0, 0, 0);
            oacc[nt2] = __builtin_amdgcn_mfma_f32_16x16x32_bf16(pa1, v1, oacc[nt2], 0, 0, 0);
        }
    }

#pragma unroll
    for (int r = 0; r < 4; ++r) {
        float inv = 1.f / fmaxf(l_run[r], 1e-20f);
        bf16* op = O + ((size_t)(q0 + wv * 16 + fq * 4 + r) * Bc + b) * CC + h * 64 + fr;
#pragma unroll
        for (int nt2 = 0; nt2 < 4; ++nt2)
            op[nt2 * 16] = __float2bfloat16(oacc[nt2][r] * inv);
    }
}

// ---------------- host-side GEMM dispatcher ----------------
static void launch_gemm(int epi, bool wb16, dim3 grid,
                        const bf16* A, const float* Wf, const bf16* Wb,
                        const float* bias, bf16* C, int Nc, int K,
                        const float* g, const float* b, const float* m, const float* v,
                        hipStream_t s)
{
    dim3 blk(256);
    if (wb16) {
        switch (epi) {
        case 0: k_mgemm<0, true><<<grid, blk, 0, s>>>(A, Wf, Wb, bias, C, Nc, K, g, b, m, v); break;
        case 1: k_mgemm<1, true><<<grid, blk, 0, s>>>(A, Wf, Wb, bias, C, Nc, K, g, b, m, v); break;
        default: k_mgemm<3, true><<<grid, blk, 0, s>>>(A, Wf, Wb, bias, C, Nc, K, g, b, m, v); break;
        }
    } else {
        switch (epi) {
        case 0: k_mgemm<0, false><<<grid, blk, 0, s>>>(A, Wf, Wb, bias, C, Nc, K, g, b, m, v); break;
        case 1: k_mgemm<1, false><<<grid, blk, 0, s>>>(A, Wf, Wb, bias, C, Nc, K, g, b, m, v); break;
        default: k_mgemm<3, false><<<grid, blk, 0, s>>>(A, Wf, Wb, bias, C, Nc, K, g, b, m, v); break;
        }
    }
}

extern "C" void kernel_launch(void* const* d_in, const int* in_sizes, int n_in,
                              void* d_out, int out_size, void* d_ws, size_t ws_size,
                              hipStream_t stream)
{
    const float* query        = (const float*)d_in[0];
    const float* memory       = (const float*)d_in[1];
    const float* pos_local    = (const float*)d_in[2];
    const float* pos_temporal = (const float*)d_in[3];
    const float* pos_ts       = (const float*)d_in[4];
    const float* ln_g[5] = {(const float*)d_in[5], (const float*)d_in[7], (const float*)d_in[9], (const float*)d_in[11], (const float*)d_in[13]};
    const float* ln_b[5] = {(const float*)d_in[6], (const float*)d_in[8], (const float*)d_in[10], (const float*)d_in[12], (const float*)d_in[14]};
    const float* sa_w_in  = (const float*)d_in[15]; const float* sa_b_in  = (const float*)d_in[16];
    const float* sa_w_out = (const float*)d_in[17]; const float* sa_b_out = (const float*)d_in[18];
    const float* ta_w_in  = (const float*)d_in[19]; const float* ta_b_in  = (const float*)d_in[20];
    const float* ta_w_out = (const float*)d_in[21]; const float* ta_b_out = (const float*)d_in[22];
    const float* ca_w_in  = (const float*)d_in[23]; const float* ca_b_in  = (const float*)d_in[24];
    const float* ca_w_out = (const float*)d_in[25]; const float* ca_b_out = (const float*)d_in[26];
    const float* fc1_w = (const float*)d_in[27]; const float* fc1_b = (const float*)d_in[28];
    const float* dw_w  = (const float*)d_in[29]; const float* dw_b  = (const float*)d_in[30];
    const float* fc2_w = (const float*)d_in[31]; const float* fc2_b = (const float*)d_in[32];
    const float* bn1g = (const float*)d_in[33], *bn1b = (const float*)d_in[34], *bn1m = (const float*)d_in[35], *bn1v = (const float*)d_in[36];
    const float* bn2g = (const float*)d_in[37], *bn2b = (const float*)d_in[38], *bn2m = (const float*)d_in[39], *bn2v = (const float*)d_in[40];
    const float* bn3g = (const float*)d_in[41], *bn3b = (const float*)d_in[42], *bn3m = (const float*)d_in[43], *bn3v = (const float*)d_in[44];
    const float* lin1_w = (const float*)d_in[45]; const float* lin1_b = (const float*)d_in[46];
    const float* lin2_w = (const float*)d_in[47]; const float* lin2_b = (const float*)d_in[48];

    dim3 blk(256);
    int gMC = (int)(MC / 256);

    size_t need_small = MC * 4 + 4 * MC * 2;
    size_t need_big   = need_small + WTOT * 2;
    if (ws_size < need_small) {
        k_fill<<<gMC, blk, 0, stream>>>((float*)d_out, 700.f, MC);
        return;
    }
    bool wb16 = (ws_size >= need_big);

    float* X = (float*)d_ws;
    bf16* B0 = (bf16*)((char*)d_ws + MC * 4);
    bf16* B1 = B0 + MC;
    bf16* B2 = B1 + MC;
    bf16* B3 = B2 + MC;
    bf16* WB = B3 + MC;
    const float* nulf = nullptr;
    bf16* nulm = nullptr;

    // bf16 weight views (valid only when wb16)
    bf16* wb_sa_in  = WB + 0;
    bf16* wb_sa_out = WB + 786432;
    bf16* wb_ta_in  = WB + 1048576;
    bf16* wb_ta_out = WB + 1835008;
    bf16* wb_ca_in  = WB + 2097152;
    bf16* wb_ca_out = WB + 2883584;
    bf16* wb_fc1    = WB + 3145728;
    bf16* wb_fc2    = WB + 4194304;
    bf16* wb_lin1   = WB + 5242880;
    bf16* wb_lin2   = WB + 6291456;

    if (wb16) {
        k_cvtw<<<(int)((WTOT + 255) / 256), blk, 0, stream>>>(WB,
            sa_w_in, sa_w_out, ta_w_in, ta_w_out, ca_w_in, ca_w_out,
            fc1_w, fc2_w, lin1_w, lin2_w);
    }

    hipMemcpyAsync(X, query, MC * sizeof(float), hipMemcpyDeviceToDevice, stream);

    // ---- stage 1: spatial window MHSA (L=S=64, Bc=320) ----
    k_ln2<<<MTOK, 64, 0, stream>>>(X, B0, B1, ln_g[0], ln_b[0], pos_local, 0, 1);
    launch_gemm(0, wb16, dim3(4, 160), B1, sa_w_in,          wb_sa_in,          sa_b_in,        B2, 512, 512, nulf, nulf, nulf, nulf, stream);
    launch_gemm(0, wb16, dim3(4, 160), B1, sa_w_in + 262144, wb_sa_in + 262144, sa_b_in + 512,  B3, 512, 512, nulf, nulf, nulf, nulf, stream);
    launch_gemm(0, wb16, dim3(4, 160), B0, sa_w_in + 524288, wb_sa_in + 524288, sa_b_in + 1024, B1, 512, 512, nulf, nulf, nulf, nulf, stream);
    k_fattn<<<dim3(320 * NHEAD, 1), blk, 0, stream>>>(B2, B3, B1, B0, 64, 64, 320);
    launch_gemm(0, wb16, dim3(4, 160), B0, sa_w_out, wb_sa_out, sa_b_out, B2, 512, 512, nulf, nulf, nulf, nulf, stream);
    k_unperm_add<<<gMC, blk, 0, stream>>>(X, B2, 1);

    // ---- stage 2: MlpDWBN, chunked over 5120-token slabs (20 planes) ----
    k_ln2<<<MTOK, 64, 0, stream>>>(X, B0, nulm, ln_g[1], ln_b[1], nulf, 0, 0);
    for (int c = 0; c < 4; ++c) {
        int off = c * 5120;
        launch_gemm(1, wb16, dim3(16, 40), B0 + (size_t)off * CC, fc1_w, wb_fc1, fc1_b, B1, 2048, 512,
                    bn1g, bn1b, bn1m, bn1v, stream);
        k_dwc<<<40960, blk, 0, stream>>>(B1, B3, dw_w, dw_b, bn2g, bn2b, bn2m, bn2v, 5120);
        launch_gemm(1, wb16, dim3(4, 40), B3, fc2_w, wb_fc2, fc2_b, B2 + (size_t)off * CC, 512, 2048,
                    bn3g, bn3b, bn3m, bn3v, stream);
    }
    k_add<<<gMC, blk, 0, stream>>>(X, B2, MC);

    // ---- stage 3: temporal MHSA (T=10: scalar path, small-S LDS) ----
    k_ln2<<<MTOK, 64, 0, stream>>>(X, B0, B1, ln_g[2], ln_b[2], pos_temporal, 0, 3);
    launch_gemm(0, wb16, dim3(4, 160), B1, ta_w_in,          wb_ta_in,          ta_b_in,        B2, 512, 512, nulf, nulf, nulf, nulf, stream);
    launch_gemm(0, wb16, dim3(4, 160), B1, ta_w_in + 262144, wb_ta_in + 262144, ta_b_in + 512,  B3, 512, 512, nulf, nulf, nulf, nulf, stream);
    launch_gemm(0, wb16, dim3(4, 160), B0, ta_w_in + 524288, wb_ta_in + 524288, ta_b_in + 1024, B1, 512, 512, nulf, nulf, nulf, nulf, stream);
    k_attn<32><<<dim3(2048 * NHEAD, 1), blk, 0, stream>>>(B2, B3, B1, B0, 10, 10, 2048);
    launch_gemm(0, wb16, dim3(4, 160), B0, ta_w_out, wb_ta_out, ta_b_out, B2, 512, 512, nulf, nulf, nulf, nulf, stream);
    k_unperm_add<<<gMC, blk, 0, stream>>>(X, B2, 3);

    // ---- stage 4: temporal-spatial cross-attention (L=S=640, Bc=32: MFMA flash) ----
    k_ln2<<<MTOK, 64, 0, stream>>>(X, nulm, B1, ln_g[3], ln_b[3], pos_ts, 640, 4);
    launch_gemm(0, wb16, dim3(4, 160), B1, ca_w_in, wb_ca_in, ca_b_in, B2, 512, 512, nulf, nulf, nulf, nulf, stream);
    k_permmem<<<gMC, blk, 0, stream>>>(memory, B1, pos_ts, 0);
    launch_gemm(0, wb16, dim3(4, 160), B1, ca_w_in + 262144, wb_ca_in + 262144, ca_b_in + 512, B3, 512, 512, nulf, nulf, nulf, nulf, stream);
    k_permmem<<<gMC, blk, 0, stream>>>(memory, B1, nulf, 0);
    launch_gemm(0, wb16, dim3(4, 160), B1, ca_w_in + 524288, wb_ca_in + 524288, ca_b_in + 1024, B0, 512, 512, nulf, nulf, nulf, nulf, stream);
    k_fattn<<<dim3(32 * NHEAD, 10), blk, 0, stream>>>(B2, B3, B0, B1, 640, 640, 32);
    launch_gemm(0, wb16, dim3(4, 160), B1, ca_w_out, wb_ca_out, ca_b_out, B2, 512, 512, nulf, nulf, nulf, nulf, stream);
    k_unperm_add<<<gMC, blk, 0, stream>>>(X, B2, 4);

    // ---- stage 5: final FFN, chunked over 5120-token slabs ----
    k_ln2<<<MTOK, 64, 0, stream>>>(X, B0, nulm, ln_g[4], ln_b[4], nulf, 0, 0);
    for (int c = 0; c < 4; ++c) {
        int off = c * 5120;
        launch_gemm(3, wb16, dim3(16, 40), B0 + (size_t)off * CC, lin1_w, wb_lin1, lin1_b, B1, 2048, 512,
                    nulf, nulf, nulf, nulf, stream);
        launch_gemm(0, wb16, dim3(4, 40), B1, lin2_w, wb_lin2, lin2_b, B2 + (size_t)off * CC, 512, 2048,
                    nulf, nulf, nulf, nulf, stream);
    }
    k_final<<<gMC, blk, 0, stream>>>(X, B2, (float*)d_out, MC);
}

// Round 4
// 1820.202 us; speedup vs baseline: 2.9274x; 1.0510x over previous
//
#include <hip/hip_runtime.h>
#include <hip/hip_bf16.h>
#include <math.h>

typedef __hip_bfloat16 bf16;
typedef unsigned int u32;
typedef __attribute__((ext_vector_type(8))) short bf16x8v;
typedef __attribute__((ext_vector_type(4))) float f32x4v;

static constexpr int NB = 8, TT = 10, HH = 16, WW = 16, CC = 512;
static constexpr int NHEAD = 8, HIDN = 2048;
static constexpr int MTOK = NB * TT * HH * WW;          // 20480 tokens
static constexpr size_t MC = (size_t)MTOK * CC;         // 10485760
static constexpr size_t HC = (size_t)MTOK * HIDN;       // 41943040
static constexpr float LNEPS = 1e-5f;
static constexpr float ATTSCALE = 0.125f;               // 1/sqrt(64)
static constexpr size_t WTOT = 7340032;                 // total weight elems pre-converted to bf16

static __device__ __forceinline__ float gelu_f(float x) {
    return 0.5f * x * (1.0f + erff(x * 0.70710678118654752f));
}

static __device__ __forceinline__ float bf2f(short s) {
    union { u32 u; float f; } c; c.u = ((u32)(unsigned short)s) << 16; return c.f;
}

// direct global->LDS async copy, 16B per lane; LDS dest = wave-uniform base + lane*16
static __device__ __forceinline__ void gl_lds16(const void* g, void* l)
{
    __builtin_amdgcn_global_load_lds((const __attribute__((address_space(1))) u32*)g,
                                     (__attribute__((address_space(3))) u32*)l, 16, 0, 0);
}

// ---------------- ws-too-small diagnostic ----------------
__global__ __launch_bounds__(256) void k_fill(float* __restrict__ out, float v, size_t n)
{
    size_t i = (size_t)blockIdx.x * 256 + threadIdx.x;
    if (i < n) out[i] = v;
}

// ---------------- one-shot fp32 -> bf16 weight conversion (28 segments of 262144) ----------------
__global__ __launch_bounds__(256) void k_cvtw(bf16* __restrict__ out,
    const float* __restrict__ p0, const float* __restrict__ p1, const float* __restrict__ p2,
    const float* __restrict__ p3, const float* __restrict__ p4, const float* __restrict__ p5,
    const float* __restrict__ p6, const float* __restrict__ p7, const float* __restrict__ p8,
    const float* __restrict__ p9)
{
    size_t id = (size_t)blockIdx.x * 256 + threadIdx.x;
    if (id >= WTOT) return;
    int sid = (int)(id >> 18);                 // /262144
    const float* base; size_t lo;
    if (sid < 3)       { base = p0; lo = id; }
    else if (sid < 4)  { base = p1; lo = id - (size_t)3  * 262144; }
    else if (sid < 7)  { base = p2; lo = id - (size_t)4  * 262144; }
    else if (sid < 8)  { base = p3; lo = id - (size_t)7  * 262144; }
    else if (sid < 11) { base = p4; lo = id - (size_t)8  * 262144; }
    else if (sid < 12) { base = p5; lo = id - (size_t)11 * 262144; }
    else if (sid < 16) { base = p6; lo = id - (size_t)12 * 262144; }
    else if (sid < 20) { base = p7; lo = id - (size_t)16 * 262144; }
    else if (sid < 24) { base = p8; lo = id - (size_t)20 * 262144; }
    else               { base = p9; lo = id - (size_t)24 * 262144; }
    out[id] = __float2bfloat16(base[lo]);
}

// ---------------- fused LayerNorm (+permute, +pos); X fp32, dst bf16 ----------------
__global__ __launch_bounds__(64) void k_ln2(const float* __restrict__ X, bf16* __restrict__ dstA,
                                            bf16* __restrict__ dstB,
                                            const float* __restrict__ g, const float* __restrict__ b,
                                            const float* __restrict__ pos, int posoff, int mode)
{
    int m = blockIdx.x;
    int lane = threadIdx.x;
    const float* row = X + (size_t)m * CC;
    float v[8], s = 0.f, s2 = 0.f;
#pragma unroll
    for (int i = 0; i < 8; ++i) { v[i] = row[lane + i * 64]; s += v[i]; s2 += v[i] * v[i]; }
#pragma unroll
    for (int msk = 1; msk < 64; msk <<= 1) { s += __shfl_xor(s, msk); s2 += __shfl_xor(s2, msk); }
    float mean = s * (1.f / 512.f);
    float var  = fmaxf(s2 * (1.f / 512.f) - mean * mean, 0.f);
    float rr = rsqrtf(var + LNEPS);

    int r, pr = 0;
    if (mode == 0) { r = m; }
    else if (mode == 1) {
        int nt = m >> 8, hw = m & 255, h = hw >> 4, w = hw & 15;
        int l = (h & 7) * 8 + (w & 7);
        r = l * 320 + nt * 4 + (h >> 3) * 2 + (w >> 3);
        pr = l;
    } else if (mode == 3) {
        int n = m / 2560, rem = m - n * 2560;
        int t = rem >> 8;
        r = t * 2048 + n * 256 + (rem & 255);
        pr = t;
    } else {
        int n = m / 2560, rem = m - n * 2560;
        int t = rem >> 8, hw = rem & 255, h = hw >> 4, w = hw & 15;
        int ij = (h & 7) * 8 + (w & 7);
        r = (t * 64 + ij) * 32 + n * 4 + (h >> 3) * 2 + (w >> 3);
        pr = t * 64 + ij;
    }
#pragma unroll
    for (int i = 0; i < 8; ++i) {
        int c = lane + i * 64;
        float y = (v[i] - mean) * rr * g[c] + b[c];
        if (dstA) dstA[(size_t)r * CC + c] = __float2bfloat16(y);
        if (dstB) dstB[(size_t)r * CC + c] = __float2bfloat16(y + pos[(size_t)(posoff + pr) * CC + c]);
    }
}

// ---------------- gather-permute of fp32 `memory` into ts layout (+optional pos) ----------------
__global__ __launch_bounds__(256) void k_permmem(const float* __restrict__ in, bf16* __restrict__ out,
                                                 const float* __restrict__ pos, int posoff)
{
    size_t id = (size_t)blockIdx.x * 256 + threadIdx.x;
    if (id >= MC) return;
    int c = (int)(id & 511);
    int r = (int)(id >> 9);
    int b = r & 31, s = r >> 5;
    int t = s >> 6, ij = s & 63;
    int i = ij >> 3, j = ij & 7;
    int n = b >> 2, qh = (b >> 1) & 1, qw = b & 1;
    int m = (n * 10 + t) * 256 + (qh * 8 + i) * 16 + qw * 8 + j;
    float v = in[(size_t)m * CC + c];
    if (pos) v += pos[(size_t)(posoff + t * 64 + ij) * CC + c];
    out[id] = __float2bfloat16(v);
}

// ---------------- reverse permute + residual add into fp32 X ----------------
__global__ __launch_bounds__(256) void k_unperm_add(float* __restrict__ X, const bf16* __restrict__ Tb, int mode)
{
    size_t id = (size_t)blockIdx.x * 256 + threadIdx.x;
    if (id >= MC) return;
    int c = (int)(id & 511);
    int m = (int)(id >> 9);
    int r;
    if (mode == 1) {
        int nt = m >> 8, hw = m & 255;
        int h = hw >> 4, w = hw & 15;
        r = ((h & 7) * 8 + (w & 7)) * 320 + nt * 4 + (h >> 3) * 2 + (w >> 3);
    } else if (mode == 3) {
        int n = m / 2560, rem = m - n * 2560;
        r = (rem >> 8) * 2048 + n * 256 + (rem & 255);
    } else {
        int n = m / 2560, rem = m - n * 2560;
        int t = rem >> 8, hw = rem & 255;
        int h = hw >> 4, w = hw & 15;
        r = (t * 64 + (h & 7) * 8 + (w & 7)) * 32 + n * 4 + (h >> 3) * 2 + (w >> 3);
    }
    X[id] += (float)Tb[(size_t)r * CC + c];
}

__global__ __launch_bounds__(256) void k_add(float* __restrict__ X, const bf16* __restrict__ Y, size_t n)
{
    size_t i = (size_t)blockIdx.x * 256 + threadIdx.x;
    if (i < n) X[i] += (float)Y[i];
}

// ---------------- final residual add: FLOAT32 output ----------------
__global__ __launch_bounds__(256) void k_final(const float* __restrict__ X, const bf16* __restrict__ F,
                                               float* __restrict__ out, size_t n)
{
    size_t i = (size_t)blockIdx.x * 256 + threadIdx.x;
    if (i < n) out[i] = X[i] + (float)F[i];
}

// ---------------- MFMA GEMM: C = A(bf16, M x K) @ W(Nc_w x K)^T + bias; out bf16 ----------------
// 128x128 tile, BK=32, 4 waves each computing a 64x64 quadrant via 16 x mfma_f32_16x16x32_bf16.
// WB16=true: bf16 weights, staging via global_load_lds width-16 into linear [128][32] LDS.
// WB16=false: fp32 weights, register staging + in-loop convert, padded [128][40] LDS.
// EPI 0: bias.  1: bias+BN+GELU.  3: bias+GELU.
// Split output: if nsplit>0, blocks with bn>=nsplit write to Cout2 at col n-nsplit (stride Nc).
template<int EPI, bool WB16>
__global__ __launch_bounds__(256) void k_mgemm(const bf16* __restrict__ A, const float* __restrict__ Wf,
                                               const bf16* __restrict__ Wb,
                                               const float* __restrict__ bias, bf16* __restrict__ Cout,
                                               bf16* __restrict__ Cout2, int nsplit,
                                               int Nc, int K,
                                               const float* __restrict__ bng, const float* __restrict__ bnb,
                                               const float* __restrict__ bnm, const float* __restrict__ bnv)
{
    __shared__ short smem[WB16 ? 2 * 128 * 32 : 2 * 128 * 40];
    constexpr int LDW = WB16 ? 32 : 40;           // LDS row stride (shorts)
    short* As = smem;
    short* Bs = smem + 128 * LDW;

    int bm = blockIdx.y * 128, bn = blockIdx.x * 128;
    int tid = threadIdx.x;
    int lane = tid & 63, wave = tid >> 6;
    int wm = (wave & 1) * 64, wn = (wave >> 1) * 64;
    int fr = lane & 15;      // frag row (A) / col (B,D)
    int fq = lane >> 4;      // quad: k-offset fq*8 (A,B), row-offset fq*4 (D)

    bf16* co = Cout; int noff = 0;
    if (nsplit > 0 && bn >= nsplit) { co = Cout2; noff = nsplit; }

    f32x4v acc[4][4];
#pragma unroll
    for (int i = 0; i < 4; ++i)
#pragma unroll
        for (int j = 0; j < 4; ++j) acc[i][j] = (f32x4v){0.f, 0.f, 0.f, 0.f};

    if constexpr (WB16) {
        int srow = wave * 32 + (lane >> 2);
        int scol = (lane & 3) * 8;
        const bf16* aptr = A  + (size_t)(bm + srow) * K + scol;
        const bf16* bptr = Wb + (size_t)(bn + srow) * K + scol;
        const size_t row16 = (size_t)16 * K;
        short* asl = &As[wave * 1024];
        short* bsl = &Bs[wave * 1024];

        for (int k0 = 0; k0 < K; k0 += 32) {
            gl_lds16(aptr + k0,         asl);
            gl_lds16(aptr + row16 + k0, asl + 512);
            gl_lds16(bptr + k0,         bsl);
            gl_lds16(bptr + row16 + k0, bsl + 512);
            __syncthreads();            // drains vmcnt -> LDS tiles complete
            bf16x8v af[4], bfr[4];
#pragma unroll
            for (int mi = 0; mi < 4; ++mi) af[mi]  = *(bf16x8v*)&As[(wm + mi * 16 + fr) * 32 + fq * 8];
#pragma unroll
            for (int ni = 0; ni < 4; ++ni) bfr[ni] = *(bf16x8v*)&Bs[(wn + ni * 16 + fr) * 32 + fq * 8];
#pragma unroll
            for (int mi = 0; mi < 4; ++mi)
#pragma unroll
                for (int ni = 0; ni < 4; ++ni)
                    acc[mi][ni] = __builtin_amdgcn_mfma_f32_16x16x32_bf16(af[mi], bfr[ni], acc[mi][ni], 0, 0, 0);
            __syncthreads();
        }
    } else {
        for (int k0 = 0; k0 < K; k0 += 32) {
#pragma unroll
            for (int i = 0; i < 2; ++i) {
                int v = tid * 2 + i;                 // 0..511
                int m = v >> 2, kk = (v & 3) * 8;
                *(uint4*)&As[m * LDW + kk] = *(const uint4*)&A[(size_t)(bm + m) * K + k0 + kk];
                float4 w0 = *(const float4*)&Wf[(size_t)(bn + m) * K + k0 + kk];
                float4 w1 = *(const float4*)&Wf[(size_t)(bn + m) * K + k0 + kk + 4];
                union { bf16 h[8]; uint4 u; } t;
                t.h[0] = __float2bfloat16(w0.x); t.h[1] = __float2bfloat16(w0.y);
                t.h[2] = __float2bfloat16(w0.z); t.h[3] = __float2bfloat16(w0.w);
                t.h[4] = __float2bfloat16(w1.x); t.h[5] = __float2bfloat16(w1.y);
                t.h[6] = __float2bfloat16(w1.z); t.h[7] = __float2bfloat16(w1.w);
                *(uint4*)&Bs[m * LDW + kk] = t.u;
            }
            __syncthreads();
            bf16x8v af[4], bfr[4];
#pragma unroll
            for (int mi = 0; mi < 4; ++mi) af[mi]  = *(bf16x8v*)&As[(wm + mi * 16 + fr) * LDW + fq * 8];
#pragma unroll
            for (int ni = 0; ni < 4; ++ni) bfr[ni] = *(bf16x8v*)&Bs[(wn + ni * 16 + fr) * LDW + fq * 8];
#pragma unroll
            for (int mi = 0; mi < 4; ++mi)
#pragma unroll
                for (int ni = 0; ni < 4; ++ni)
                    acc[mi][ni] = __builtin_amdgcn_mfma_f32_16x16x32_bf16(af[mi], bfr[ni], acc[mi][ni], 0, 0, 0);
            __syncthreads();
        }
    }

#pragma unroll
    for (int mi = 0; mi < 4; ++mi)
#pragma unroll
        for (int ni = 0; ni < 4; ++ni)
#pragma unroll
            for (int r = 0; r < 4; ++r) {
                int m = bm + wm + mi * 16 + fq * 4 + r;
                int n = bn + wn + ni * 16 + fr;
                float v = acc[mi][ni][r] + bias[n];
                if constexpr (EPI == 1) {
                    v = (v - bnm[n]) * rsqrtf(bnv[n] + LNEPS) * bng[n] + bnb[n];
                    v = gelu_f(v);
                }
                if constexpr (EPI == 3) v = gelu_f(v);
                co[(size_t)m * Nc + (n - noff)] = __float2bfloat16(v);
            }
}

// ---------------- elementwise dwconv3x3 + BN2 + GELU over an ntok-token chunk ----------------
__global__ __launch_bounds__(256) void k_dwc(const bf16* __restrict__ H1c, bf16* __restrict__ H2c,
                                             const float* __restrict__ dww, const float* __restrict__ dwb,
                                             const float* __restrict__ g2, const float* __restrict__ b2,
                                             const float* __restrict__ m2, const float* __restrict__ v2,
                                             int ntok)
{
    size_t id = (size_t)blockIdx.x * 256 + threadIdx.x;
    if (id >= (size_t)ntok * HIDN) return;
    int k = (int)(id & 2047);
    int lm = (int)(id >> 11);
    int p = lm >> 8, hw = lm & 255, h = hw >> 4, w = hw & 15;
    float a = dwb[k];
#pragma unroll
    for (int dh = -1; dh <= 1; ++dh) {
        int h2 = h + dh;
        if (h2 < 0 || h2 > 15) continue;
#pragma unroll
        for (int dw = -1; dw <= 1; ++dw) {
            int w2 = w + dw;
            if (w2 < 0 || w2 > 15) continue;
            a += (float)H1c[(((size_t)p * 16 + h2) * 16 + w2) * HIDN + k]
               * dww[k * 9 + (dh + 1) * 3 + (dw + 1)];
        }
    }
    float xn = (a - m2[k]) * rsqrtf(v2[k] + LNEPS) * g2[k] + b2[k];
    H2c[id] = __float2bfloat16(gelu_f(xn));
}

// ---------------- temporal attention, L=S=10, d=64, one (b,h) per wave ----------------
// grid = 16384/4 blocks of 256. Lane = (quad = q-subrow, slot = s / d-slice).
__global__ __launch_bounds__(256) void k_tattn(const bf16* __restrict__ Q, const bf16* __restrict__ K,
                                               const bf16* __restrict__ V, bf16* __restrict__ O)
{
    __shared__ short sQ[4][10][72];
    __shared__ short sK[4][10][72];
    __shared__ short sV[4][10][72];
    int tid = threadIdx.x, wv = tid >> 6, l = tid & 63;
    int p = blockIdx.x * 4 + wv;
    int b = p >> 3, h = p & 7;
    const size_t base = (size_t)b * CC + h * 64;      // row r at base + r*2048*CC

    int cr = l >> 3, ccx = (l & 7) * 8;
#pragma unroll
    for (int i = 0; i < 2; ++i) {
        int r = cr + i * 8;
        if (r < 10) {
            size_t g = base + (size_t)r * 2048 * CC + ccx;
            *(uint4*)&sQ[wv][r][ccx] = *(const uint4*)&Q[g];
            *(uint4*)&sK[wv][r][ccx] = *(const uint4*)&K[g];
            *(uint4*)&sV[wv][r][ccx] = *(const uint4*)&V[g];
        }
    }
    __syncthreads();

    int slot = l & 15, quad = l >> 4;
#pragma unroll
    for (int qo = 0; qo < 3; ++qo) {
        int q = qo * 4 + quad;                        // 0..11
        int qc = q < 10 ? q : 0;
        float acc = 0.f;
        int sc = slot < 10 ? slot : 0;
#pragma unroll
        for (int dd = 0; dd < 8; ++dd) {
            bf16x8v qv = *(bf16x8v*)&sQ[wv][qc][dd * 8];
            bf16x8v kv = *(bf16x8v*)&sK[wv][sc][dd * 8];
#pragma unroll
            for (int j = 0; j < 8; ++j) acc += bf2f(qv[j]) * bf2f(kv[j]);
        }
        float S = (slot < 10 && q < 10) ? acc * ATTSCALE : -1e30f;
        float mx = S;
#pragma unroll
        for (int msk = 1; msk < 16; msk <<= 1) mx = fmaxf(mx, __shfl_xor(mx, msk));
        float e = (slot < 10 && q < 10) ? __expf(S - mx) : 0.f;
        float sum = e;
#pragma unroll
        for (int msk = 1; msk < 16; msk <<= 1) sum += __shfl_xor(sum, msk);
        float inv = 1.f / fmaxf(sum, 1e-20f);

        float o0 = 0.f, o1 = 0.f, o2 = 0.f, o3 = 0.f;
#pragma unroll
        for (int s = 0; s < 10; ++s) {
            float ps = __shfl(e, (l & 48) | s);
            uint2 vv = *(uint2*)&sV[wv][s][slot * 4];
            const short* vs = (const short*)&vv;
            o0 += ps * bf2f(vs[0]);
            o1 += ps * bf2f(vs[1]);
            o2 += ps * bf2f(vs[2]);
            o3 += ps * bf2f(vs[3]);
        }
        if (q < 10) {
            union { ushort us[4]; uint2 u; } pk;
            union { bf16 hh; ushort uu; } cv;
            cv.hh = __float2bfloat16(o0 * inv); pk.us[0] = cv.uu;
            cv.hh = __float2bfloat16(o1 * inv); pk.us[1] = cv.uu;
            cv.hh = __float2bfloat16(o2 * inv); pk.us[2] = cv.uu;
            cv.hh = __float2bfloat16(o3 * inv); pk.us[3] = cv.uu;
            *(uint2*)&O[base + (size_t)q * 2048 * CC + slot * 4] = pk.u;
        }
    }
}

// ---------------- MFMA flash attention: requires L%64==0, S%64==0, d=64 ----------------
// grid.x = Bc*NHEAD (b*8+h), grid.y = L/64. 256 threads = 4 waves, wave w owns q rows w*16..w*16+15.
// sVt swizzle: off(d,s) = d*64 + (s ^ ((((d>>3)^(d&7))&7)<<3)).
__global__ __launch_bounds__(256) void k_fattn(const bf16* __restrict__ Q, const bf16* __restrict__ K,
                                               const bf16* __restrict__ V, bf16* __restrict__ O,
                                               int L, int S, int Bc)
{
    __shared__ short sK[64][72];        // [s][d] bf16, stride 72
    __shared__ short sVt[64 * 64];      // [d][s] bf16, swizzled
    __shared__ short sP[4][16][40];     // per-wave P bounce

    int b = blockIdx.x >> 3;
    int h = blockIdx.x & 7;
    int q0 = blockIdx.y * 64;
    int tid = threadIdx.x;
    int wv = tid >> 6;
    int lane = tid & 63;
    int fr = lane & 15;
    int fq = lane >> 4;

    const bf16* qp = Q + ((size_t)(q0 + wv * 16 + fr) * Bc + b) * CC + h * 64 + fq * 8;
    bf16x8v qf0 = *(const bf16x8v*)qp;
    bf16x8v qf1 = *(const bf16x8v*)(qp + 32);

    f32x4v oacc[4];
#pragma unroll
    for (int i = 0; i < 4; ++i) oacc[i] = (f32x4v){0.f, 0.f, 0.f, 0.f};
    float m_run[4] = {-1e30f, -1e30f, -1e30f, -1e30f};
    float l_run[4] = {0.f, 0.f, 0.f, 0.f};

    int ks = tid >> 2, kd0 = (tid & 3) * 16;
    int vd0 = (tid & 7) * 8, vs2 = (tid >> 3) * 2;

    for (int s0 = 0; s0 < S; s0 += 64) {
        __syncthreads();
        {
            const bf16* kp = K + ((size_t)(s0 + ks) * Bc + b) * CC + h * 64 + kd0;
            *(uint4*)&sK[ks][kd0]     = *(const uint4*)kp;
            *(uint4*)&sK[ks][kd0 + 8] = *(const uint4*)(kp + 8);
        }
        {
            const bf16* vp0 = V + ((size_t)(s0 + vs2) * Bc + b) * CC + h * 64 + vd0;
            const bf16* vp1 = vp0 + (size_t)Bc * CC;
            uint4 va = *(const uint4*)vp0;
            uint4 vb = *(const uint4*)vp1;
            const ushort* as = (const ushort*)&va;
            const ushort* bs = (const ushort*)&vb;
#pragma unroll
            for (int j = 0; j < 8; ++j) {
                int dd = vd0 + j;
                int sw = vs2 ^ (((( dd >> 3) ^ (dd & 7)) & 7) << 3);
                *(uint*)&sVt[dd * 64 + sw] = (uint)as[j] | ((uint)bs[j] << 16);
            }
        }
        __syncthreads();

        f32x4v sc[4];
#pragma unroll
        for (int nt = 0; nt < 4; ++nt) {
            bf16x8v k0 = *(bf16x8v*)&sK[nt * 16 + fr][fq * 8];
            bf16x8v k1 = *(bf16x8v*)&sK[nt * 16 + fr][32 + fq * 8];
            f32x4v z = (f32x4v){0.f, 0.f, 0.f, 0.f};
            z = __builtin_amdgcn_mfma_f32_16x16x32_bf16(qf0, k0, z, 0, 0, 0);
            z = __builtin_amdgcn_mfma_f32_16x16x32_bf16(qf1, k1, z, 0, 0, 0);
            sc[nt] = z;
        }

        short (*sPw)[40] = sP[wv];
#pragma unroll
        for (int r = 0; r < 4; ++r) {
            float mx = fmaxf(fmaxf(sc[0][r], sc[1][r]), fmaxf(sc[2][r], sc[3][r])) * ATTSCALE;
#pragma unroll
            for (int msk = 1; msk < 16; msk <<= 1) mx = fmaxf(mx, __shfl_xor(mx, msk));
            float mnew = fmaxf(m_run[r], mx);
            float alpha = __expf(m_run[r] - mnew);
            m_run[r] = mnew;
            float rs = 0.f;
#pragma unroll
            for (int nt = 0; nt < 4; ++nt) {
                float p = __expf(sc[nt][r] * ATTSCALE - mnew);
                union { bf16 hh; ushort uu; } cv;
                cv.hh = __float2bfloat16(p);
                rs += __bfloat162float(cv.hh);
                sPw[fq * 4 + r][fr + 16 * nt] = (short)cv.uu;
            }
#pragma unroll
            for (int msk = 1; msk < 16; msk <<= 1) rs += __shfl_xor(rs, msk);
            l_run[r] = l_run[r] * alpha + rs;
#pragma unroll
            for (int nt2 = 0; nt2 < 4; ++nt2) oacc[nt2][r] *= alpha;
        }
        __syncthreads();

        bf16x8v pa0 = *(bf16x8v*)&sPw[fr][fq * 8];
        bf16x8v pa1 = *(bf16x8v*)&sPw[fr][32 + fq * 8];
#pragma unroll
        for (int nt2 = 0; nt2 < 4; ++nt2) {
            int vr = nt2 * 16 + fr;
            int vx = (((vr >> 3) ^ (vr & 7)) & 7) << 3;
            bf16x8v v0 = *(bf16x8v*)&sVt[vr * 64 + ((fq * 8) ^ vx)];
            bf16x8v v1 = *(bf16x8v*)&sVt[vr * 64 + ((32 + fq * 8) ^ vx)];
            oacc[nt2] = __builtin_amdgcn_mfma_f32_16x16x32_bf16(pa0, v0, oacc[nt2], 0, 0, 0);
            oacc[nt2] = __builtin_amdgcn_mfma_f32_16x16x32_bf16(pa1, v1, oacc[nt2], 0, 0, 0);
        }
    }

#pragma unroll
    for (int r = 0; r < 4; ++r) {
        float inv = 1.f / fmaxf(l_run[r], 1e-20f);
        bf16* op = O + ((size_t)(q0 + wv * 16 + fq * 4 + r) * Bc + b) * CC + h * 64 + fr;
#pragma unroll
        for (int nt2 = 0; nt2 < 4; ++nt2)
            op[nt2 * 16] = __float2bfloat16(oacc[nt2][r] * inv);
    }
}

// ---------------- host-side GEMM dispatcher ----------------
static void launch_gemm(int epi, bool wb16, dim3 grid,
                        const bf16* A, const float* Wf, const bf16* Wb,
                        const float* bias, bf16* C, bf16* C2, int nsplit, int Nc, int K,
                        const float* g, const float* b, const float* m, const float* v,
                        hipStream_t s)
{
    dim3 blk(256);
    if (wb16) {
        switch (epi) {
        case 0: k_mgemm<0, true><<<grid, blk, 0, s>>>(A, Wf, Wb, bias, C, C2, nsplit, Nc, K, g, b, m, v); break;
        case 1: k_mgemm<1, true><<<grid, blk, 0, s>>>(A, Wf, Wb, bias, C, C2, nsplit, Nc, K, g, b, m, v); break;
        default: k_mgemm<3, true><<<grid, blk, 0, s>>>(A, Wf, Wb, bias, C, C2, nsplit, Nc, K, g, b, m, v); break;
        }
    } else {
        switch (epi) {
        case 0: k_mgemm<0, false><<<grid, blk, 0, s>>>(A, Wf, Wb, bias, C, C2, nsplit, Nc, K, g, b, m, v); break;
        case 1: k_mgemm<1, false><<<grid, blk, 0, s>>>(A, Wf, Wb, bias, C, C2, nsplit, Nc, K, g, b, m, v); break;
        default: k_mgemm<3, false><<<grid, blk, 0, s>>>(A, Wf, Wb, bias, C, C2, nsplit, Nc, K, g, b, m, v); break;
        }
    }
}

extern "C" void kernel_launch(void* const* d_in, const int* in_sizes, int n_in,
                              void* d_out, int out_size, void* d_ws, size_t ws_size,
                              hipStream_t stream)
{
    const float* query        = (const float*)d_in[0];
    const float* memory       = (const float*)d_in[1];
    const float* pos_local    = (const float*)d_in[2];
    const float* pos_temporal = (const float*)d_in[3];
    const float* pos_ts       = (const float*)d_in[4];
    const float* ln_g[5] = {(const float*)d_in[5], (const float*)d_in[7], (const float*)d_in[9], (const float*)d_in[11], (const float*)d_in[13]};
    const float* ln_b[5] = {(const float*)d_in[6], (const float*)d_in[8], (const float*)d_in[10], (const float*)d_in[12], (const float*)d_in[14]};
    const float* sa_w_in  = (const float*)d_in[15]; const float* sa_b_in  = (const float*)d_in[16];
    const float* sa_w_out = (const float*)d_in[17]; const float* sa_b_out = (const float*)d_in[18];
    const float* ta_w_in  = (const float*)d_in[19]; const float* ta_b_in  = (const float*)d_in[20];
    const float* ta_w_out = (const float*)d_in[21]; const float* ta_b_out = (const float*)d_in[22];
    const float* ca_w_in  = (const float*)d_in[23]; const float* ca_b_in  = (const float*)d_in[24];
    const float* ca_w_out = (const float*)d_in[25]; const float* ca_b_out = (const float*)d_in[26];
    const float* fc1_w = (const float*)d_in[27]; const float* fc1_b = (const float*)d_in[28];
    const float* dw_w  = (const float*)d_in[29]; const float* dw_b  = (const float*)d_in[30];
    const float* fc2_w = (const float*)d_in[31]; const float* fc2_b = (const float*)d_in[32];
    const float* bn1g = (const float*)d_in[33], *bn1b = (const float*)d_in[34], *bn1m = (const float*)d_in[35], *bn1v = (const float*)d_in[36];
    const float* bn2g = (const float*)d_in[37], *bn2b = (const float*)d_in[38], *bn2m = (const float*)d_in[39], *bn2v = (const float*)d_in[40];
    const float* bn3g = (const float*)d_in[41], *bn3b = (const float*)d_in[42], *bn3m = (const float*)d_in[43], *bn3v = (const float*)d_in[44];
    const float* lin1_w = (const float*)d_in[45]; const float* lin1_b = (const float*)d_in[46];
    const float* lin2_w = (const float*)d_in[47]; const float* lin2_b = (const float*)d_in[48];

    dim3 blk(256);
    int gMC = (int)(MC / 256);

    size_t need_small = MC * 4 + 4 * MC * 2;
    size_t need_big   = need_small + WTOT * 2;
    size_t need_tA    = need_big + 2 * HC * 2;          // + H1,H2 (bf16, hidden dim)
    if (ws_size < need_small) {
        k_fill<<<gMC, blk, 0, stream>>>((float*)d_out, 700.f, MC);
        return;
    }
    bool wb16  = (ws_size >= need_big);
    bool tierA = (ws_size >= need_tA);

    float* X = (float*)d_ws;
    bf16* B0 = (bf16*)((char*)d_ws + MC * 4);
    bf16* B1 = B0 + MC;
    bf16* B2 = B1 + MC;
    bf16* B3 = B2 + MC;
    bf16* WB = B3 + MC;
    bf16* H1 = WB + WTOT;           // valid only when tierA
    bf16* H2 = H1 + HC;
    const float* nulf = nullptr;
    bf16* nulm = nullptr;

    // bf16 weight views (valid only when wb16)
    bf16* wb_sa_in  = WB + 0;
    bf16* wb_sa_out = WB + 786432;
    bf16* wb_ta_in  = WB + 1048576;
    bf16* wb_ta_out = WB + 1835008;
    bf16* wb_ca_in  = WB + 2097152;
    bf16* wb_ca_out = WB + 2883584;
    bf16* wb_fc1    = WB + 3145728;
    bf16* wb_fc2    = WB + 4194304;
    bf16* wb_lin1   = WB + 5242880;
    bf16* wb_lin2   = WB + 6291456;

    if (wb16) {
        k_cvtw<<<(int)((WTOT + 255) / 256), blk, 0, stream>>>(WB,
            sa_w_in, sa_w_out, ta_w_in, ta_w_out, ca_w_in, ca_w_out,
            fc1_w, fc2_w, lin1_w, lin2_w);
    }

    hipMemcpyAsync(X, query, MC * sizeof(float), hipMemcpyDeviceToDevice, stream);

    // ---- stage 1: spatial window MHSA (L=S=64, Bc=320) ----
    k_ln2<<<MTOK, 64, 0, stream>>>(X, B0, B1, ln_g[0], ln_b[0], pos_local, 0, 1);
    // fused q+k projection (w_in rows 0..1023): Q->B2, K->B3
    launch_gemm(0, wb16, dim3(8, 160), B1, sa_w_in, wb_sa_in, sa_b_in, B2, B3, 512, 512, 512, nulf, nulf, nulf, nulf, stream);
    launch_gemm(0, wb16, dim3(4, 160), B0, sa_w_in + 524288, wb_sa_in + 524288, sa_b_in + 1024, B1, nulm, 0, 512, 512, nulf, nulf, nulf, nulf, stream);
    k_fattn<<<dim3(320 * NHEAD, 1), blk, 0, stream>>>(B2, B3, B1, B0, 64, 64, 320);
    launch_gemm(0, wb16, dim3(4, 160), B0, sa_w_out, wb_sa_out, sa_b_out, B2, nulm, 0, 512, 512, nulf, nulf, nulf, nulf, stream);
    k_unperm_add<<<gMC, blk, 0, stream>>>(X, B2, 1);

    // ---- stage 2: MlpDWBN ----
    k_ln2<<<MTOK, 64, 0, stream>>>(X, B0, nulm, ln_g[1], ln_b[1], nulf, 0, 0);
    if (tierA) {
        launch_gemm(1, wb16, dim3(16, 160), B0, fc1_w, wb_fc1, fc1_b, H1, nulm, 0, 2048, 512,
                    bn1g, bn1b, bn1m, bn1v, stream);
        k_dwc<<<(int)(HC / 256), blk, 0, stream>>>(H1, H2, dw_w, dw_b, bn2g, bn2b, bn2m, bn2v, MTOK);
        launch_gemm(1, wb16, dim3(4, 160), H2, fc2_w, wb_fc2, fc2_b, B2, nulm, 0, 512, 2048,
                    bn3g, bn3b, bn3m, bn3v, stream);
    } else {
        for (int c = 0; c < 4; ++c) {
            int off = c * 5120;
            launch_gemm(1, wb16, dim3(16, 40), B0 + (size_t)off * CC, fc1_w, wb_fc1, fc1_b, B1, nulm, 0, 2048, 512,
                        bn1g, bn1b, bn1m, bn1v, stream);
            k_dwc<<<40960, blk, 0, stream>>>(B1, B3, dw_w, dw_b, bn2g, bn2b, bn2m, bn2v, 5120);
            launch_gemm(1, wb16, dim3(4, 40), B3, fc2_w, wb_fc2, fc2_b, B2 + (size_t)off * CC, nulm, 0, 512, 2048,
                        bn3g, bn3b, bn3m, bn3v, stream);
        }
    }
    k_add<<<gMC, blk, 0, stream>>>(X, B2, MC);

    // ---- stage 3: temporal MHSA (T=10: wave-per-head kernel) ----
    k_ln2<<<MTOK, 64, 0, stream>>>(X, B0, B1, ln_g[2], ln_b[2], pos_temporal, 0, 3);
    launch_gemm(0, wb16, dim3(8, 160), B1, ta_w_in, wb_ta_in, ta_b_in, B2, B3, 512, 512, 512, nulf, nulf, nulf, nulf, stream);
    launch_gemm(0, wb16, dim3(4, 160), B0, ta_w_in + 524288, wb_ta_in + 524288, ta_b_in + 1024, B1, nulm, 0, 512, 512, nulf, nulf, nulf, nulf, stream);
    k_tattn<<<4096, blk, 0, stream>>>(B2, B3, B1, B0);
    launch_gemm(0, wb16, dim3(4, 160), B0, ta_w_out, wb_ta_out, ta_b_out, B2, nulm, 0, 512, 512, nulf, nulf, nulf, nulf, stream);
    k_unperm_add<<<gMC, blk, 0, stream>>>(X, B2, 3);

    // ---- stage 4: temporal-spatial cross-attention (L=S=640, Bc=32: MFMA flash) ----
    k_ln2<<<MTOK, 64, 0, stream>>>(X, nulm, B1, ln_g[3], ln_b[3], pos_ts, 640, 4);
    launch_gemm(0, wb16, dim3(4, 160), B1, ca_w_in, wb_ca_in, ca_b_in, B2, nulm, 0, 512, 512, nulf, nulf, nulf, nulf, stream);
    k_permmem<<<gMC, blk, 0, stream>>>(memory, B1, pos_ts, 0);
    launch_gemm(0, wb16, dim3(4, 160), B1, ca_w_in + 262144, wb_ca_in + 262144, ca_b_in + 512, B3, nulm, 0, 512, 512, nulf, nulf, nulf, nulf, stream);
    k_permmem<<<gMC, blk, 0, stream>>>(memory, B1, nulf, 0);
    launch_gemm(0, wb16, dim3(4, 160), B1, ca_w_in + 524288, wb_ca_in + 524288, ca_b_in + 1024, B0, nulm, 0, 512, 512, nulf, nulf, nulf, nulf, stream);
    k_fattn<<<dim3(32 * NHEAD, 10), blk, 0, stream>>>(B2, B3, B0, B1, 640, 640, 32);
    launch_gemm(0, wb16, dim3(4, 160), B1, ca_w_out, wb_ca_out, ca_b_out, B2, nulm, 0, 512, 512, nulf, nulf, nulf, nulf, stream);
    k_unperm_add<<<gMC, blk, 0, stream>>>(X, B2, 4);

    // ---- stage 5: final FFN ----
    k_ln2<<<MTOK, 64, 0, stream>>>(X, B0, nulm, ln_g[4], ln_b[4], nulf, 0, 0);
    if (tierA) {
        launch_gemm(3, wb16, dim3(16, 160), B0, lin1_w, wb_lin1, lin1_b, H1, nulm, 0, 2048, 512,
                    nulf, nulf, nulf, nulf, stream);
        launch_gemm(0, wb16, dim3(4, 160), H1, lin2_w, wb_lin2, lin2_b, B2, nulm, 0, 512, 2048,
                    nulf, nulf, nulf, nulf, stream);
    } else {
        for (int c = 0; c < 4; ++c) {
            int off = c * 5120;
            launch_gemm(3, wb16, dim3(16, 40), B0 + (size_t)off * CC, lin1_w, wb_lin1, lin1_b, B1, nulm, 0, 2048, 512,
                        nulf, nulf, nulf, nulf, stream);
            launch_gemm(0, wb16, dim3(4, 40), B1, lin2_w, wb_lin2, lin2_b, B2 + (size_t)off * CC, nulm, 0, 512, 2048,
                        nulf, nulf, nulf, nulf, stream);
        }
    }
    k_final<<<gMC, blk, 0, stream>>>(X, B2, (float*)d_out, MC);
}

// Round 5
// 1753.698 us; speedup vs baseline: 3.0384x; 1.0379x over previous
//
#include <hip/hip_runtime.h>
#include <hip/hip_bf16.h>
#include <math.h>

typedef __hip_bfloat16 bf16;
typedef unsigned int u32;
typedef __attribute__((ext_vector_type(8))) short bf16x8v;
typedef __attribute__((ext_vector_type(4))) float f32x4v;

static constexpr int NB = 8, TT = 10, HH = 16, WW = 16, CC = 512;
static constexpr int NHEAD = 8, HIDN = 2048;
static constexpr int MTOK = NB * TT * HH * WW;          // 20480 tokens
static constexpr size_t MC = (size_t)MTOK * CC;         // 10485760
static constexpr size_t HC = (size_t)MTOK * HIDN;       // 41943040
static constexpr float LNEPS = 1e-5f;
static constexpr float ATTSCALE = 0.125f;               // 1/sqrt(64)
static constexpr size_t WTOT = 7340032;                 // total weight elems pre-converted to bf16

static __device__ __forceinline__ float gelu_f(float x) {
    return 0.5f * x * (1.0f + erff(x * 0.70710678118654752f));
}

static __device__ __forceinline__ float bf2f(short s) {
    union { u32 u; float f; } c; c.u = ((u32)(unsigned short)s) << 16; return c.f;
}

// direct global->LDS async copy, 16B per lane; LDS dest = wave-uniform base + lane*16
static __device__ __forceinline__ void gl_lds16(const void* g, void* l)
{
    __builtin_amdgcn_global_load_lds((const __attribute__((address_space(1))) u32*)g,
                                     (__attribute__((address_space(3))) u32*)l, 16, 0, 0);
}

// token index m -> permuted row (and pos-row pr) for each layout mode
static __device__ __forceinline__ int perm_row(int m, int mode, int* pr)
{
    if (mode == 1) {
        int nt = m >> 8, hw = m & 255, h = hw >> 4, w = hw & 15;
        int l = (h & 7) * 8 + (w & 7);
        *pr = l;
        return l * 320 + nt * 4 + (h >> 3) * 2 + (w >> 3);
    } else if (mode == 3) {
        int n = m / 2560, rem = m - n * 2560;
        int t = rem >> 8;
        *pr = t;
        return t * 2048 + n * 256 + (rem & 255);
    } else if (mode == 4) {
        int n = m / 2560, rem = m - n * 2560;
        int t = rem >> 8, hw = rem & 255, h = hw >> 4, w = hw & 15;
        int ij = (h & 7) * 8 + (w & 7);
        *pr = t * 64 + ij;
        return (t * 64 + ij) * 32 + n * 4 + (h >> 3) * 2 + (w >> 3);
    }
    *pr = 0;
    return m;
}

// ---------------- ws-too-small diagnostic ----------------
__global__ __launch_bounds__(256) void k_fill(float* __restrict__ out, float v, size_t n)
{
    size_t i = (size_t)blockIdx.x * 256 + threadIdx.x;
    if (i < n) out[i] = v;
}

// ---------------- one-shot fp32 -> bf16 weight conversion (28 segments of 262144) ----------------
__global__ __launch_bounds__(256) void k_cvtw(bf16* __restrict__ out,
    const float* __restrict__ p0, const float* __restrict__ p1, const float* __restrict__ p2,
    const float* __restrict__ p3, const float* __restrict__ p4, const float* __restrict__ p5,
    const float* __restrict__ p6, const float* __restrict__ p7, const float* __restrict__ p8,
    const float* __restrict__ p9)
{
    size_t id = (size_t)blockIdx.x * 256 + threadIdx.x;
    if (id >= WTOT) return;
    int sid = (int)(id >> 18);                 // /262144
    const float* base; size_t lo;
    if (sid < 3)       { base = p0; lo = id; }
    else if (sid < 4)  { base = p1; lo = id - (size_t)3  * 262144; }
    else if (sid < 7)  { base = p2; lo = id - (size_t)4  * 262144; }
    else if (sid < 8)  { base = p3; lo = id - (size_t)7  * 262144; }
    else if (sid < 11) { base = p4; lo = id - (size_t)8  * 262144; }
    else if (sid < 12) { base = p5; lo = id - (size_t)11 * 262144; }
    else if (sid < 16) { base = p6; lo = id - (size_t)12 * 262144; }
    else if (sid < 20) { base = p7; lo = id - (size_t)16 * 262144; }
    else if (sid < 24) { base = p8; lo = id - (size_t)20 * 262144; }
    else               { base = p9; lo = id - (size_t)24 * 262144; }
    out[id] = __float2bfloat16(base[lo]);
}

// ---------------- fused [residual-add +] LayerNorm (+permute, +pos); X fp32, dst bf16 ----------------
// resid (optional, bf16, permuted layout rmode): X[m] += unperm(resid); X written back.
__global__ __launch_bounds__(64) void k_ln2(float* __restrict__ X, bf16* __restrict__ dstA,
                                            bf16* __restrict__ dstB,
                                            const float* __restrict__ g, const float* __restrict__ b,
                                            const float* __restrict__ pos, int posoff, int mode,
                                            const bf16* __restrict__ resid, int rmode)
{
    int m = blockIdx.x;
    int lane = threadIdx.x;
    float* row = X + (size_t)m * CC;
    float v[8], s = 0.f, s2 = 0.f;
    if (resid) {
        int du;
        int rr = perm_row(m, rmode, &du);
        const bf16* rp = resid + (size_t)rr * CC;
#pragma unroll
        for (int i = 0; i < 8; ++i) {
            int c = lane + i * 64;
            float y = row[c] + (float)rp[c];
            row[c] = y;
            v[i] = y; s += y; s2 += y * y;
        }
    } else {
#pragma unroll
        for (int i = 0; i < 8; ++i) { int c = lane + i * 64; v[i] = row[c]; s += v[i]; s2 += v[i] * v[i]; }
    }
#pragma unroll
    for (int msk = 1; msk < 64; msk <<= 1) { s += __shfl_xor(s, msk); s2 += __shfl_xor(s2, msk); }
    float mean = s * (1.f / 512.f);
    float var  = fmaxf(s2 * (1.f / 512.f) - mean * mean, 0.f);
    float rr2 = rsqrtf(var + LNEPS);

    int pr;
    int r = perm_row(m, mode, &pr);
#pragma unroll
    for (int i = 0; i < 8; ++i) {
        int c = lane + i * 64;
        float y = (v[i] - mean) * rr2 * g[c] + b[c];
        if (dstA) dstA[(size_t)r * CC + c] = __float2bfloat16(y);
        if (dstB) dstB[(size_t)r * CC + c] = __float2bfloat16(y + pos[(size_t)(posoff + pr) * CC + c]);
    }
}

// ---------------- gather-permute of fp32 `memory` into ts layout; out=(+pos), out2=plain ----------------
__global__ __launch_bounds__(256) void k_permmem(const float* __restrict__ in, bf16* __restrict__ out,
                                                 bf16* __restrict__ out2,
                                                 const float* __restrict__ pos, int posoff)
{
    size_t id = (size_t)blockIdx.x * 256 + threadIdx.x;
    if (id >= MC) return;
    int c = (int)(id & 511);
    int r = (int)(id >> 9);
    int b = r & 31, s = r >> 5;
    int t = s >> 6, ij = s & 63;
    int i = ij >> 3, j = ij & 7;
    int n = b >> 2, qh = (b >> 1) & 1, qw = b & 1;
    int m = (n * 10 + t) * 256 + (qh * 8 + i) * 16 + qw * 8 + j;
    float v = in[(size_t)m * CC + c];
    if (out2) out2[id] = __float2bfloat16(v);
    if (pos) v += pos[(size_t)(posoff + t * 64 + ij) * CC + c];
    out[id] = __float2bfloat16(v);
}

// ---------------- final residual add: FLOAT32 output ----------------
__global__ __launch_bounds__(256) void k_final(const float* __restrict__ X, const bf16* __restrict__ F,
                                               float* __restrict__ out, size_t n)
{
    size_t i = (size_t)blockIdx.x * 256 + threadIdx.x;
    if (i < n) out[i] = X[i] + (float)F[i];
}

// ---------------- MFMA GEMM: C = A(bf16, M x K) @ W(Nc_w x K)^T + bias; out bf16 ----------------
// 128x128 tile, BK=32, 4 waves each computing a 64x64 quadrant via 16 x mfma_f32_16x16x32_bf16.
// WB16=true: bf16 weights, staging via global_load_lds width-16 into linear [128][32] LDS.
// WB16=false: fp32 weights, register staging + in-loop convert, padded [128][40] LDS.
// EPI 0: bias.  1: bias+BN+GELU.  3: bias+GELU.
// Split output: if nsplit>0, blocks with bn>=nsplit write to Cout2 at col n-nsplit (stride Nc).
template<int EPI, bool WB16>
__global__ __launch_bounds__(256) void k_mgemm(const bf16* __restrict__ A, const float* __restrict__ Wf,
                                               const bf16* __restrict__ Wb,
                                               const float* __restrict__ bias, bf16* __restrict__ Cout,
                                               bf16* __restrict__ Cout2, int nsplit,
                                               int Nc, int K,
                                               const float* __restrict__ bng, const float* __restrict__ bnb,
                                               const float* __restrict__ bnm, const float* __restrict__ bnv)
{
    __shared__ short smem[WB16 ? 2 * 128 * 32 : 2 * 128 * 40];
    constexpr int LDW = WB16 ? 32 : 40;           // LDS row stride (shorts)
    short* As = smem;
    short* Bs = smem + 128 * LDW;

    int bm = blockIdx.y * 128, bn = blockIdx.x * 128;
    int tid = threadIdx.x;
    int lane = tid & 63, wave = tid >> 6;
    int wm = (wave & 1) * 64, wn = (wave >> 1) * 64;
    int fr = lane & 15;      // frag row (A) / col (B,D)
    int fq = lane >> 4;      // quad: k-offset fq*8 (A,B), row-offset fq*4 (D)

    bf16* co = Cout; int noff = 0;
    if (nsplit > 0 && bn >= nsplit) { co = Cout2; noff = nsplit; }

    f32x4v acc[4][4];
#pragma unroll
    for (int i = 0; i < 4; ++i)
#pragma unroll
        for (int j = 0; j < 4; ++j) acc[i][j] = (f32x4v){0.f, 0.f, 0.f, 0.f};

    if constexpr (WB16) {
        int srow = wave * 32 + (lane >> 2);
        int scol = (lane & 3) * 8;
        const bf16* aptr = A  + (size_t)(bm + srow) * K + scol;
        const bf16* bptr = Wb + (size_t)(bn + srow) * K + scol;
        const size_t row16 = (size_t)16 * K;
        short* asl = &As[wave * 1024];
        short* bsl = &Bs[wave * 1024];

        for (int k0 = 0; k0 < K; k0 += 32) {
            gl_lds16(aptr + k0,         asl);
            gl_lds16(aptr + row16 + k0, asl + 512);
            gl_lds16(bptr + k0,         bsl);
            gl_lds16(bptr + row16 + k0, bsl + 512);
            __syncthreads();            // drains vmcnt -> LDS tiles complete
            bf16x8v af[4], bfr[4];
#pragma unroll
            for (int mi = 0; mi < 4; ++mi) af[mi]  = *(bf16x8v*)&As[(wm + mi * 16 + fr) * 32 + fq * 8];
#pragma unroll
            for (int ni = 0; ni < 4; ++ni) bfr[ni] = *(bf16x8v*)&Bs[(wn + ni * 16 + fr) * 32 + fq * 8];
#pragma unroll
            for (int mi = 0; mi < 4; ++mi)
#pragma unroll
                for (int ni = 0; ni < 4; ++ni)
                    acc[mi][ni] = __builtin_amdgcn_mfma_f32_16x16x32_bf16(af[mi], bfr[ni], acc[mi][ni], 0, 0, 0);
            __syncthreads();
        }
    } else {
        for (int k0 = 0; k0 < K; k0 += 32) {
#pragma unroll
            for (int i = 0; i < 2; ++i) {
                int v = tid * 2 + i;                 // 0..511
                int m = v >> 2, kk = (v & 3) * 8;
                *(uint4*)&As[m * LDW + kk] = *(const uint4*)&A[(size_t)(bm + m) * K + k0 + kk];
                float4 w0 = *(const float4*)&Wf[(size_t)(bn + m) * K + k0 + kk];
                float4 w1 = *(const float4*)&Wf[(size_t)(bn + m) * K + k0 + kk + 4];
                union { bf16 h[8]; uint4 u; } t;
                t.h[0] = __float2bfloat16(w0.x); t.h[1] = __float2bfloat16(w0.y);
                t.h[2] = __float2bfloat16(w0.z); t.h[3] = __float2bfloat16(w0.w);
                t.h[4] = __float2bfloat16(w1.x); t.h[5] = __float2bfloat16(w1.y);
                t.h[6] = __float2bfloat16(w1.z); t.h[7] = __float2bfloat16(w1.w);
                *(uint4*)&Bs[m * LDW + kk] = t.u;
            }
            __syncthreads();
            bf16x8v af[4], bfr[4];
#pragma unroll
            for (int mi = 0; mi < 4; ++mi) af[mi]  = *(bf16x8v*)&As[(wm + mi * 16 + fr) * LDW + fq * 8];
#pragma unroll
            for (int ni = 0; ni < 4; ++ni) bfr[ni] = *(bf16x8v*)&Bs[(wn + ni * 16 + fr) * LDW + fq * 8];
#pragma unroll
            for (int mi = 0; mi < 4; ++mi)
#pragma unroll
                for (int ni = 0; ni < 4; ++ni)
                    acc[mi][ni] = __builtin_amdgcn_mfma_f32_16x16x32_bf16(af[mi], bfr[ni], acc[mi][ni], 0, 0, 0);
            __syncthreads();
        }
    }

#pragma unroll
    for (int mi = 0; mi < 4; ++mi)
#pragma unroll
        for (int ni = 0; ni < 4; ++ni)
#pragma unroll
            for (int r = 0; r < 4; ++r) {
                int m = bm + wm + mi * 16 + fq * 4 + r;
                int n = bn + wn + ni * 16 + fr;
                float v = acc[mi][ni][r] + bias[n];
                if constexpr (EPI == 1) {
                    v = (v - bnm[n]) * rsqrtf(bnv[n] + LNEPS) * bng[n] + bnb[n];
                    v = gelu_f(v);
                }
                if constexpr (EPI == 3) v = gelu_f(v);
                co[(size_t)m * Nc + (n - noff)] = __float2bfloat16(v);
            }
}

// ---------------- elementwise dwconv3x3 + BN2 + GELU over an ntok-token chunk ----------------
__global__ __launch_bounds__(256) void k_dwc(const bf16* __restrict__ H1c, bf16* __restrict__ H2c,
                                             const float* __restrict__ dww, const float* __restrict__ dwb,
                                             const float* __restrict__ g2, const float* __restrict__ b2,
                                             const float* __restrict__ m2, const float* __restrict__ v2,
                                             int ntok)
{
    size_t id = (size_t)blockIdx.x * 256 + threadIdx.x;
    if (id >= (size_t)ntok * HIDN) return;
    int k = (int)(id & 2047);
    int lm = (int)(id >> 11);
    int p = lm >> 8, hw = lm & 255, h = hw >> 4, w = hw & 15;
    float a = dwb[k];
#pragma unroll
    for (int dh = -1; dh <= 1; ++dh) {
        int h2 = h + dh;
        if (h2 < 0 || h2 > 15) continue;
#pragma unroll
        for (int dw = -1; dw <= 1; ++dw) {
            int w2 = w + dw;
            if (w2 < 0 || w2 > 15) continue;
            a += (float)H1c[(((size_t)p * 16 + h2) * 16 + w2) * HIDN + k]
               * dww[k * 9 + (dh + 1) * 3 + (dw + 1)];
        }
    }
    float xn = (a - m2[k]) * rsqrtf(v2[k] + LNEPS) * g2[k] + b2[k];
    H2c[id] = __float2bfloat16(gelu_f(xn));
}

// ---------------- temporal attention, L=S=10, d=64, one (b,h) per wave ----------------
__global__ __launch_bounds__(256) void k_tattn(const bf16* __restrict__ Q, const bf16* __restrict__ K,
                                               const bf16* __restrict__ V, bf16* __restrict__ O)
{
    __shared__ short sQ[4][10][72];
    __shared__ short sK[4][10][72];
    __shared__ short sV[4][10][72];
    int tid = threadIdx.x, wv = tid >> 6, l = tid & 63;
    int p = blockIdx.x * 4 + wv;
    int b = p >> 3, h = p & 7;
    const size_t base = (size_t)b * CC + h * 64;      // row r at base + r*2048*CC

    int cr = l >> 3, ccx = (l & 7) * 8;
#pragma unroll
    for (int i = 0; i < 2; ++i) {
        int r = cr + i * 8;
        if (r < 10) {
            size_t g = base + (size_t)r * 2048 * CC + ccx;
            *(uint4*)&sQ[wv][r][ccx] = *(const uint4*)&Q[g];
            *(uint4*)&sK[wv][r][ccx] = *(const uint4*)&K[g];
            *(uint4*)&sV[wv][r][ccx] = *(const uint4*)&V[g];
        }
    }
    __syncthreads();

    int slot = l & 15, quad = l >> 4;
#pragma unroll
    for (int qo = 0; qo < 3; ++qo) {
        int q = qo * 4 + quad;                        // 0..11
        int qc = q < 10 ? q : 0;
        float acc = 0.f;
        int sc = slot < 10 ? slot : 0;
#pragma unroll
        for (int dd = 0; dd < 8; ++dd) {
            bf16x8v qv = *(bf16x8v*)&sQ[wv][qc][dd * 8];
            bf16x8v kv = *(bf16x8v*)&sK[wv][sc][dd * 8];
#pragma unroll
            for (int j = 0; j < 8; ++j) acc += bf2f(qv[j]) * bf2f(kv[j]);
        }
        float S = (slot < 10 && q < 10) ? acc * ATTSCALE : -1e30f;
        float mx = S;
#pragma unroll
        for (int msk = 1; msk < 16; msk <<= 1) mx = fmaxf(mx, __shfl_xor(mx, msk));
        float e = (slot < 10 && q < 10) ? __expf(S - mx) : 0.f;
        float sum = e;
#pragma unroll
        for (int msk = 1; msk < 16; msk <<= 1) sum += __shfl_xor(sum, msk);
        float inv = 1.f / fmaxf(sum, 1e-20f);

        float o0 = 0.f, o1 = 0.f, o2 = 0.f, o3 = 0.f;
#pragma unroll
        for (int s = 0; s < 10; ++s) {
            float ps = __shfl(e, (l & 48) | s);
            uint2 vv = *(uint2*)&sV[wv][s][slot * 4];
            const short* vs = (const short*)&vv;
            o0 += ps * bf2f(vs[0]);
            o1 += ps * bf2f(vs[1]);
            o2 += ps * bf2f(vs[2]);
            o3 += ps * bf2f(vs[3]);
        }
        if (q < 10) {
            union { ushort us[4]; uint2 u; } pk;
            union { bf16 hh; ushort uu; } cv;
            cv.hh = __float2bfloat16(o0 * inv); pk.us[0] = cv.uu;
            cv.hh = __float2bfloat16(o1 * inv); pk.us[1] = cv.uu;
            cv.hh = __float2bfloat16(o2 * inv); pk.us[2] = cv.uu;
            cv.hh = __float2bfloat16(o3 * inv); pk.us[3] = cv.uu;
            *(uint2*)&O[base + (size_t)q * 2048 * CC + slot * 4] = pk.u;
        }
    }
}

// ---------------- MFMA flash attention, swapped-QK^T + defer-max ----------------
// grid.x = L/64 (q-tile), grid.y = Bc*NHEAD (b*8+h) -- consecutive blocks share K/V (L2 reuse).
// 4 waves; wave w owns q rows w*16..w*16+15. Swapped QK: mfma(K,Q) -> lane holds q = lane&15,
// s = nt*16+fq*4+r. Row softmax: in-register max/sum + 2 shfl_xor. Defer-max THR=8 (T13).
// sVt swizzle: off(d,s) = d*64 + (s ^ ((((d>>3)^(d&7))&7)<<3)).
__global__ __launch_bounds__(256) void k_fattn(const bf16* __restrict__ Q, const bf16* __restrict__ K,
                                               const bf16* __restrict__ V, bf16* __restrict__ O,
                                               int L, int S, int Bc)
{
    __shared__ short sK[64][72];        // [s][d] bf16, stride 72
    __shared__ short sVt[64 * 64];      // [d][s] bf16, swizzled
    __shared__ short sP[4][16][40];     // per-wave P bounce: [wave][q][s]

    int b = (int)blockIdx.y >> 3;
    int h = (int)blockIdx.y & 7;
    int q0 = blockIdx.x * 64;
    int tid = threadIdx.x;
    int wv = tid >> 6;
    int lane = tid & 63;
    int fr = lane & 15;
    int fq = lane >> 4;

    const bf16* qp = Q + ((size_t)(q0 + wv * 16 + fr) * Bc + b) * CC + h * 64 + fq * 8;
    bf16x8v qf0 = *(const bf16x8v*)qp;
    bf16x8v qf1 = *(const bf16x8v*)(qp + 32);

    f32x4v oacc[4];
#pragma unroll
    for (int i = 0; i < 4; ++i) oacc[i] = (f32x4v){0.f, 0.f, 0.f, 0.f};
    float m_run = -1e30f, l_run = 0.f;   // for q-row = fr (replicated over fq groups)

    int ks = tid >> 2, kd0 = (tid & 3) * 16;
    int vd0 = (tid & 7) * 8, vs2 = (tid >> 3) * 2;

    for (int s0 = 0; s0 < S; s0 += 64) {
        __syncthreads();
        {
            const bf16* kp = K + ((size_t)(s0 + ks) * Bc + b) * CC + h * 64 + kd0;
            *(uint4*)&sK[ks][kd0]     = *(const uint4*)kp;
            *(uint4*)&sK[ks][kd0 + 8] = *(const uint4*)(kp + 8);
        }
        {
            const bf16* vp0 = V + ((size_t)(s0 + vs2) * Bc + b) * CC + h * 64 + vd0;
            const bf16* vp1 = vp0 + (size_t)Bc * CC;
            uint4 va = *(const uint4*)vp0;
            uint4 vb = *(const uint4*)vp1;
            const ushort* as = (const ushort*)&va;
            const ushort* bs = (const ushort*)&vb;
#pragma unroll
            for (int j = 0; j < 8; ++j) {
                int dd = vd0 + j;
                int sw = vs2 ^ (((( dd >> 3) ^ (dd & 7)) & 7) << 3);
                *(u32*)&sVt[dd * 64 + sw] = (u32)as[j] | ((u32)bs[j] << 16);
            }
        }
        __syncthreads();

        // QK^T swapped: sc[nt][r] = S_raw[s = nt*16+fq*4+r][q = fr]
        f32x4v sc[4];
#pragma unroll
        for (int nt = 0; nt < 4; ++nt) {
            bf16x8v k0 = *(bf16x8v*)&sK[nt * 16 + fr][fq * 8];
            bf16x8v k1 = *(bf16x8v*)&sK[nt * 16 + fr][32 + fq * 8];
            f32x4v z = (f32x4v){0.f, 0.f, 0.f, 0.f};
            z = __builtin_amdgcn_mfma_f32_16x16x32_bf16(k0, qf0, z, 0, 0, 0);
            z = __builtin_amdgcn_mfma_f32_16x16x32_bf16(k1, qf1, z, 0, 0, 0);
            sc[nt] = z;
        }

        // row max (q = fr): in-register + 2 shuffles across fq groups
        float pm = sc[0][0];
#pragma unroll
        for (int nt = 0; nt < 4; ++nt)
#pragma unroll
            for (int r = 0; r < 4; ++r) pm = fmaxf(pm, sc[nt][r]);
        pm *= ATTSCALE;
        pm = fmaxf(pm, __shfl_xor(pm, 16));
        pm = fmaxf(pm, __shfl_xor(pm, 32));

        if (__any(pm > m_run + 8.f)) {            // defer-max: rescale only on real growth
            float mnew = fmaxf(m_run, pm);
            float alpha = __expf(m_run - mnew);
            m_run = mnew;
            l_run *= alpha;
            float al0 = __shfl(alpha, (lane & 48) | (fq * 4 + 0));
            float al1 = __shfl(alpha, (lane & 48) | (fq * 4 + 1));
            float al2 = __shfl(alpha, (lane & 48) | (fq * 4 + 2));
            float al3 = __shfl(alpha, (lane & 48) | (fq * 4 + 3));
#pragma unroll
            for (int nt2 = 0; nt2 < 4; ++nt2) {
                oacc[nt2][0] *= al0; oacc[nt2][1] *= al1;
                oacc[nt2][2] *= al2; oacc[nt2][3] *= al3;
            }
        }

        short (*sPw)[40] = sP[wv];
        float rs = 0.f;
#pragma unroll
        for (int nt = 0; nt < 4; ++nt) {
#pragma unroll
            for (int rp = 0; rp < 2; ++rp) {
                float p0 = __expf(sc[nt][2 * rp]     * ATTSCALE - m_run);
                float p1 = __expf(sc[nt][2 * rp + 1] * ATTSCALE - m_run);
                union { bf16 hh; ushort uu; } c0, c1;
                c0.hh = __float2bfloat16(p0);
                c1.hh = __float2bfloat16(p1);
                *(u32*)&sPw[fr][nt * 16 + fq * 4 + 2 * rp] = (u32)c0.uu | ((u32)c1.uu << 16);
                rs += bf2f((short)c0.uu) + bf2f((short)c1.uu);   // denom matches bf16 P
            }
        }
        rs += __shfl_xor(rs, 16);
        rs += __shfl_xor(rs, 32);
        l_run += rs;
        __syncthreads();

        // PV: A = P[q][s], B' = V^T[d][s] -> oacc: row q = fq*4+r, col d = nt2*16+fr
        bf16x8v pa0 = *(bf16x8v*)&sPw[fr][fq * 8];
        bf16x8v pa1 = *(bf16x8v*)&sPw[fr][32 + fq * 8];
#pragma unroll
        for (int nt2 = 0; nt2 < 4; ++nt2) {
            int vr = nt2 * 16 + fr;
            int vx = (((vr >> 3) ^ (vr & 7)) & 7) << 3;
            bf16x8v v0 = *(bf16x8v*)&sVt[vr * 64 + ((fq * 8) ^ vx)];
            bf16x8v v1 = *(bf16x8v*)&sVt[vr * 64 + ((32 + fq * 8) ^ vx)];
            oacc[nt2] = __builtin_amdgcn_mfma_f32_16x16x32_bf16(pa0, v0, oacc[nt2], 0, 0, 0);
            oacc[nt2] = __builtin_amdgcn_mfma_f32_16x16x32_bf16(pa1, v1, oacc[nt2], 0, 0, 0);
        }
    }

    // epilogue: lane holds q = fq*4+r rows; l_run lives in lane (group)|q
    float linv[4];
#pragma unroll
    for (int r = 0; r < 4; ++r)
        linv[r] = __shfl(l_run, (lane & 48) | (fq * 4 + r));
#pragma unroll
    for (int r = 0; r < 4; ++r) {
        float inv = 1.f / fmaxf(linv[r], 1e-20f);
        bf16* op = O + ((size_t)(q0 + wv * 16 + fq * 4 + r) * Bc + b) * CC + h * 64 + fr;
#pragma unroll
        for (int nt2 = 0; nt2 < 4; ++nt2)
            op[nt2 * 16] = __float2bfloat16(oacc[nt2][r] * inv);
    }
}

// ---------------- host-side GEMM dispatcher ----------------
static void launch_gemm(int epi, bool wb16, dim3 grid,
                        const bf16* A, const float* Wf, const bf16* Wb,
                        const float* bias, bf16* C, bf16* C2, int nsplit, int Nc, int K,
                        const float* g, const float* b, const float* m, const float* v,
                        hipStream_t s)
{
    dim3 blk(256);
    if (wb16) {
        switch (epi) {
        case 0: k_mgemm<0, true><<<grid, blk, 0, s>>>(A, Wf, Wb, bias, C, C2, nsplit, Nc, K, g, b, m, v); break;
        case 1: k_mgemm<1, true><<<grid, blk, 0, s>>>(A, Wf, Wb, bias, C, C2, nsplit, Nc, K, g, b, m, v); break;
        default: k_mgemm<3, true><<<grid, blk, 0, s>>>(A, Wf, Wb, bias, C, C2, nsplit, Nc, K, g, b, m, v); break;
        }
    } else {
        switch (epi) {
        case 0: k_mgemm<0, false><<<grid, blk, 0, s>>>(A, Wf, Wb, bias, C, C2, nsplit, Nc, K, g, b, m, v); break;
        case 1: k_mgemm<1, false><<<grid, blk, 0, s>>>(A, Wf, Wb, bias, C, C2, nsplit, Nc, K, g, b, m, v); break;
        default: k_mgemm<3, false><<<grid, blk, 0, s>>>(A, Wf, Wb, bias, C, C2, nsplit, Nc, K, g, b, m, v); break;
        }
    }
}

extern "C" void kernel_launch(void* const* d_in, const int* in_sizes, int n_in,
                              void* d_out, int out_size, void* d_ws, size_t ws_size,
                              hipStream_t stream)
{
    const float* query        = (const float*)d_in[0];
    const float* memory       = (const float*)d_in[1];
    const float* pos_local    = (const float*)d_in[2];
    const float* pos_temporal = (const float*)d_in[3];
    const float* pos_ts       = (const float*)d_in[4];
    const float* ln_g[5] = {(const float*)d_in[5], (const float*)d_in[7], (const float*)d_in[9], (const float*)d_in[11], (const float*)d_in[13]};
    const float* ln_b[5] = {(const float*)d_in[6], (const float*)d_in[8], (const float*)d_in[10], (const float*)d_in[12], (const float*)d_in[14]};
    const float* sa_w_in  = (const float*)d_in[15]; const float* sa_b_in  = (const float*)d_in[16];
    const float* sa_w_out = (const float*)d_in[17]; const float* sa_b_out = (const float*)d_in[18];
    const float* ta_w_in  = (const float*)d_in[19]; const float* ta_b_in  = (const float*)d_in[20];
    const float* ta_w_out = (const float*)d_in[21]; const float* ta_b_out = (const float*)d_in[22];
    const float* ca_w_in  = (const float*)d_in[23]; const float* ca_b_in  = (const float*)d_in[24];
    const float* ca_w_out = (const float*)d_in[25]; const float* ca_b_out = (const float*)d_in[26];
    const float* fc1_w = (const float*)d_in[27]; const float* fc1_b = (const float*)d_in[28];
    const float* dw_w  = (const float*)d_in[29]; const float* dw_b  = (const float*)d_in[30];
    const float* fc2_w = (const float*)d_in[31]; const float* fc2_b = (const float*)d_in[32];
    const float* bn1g = (const float*)d_in[33], *bn1b = (const float*)d_in[34], *bn1m = (const float*)d_in[35], *bn1v = (const float*)d_in[36];
    const float* bn2g = (const float*)d_in[37], *bn2b = (const float*)d_in[38], *bn2m = (const float*)d_in[39], *bn2v = (const float*)d_in[40];
    const float* bn3g = (const float*)d_in[41], *bn3b = (const float*)d_in[42], *bn3m = (const float*)d_in[43], *bn3v = (const float*)d_in[44];
    const float* lin1_w = (const float*)d_in[45]; const float* lin1_b = (const float*)d_in[46];
    const float* lin2_w = (const float*)d_in[47]; const float* lin2_b = (const float*)d_in[48];

    dim3 blk(256);
    int gMC = (int)(MC / 256);

    size_t need_small = MC * 4 + 4 * MC * 2;
    size_t need_big   = need_small + WTOT * 2;
    size_t need_tA    = need_big + 2 * HC * 2;          // + H1,H2 (bf16, hidden dim)
    if (ws_size < need_small) {
        k_fill<<<gMC, blk, 0, stream>>>((float*)d_out, 700.f, MC);
        return;
    }
    bool wb16  = (ws_size >= need_big);
    bool tierA = (ws_size >= need_tA);

    float* X = (float*)d_ws;
    bf16* B0 = (bf16*)((char*)d_ws + MC * 4);
    bf16* B1 = B0 + MC;
    bf16* B2 = B1 + MC;
    bf16* B3 = B2 + MC;
    bf16* WB = B3 + MC;
    bf16* H1 = WB + WTOT;           // valid only when tierA
    bf16* H2 = H1 + HC;
    const float* nulf = nullptr;
    bf16* nulm = nullptr;

    // bf16 weight views (valid only when wb16)
    bf16* wb_sa_in  = WB + 0;
    bf16* wb_sa_out = WB + 786432;
    bf16* wb_ta_in  = WB + 1048576;
    bf16* wb_ta_out = WB + 1835008;
    bf16* wb_ca_in  = WB + 2097152;
    bf16* wb_ca_out = WB + 2883584;
    bf16* wb_fc1    = WB + 3145728;
    bf16* wb_fc2    = WB + 4194304;
    bf16* wb_lin1   = WB + 5242880;
    bf16* wb_lin2   = WB + 6291456;

    if (wb16) {
        k_cvtw<<<(int)((WTOT + 255) / 256), blk, 0, stream>>>(WB,
            sa_w_in, sa_w_out, ta_w_in, ta_w_out, ca_w_in, ca_w_out,
            fc1_w, fc2_w, lin1_w, lin2_w);
    }

    hipMemcpyAsync(X, query, MC * sizeof(float), hipMemcpyDeviceToDevice, stream);

    // ---- stage 1: spatial window MHSA (L=S=64, Bc=320) ----
    k_ln2<<<MTOK, 64, 0, stream>>>(X, B0, B1, ln_g[0], ln_b[0], pos_local, 0, 1, nulm, 0);
    launch_gemm(0, wb16, dim3(8, 160), B1, sa_w_in, wb_sa_in, sa_b_in, B2, B3, 512, 512, 512, nulf, nulf, nulf, nulf, stream);
    launch_gemm(0, wb16, dim3(4, 160), B0, sa_w_in + 524288, wb_sa_in + 524288, sa_b_in + 1024, B1, nulm, 0, 512, 512, nulf, nulf, nulf, nulf, stream);
    k_fattn<<<dim3(1, 320 * NHEAD), blk, 0, stream>>>(B2, B3, B1, B0, 64, 64, 320);
    launch_gemm(0, wb16, dim3(4, 160), B0, sa_w_out, wb_sa_out, sa_b_out, B2, nulm, 0, 512, 512, nulf, nulf, nulf, nulf, stream);

    // ---- stage 2: MlpDWBN (residual of stage 1 fused into LN) ----
    k_ln2<<<MTOK, 64, 0, stream>>>(X, B0, nulm, ln_g[1], ln_b[1], nulf, 0, 0, B2, 1);
    if (tierA) {
        launch_gemm(1, wb16, dim3(16, 160), B0, fc1_w, wb_fc1, fc1_b, H1, nulm, 0, 2048, 512,
                    bn1g, bn1b, bn1m, bn1v, stream);
        k_dwc<<<(int)(HC / 256), blk, 0, stream>>>(H1, H2, dw_w, dw_b, bn2g, bn2b, bn2m, bn2v, MTOK);
        launch_gemm(1, wb16, dim3(4, 160), H2, fc2_w, wb_fc2, fc2_b, B2, nulm, 0, 512, 2048,
                    bn3g, bn3b, bn3m, bn3v, stream);
    } else {
        for (int c = 0; c < 4; ++c) {
            int off = c * 5120;
            launch_gemm(1, wb16, dim3(16, 40), B0 + (size_t)off * CC, fc1_w, wb_fc1, fc1_b, B1, nulm, 0, 2048, 512,
                        bn1g, bn1b, bn1m, bn1v, stream);
            k_dwc<<<40960, blk, 0, stream>>>(B1, B3, dw_w, dw_b, bn2g, bn2b, bn2m, bn2v, 5120);
            launch_gemm(1, wb16, dim3(4, 40), B3, fc2_w, wb_fc2, fc2_b, B2 + (size_t)off * CC, nulm, 0, 512, 2048,
                        bn3g, bn3b, bn3m, bn3v, stream);
        }
    }

    // ---- stage 3: temporal MHSA (T=10; stage-2 residual fused into LN) ----
    k_ln2<<<MTOK, 64, 0, stream>>>(X, B0, B1, ln_g[2], ln_b[2], pos_temporal, 0, 3, B2, 0);
    launch_gemm(0, wb16, dim3(8, 160), B1, ta_w_in, wb_ta_in, ta_b_in, B2, B3, 512, 512, 512, nulf, nulf, nulf, nulf, stream);
    launch_gemm(0, wb16, dim3(4, 160), B0, ta_w_in + 524288, wb_ta_in + 524288, ta_b_in + 1024, B1, nulm, 0, 512, 512, nulf, nulf, nulf, nulf, stream);
    k_tattn<<<4096, blk, 0, stream>>>(B2, B3, B1, B0);
    launch_gemm(0, wb16, dim3(4, 160), B0, ta_w_out, wb_ta_out, ta_b_out, B2, nulm, 0, 512, 512, nulf, nulf, nulf, nulf, stream);

    // ---- stage 4: temporal-spatial cross-attention (stage-3 residual fused into LN) ----
    k_ln2<<<MTOK, 64, 0, stream>>>(X, nulm, B1, ln_g[3], ln_b[3], pos_ts, 640, 4, B2, 3);
    launch_gemm(0, wb16, dim3(4, 160), B1, ca_w_in, wb_ca_in, ca_b_in, B2, nulm, 0, 512, 512, nulf, nulf, nulf, nulf, stream);
    if (tierA) {
        k_permmem<<<gMC, blk, 0, stream>>>(memory, B1, H1, pos_ts, 0);
        launch_gemm(0, wb16, dim3(4, 160), B1, ca_w_in + 262144, wb_ca_in + 262144, ca_b_in + 512, B3, nulm, 0, 512, 512, nulf, nulf, nulf, nulf, stream);
        launch_gemm(0, wb16, dim3(4, 160), H1, ca_w_in + 524288, wb_ca_in + 524288, ca_b_in + 1024, B0, nulm, 0, 512, 512, nulf, nulf, nulf, nulf, stream);
    } else {
        k_permmem<<<gMC, blk, 0, stream>>>(memory, B1, nulm, pos_ts, 0);
        launch_gemm(0, wb16, dim3(4, 160), B1, ca_w_in + 262144, wb_ca_in + 262144, ca_b_in + 512, B3, nulm, 0, 512, 512, nulf, nulf, nulf, nulf, stream);
        k_permmem<<<gMC, blk, 0, stream>>>(memory, B1, nulm, nulf, 0);
        launch_gemm(0, wb16, dim3(4, 160), B1, ca_w_in + 524288, wb_ca_in + 524288, ca_b_in + 1024, B0, nulm, 0, 512, 512, nulf, nulf, nulf, nulf, stream);
    }
    k_fattn<<<dim3(10, 32 * NHEAD), blk, 0, stream>>>(B2, B3, B0, B1, 640, 640, 32);
    launch_gemm(0, wb16, dim3(4, 160), B1, ca_w_out, wb_ca_out, ca_b_out, B2, nulm, 0, 512, 512, nulf, nulf, nulf, nulf, stream);

    // ---- stage 5: final FFN (stage-4 residual fused into LN) ----
    k_ln2<<<MTOK, 64, 0, stream>>>(X, B0, nulm, ln_g[4], ln_b[4], nulf, 0, 0, B2, 4);
    if (tierA) {
        launch_gemm(3, wb16, dim3(16, 160), B0, lin1_w, wb_lin1, lin1_b, H1, nulm, 0, 2048, 512,
                    nulf, nulf, nulf, nulf, stream);
        launch_gemm(0, wb16, dim3(4, 160), H1, lin2_w, wb_lin2, lin2_b, B2, nulm, 0, 512, 2048,
                    nulf, nulf, nulf, nulf, stream);
    } else {
        for (int c = 0; c < 4; ++c) {
            int off = c * 5120;
            launch_gemm(3, wb16, dim3(16, 40), B0 + (size_t)off * CC, lin1_w, wb_lin1, lin1_b, B1, nulm, 0, 2048, 512,
                        nulf, nulf, nulf, nulf, stream);
            launch_gemm(0, wb16, dim3(4, 40), B1, lin2_w, wb_lin2, lin2_b, B2 + (size_t)off * CC, nulm, 0, 512, 2048,
                        nulf, nulf, nulf, nulf, stream);
        }
    }
    k_final<<<gMC, blk, 0, stream>>>(X, B2, (float*)d_out, MC);
}

// Round 6
// 1385.404 us; speedup vs baseline: 3.8462x; 1.2658x over previous
//
#include <hip/hip_runtime.h>
#include <hip/hip_bf16.h>
#include <math.h>

typedef __hip_bfloat16 bf16;
typedef unsigned int u32;
typedef __attribute__((ext_vector_type(8))) short bf16x8v;
typedef __attribute__((ext_vector_type(4))) float f32x4v;

static constexpr int NB = 8, TT = 10, HH = 16, WW = 16, CC = 512;
static constexpr int NHEAD = 8, HIDN = 2048;
static constexpr int MTOK = NB * TT * HH * WW;          // 20480 tokens
static constexpr size_t MC = (size_t)MTOK * CC;         // 10485760
static constexpr float LNEPS = 1e-5f;
static constexpr float ATTSCALE = 0.125f;               // 1/sqrt(64)
static constexpr size_t WTOT = 7340032;                 // total weight elems pre-converted to bf16

static __device__ __forceinline__ float gelu_f(float x) {
    return 0.5f * x * (1.0f + erff(x * 0.70710678118654752f));
}

static __device__ __forceinline__ float bf2f(short s) {
    union { u32 u; float f; } c; c.u = ((u32)(unsigned short)s) << 16; return c.f;
}

// direct global->LDS async copy, 16B per lane; LDS dest = wave-uniform base + lane*16
static __device__ __forceinline__ void gl_lds16(const void* g, void* l)
{
    __builtin_amdgcn_global_load_lds((const __attribute__((address_space(1))) u32*)g,
                                     (__attribute__((address_space(3))) u32*)l, 16, 0, 0);
}

// token index m -> permuted row (and pos-row pr) for each layout mode
static __device__ __forceinline__ int perm_row(int m, int mode, int* pr)
{
    if (mode == 1) {
        int nt = m >> 8, hw = m & 255, h = hw >> 4, w = hw & 15;
        int l = (h & 7) * 8 + (w & 7);
        *pr = l;
        return l * 320 + nt * 4 + (h >> 3) * 2 + (w >> 3);
    } else if (mode == 3) {
        int n = m / 2560, rem = m - n * 2560;
        int t = rem >> 8;
        *pr = t;
        return t * 2048 + n * 256 + (rem & 255);
    } else if (mode == 4) {
        int n = m / 2560, rem = m - n * 2560;
        int t = rem >> 8, hw = rem & 255, h = hw >> 4, w = hw & 15;
        int ij = (h & 7) * 8 + (w & 7);
        *pr = t * 64 + ij;
        return (t * 64 + ij) * 32 + n * 4 + (h >> 3) * 2 + (w >> 3);
    }
    *pr = 0;
    return m;
}

// ---------------- ws-too-small diagnostic ----------------
__global__ __launch_bounds__(256) void k_fill(float* __restrict__ out, float v, size_t n)
{
    size_t i = (size_t)blockIdx.x * 256 + threadIdx.x;
    if (i < n) out[i] = v;
}

// ---------------- one-shot fp32 -> bf16 weight conversion (28 segments of 262144) ----------------
__global__ __launch_bounds__(256) void k_cvtw(bf16* __restrict__ out,
    const float* __restrict__ p0, const float* __restrict__ p1, const float* __restrict__ p2,
    const float* __restrict__ p3, const float* __restrict__ p4, const float* __restrict__ p5,
    const float* __restrict__ p6, const float* __restrict__ p7, const float* __restrict__ p8,
    const float* __restrict__ p9)
{
    size_t id = (size_t)blockIdx.x * 256 + threadIdx.x;
    if (id >= WTOT) return;
    int sid = (int)(id >> 18);                 // /262144
    const float* base; size_t lo;
    if (sid < 3)       { base = p0; lo = id; }
    else if (sid < 4)  { base = p1; lo = id - (size_t)3  * 262144; }
    else if (sid < 7)  { base = p2; lo = id - (size_t)4  * 262144; }
    else if (sid < 8)  { base = p3; lo = id - (size_t)7  * 262144; }
    else if (sid < 11) { base = p4; lo = id - (size_t)8  * 262144; }
    else if (sid < 12) { base = p5; lo = id - (size_t)11 * 262144; }
    else if (sid < 16) { base = p6; lo = id - (size_t)12 * 262144; }
    else if (sid < 20) { base = p7; lo = id - (size_t)16 * 262144; }
    else if (sid < 24) { base = p8; lo = id - (size_t)20 * 262144; }
    else               { base = p9; lo = id - (size_t)24 * 262144; }
    out[id] = __float2bfloat16(base[lo]);
}

// ---------------- dwconv prep: transpose weights to [9][2048] fp32; fold BN2 ----------------
__global__ __launch_bounds__(256) void k_dwprep(const float* __restrict__ dww,
    const float* __restrict__ g2, const float* __restrict__ b2,
    const float* __restrict__ m2, const float* __restrict__ v2,
    float* __restrict__ dwt, float* __restrict__ sc2, float* __restrict__ sb2)
{
    int k = blockIdx.x * 256 + threadIdx.x;       // 0..2047
#pragma unroll
    for (int t = 0; t < 9; ++t) dwt[t * 2048 + k] = dww[k * 9 + t];
    float sc = g2[k] * rsqrtf(v2[k] + LNEPS);
    sc2[k] = sc;
    sb2[k] = b2[k] - m2[k] * sc;
}

// ---------------- fused [residual-add +] LayerNorm (+permute, +pos); reads Xin, dst bf16 ----------------
// resid (optional, bf16, permuted layout rmode): X[m] = Xin[m] + unperm(resid) (written back to X).
__global__ __launch_bounds__(64) void k_ln2(float* __restrict__ X, const float* __restrict__ Xin,
                                            bf16* __restrict__ dstA, bf16* __restrict__ dstB,
                                            const float* __restrict__ g, const float* __restrict__ b,
                                            const float* __restrict__ pos, int posoff, int mode,
                                            const bf16* __restrict__ resid, int rmode)
{
    int m = blockIdx.x;
    int lane = threadIdx.x;
    const float* row = Xin + (size_t)m * CC;
    float v[8], s = 0.f, s2 = 0.f;
    if (resid) {
        int du;
        int rr = perm_row(m, rmode, &du);
        const bf16* rp = resid + (size_t)rr * CC;
        float* xo = X + (size_t)m * CC;
#pragma unroll
        for (int i = 0; i < 8; ++i) {
            int c = lane + i * 64;
            float y = row[c] + (float)rp[c];
            xo[c] = y;
            v[i] = y; s += y; s2 += y * y;
        }
    } else {
#pragma unroll
        for (int i = 0; i < 8; ++i) { int c = lane + i * 64; v[i] = row[c]; s += v[i]; s2 += v[i] * v[i]; }
    }
#pragma unroll
    for (int msk = 1; msk < 64; msk <<= 1) { s += __shfl_xor(s, msk); s2 += __shfl_xor(s2, msk); }
    float mean = s * (1.f / 512.f);
    float var  = fmaxf(s2 * (1.f / 512.f) - mean * mean, 0.f);
    float rr2 = rsqrtf(var + LNEPS);

    int pr;
    int r = perm_row(m, mode, &pr);
#pragma unroll
    for (int i = 0; i < 8; ++i) {
        int c = lane + i * 64;
        float y = (v[i] - mean) * rr2 * g[c] + b[c];
        if (dstA) dstA[(size_t)r * CC + c] = __float2bfloat16(y);
        if (dstB) dstB[(size_t)r * CC + c] = __float2bfloat16(y + pos[(size_t)(posoff + pr) * CC + c]);
    }
}

// ---------------- gather-permute of fp32 `memory` into ts layout; out=(+pos), out2=plain ----------------
__global__ __launch_bounds__(256) void k_permmem(const float* __restrict__ in, bf16* __restrict__ out,
                                                 bf16* __restrict__ out2,
                                                 const float* __restrict__ pos, int posoff)
{
    size_t id = (size_t)blockIdx.x * 256 + threadIdx.x;
    if (id >= MC) return;
    int c = (int)(id & 511);
    int r = (int)(id >> 9);
    int b = r & 31, s = r >> 5;
    int t = s >> 6, ij = s & 63;
    int i = ij >> 3, j = ij & 7;
    int n = b >> 2, qh = (b >> 1) & 1, qw = b & 1;
    int m = (n * 10 + t) * 256 + (qh * 8 + i) * 16 + qw * 8 + j;
    float v = in[(size_t)m * CC + c];
    if (out2) out2[id] = __float2bfloat16(v);
    if (pos) v += pos[(size_t)(posoff + t * 64 + ij) * CC + c];
    out[id] = __float2bfloat16(v);
}

// ---------------- final residual add: FLOAT32 output ----------------
__global__ __launch_bounds__(256) void k_final(const float* __restrict__ X, const bf16* __restrict__ F,
                                               float* __restrict__ out, size_t n)
{
    size_t i = (size_t)blockIdx.x * 256 + threadIdx.x;
    if (i < n) out[i] = X[i] + (float)F[i];
}

// ---------------- MFMA GEMM: C = A(bf16, M x K) @ W(Nc_w x K)^T + bias; out bf16 ----------------
// 128x128 tile, BK=32, 4 waves each computing a 64x64 quadrant via 16 x mfma_f32_16x16x32_bf16.
// WB16=true: bf16 weights, staging via global_load_lds width-16 into linear [128][32] LDS.
// WB16=false: fp32 weights, register staging + in-loop convert, padded [128][40] LDS.
// EPI 0: bias.  1: bias+BN+GELU.  3: bias+GELU.
// Split output: if nsplit>0, blocks with bn>=nsplit write to Cout2 at col n-nsplit (stride Nc).
template<int EPI, bool WB16>
__global__ __launch_bounds__(256) void k_mgemm(const bf16* __restrict__ A, const float* __restrict__ Wf,
                                               const bf16* __restrict__ Wb,
                                               const float* __restrict__ bias, bf16* __restrict__ Cout,
                                               bf16* __restrict__ Cout2, int nsplit,
                                               int Nc, int K,
                                               const float* __restrict__ bng, const float* __restrict__ bnb,
                                               const float* __restrict__ bnm, const float* __restrict__ bnv)
{
    __shared__ short smem[WB16 ? 2 * 128 * 32 : 2 * 128 * 40];
    constexpr int LDW = WB16 ? 32 : 40;           // LDS row stride (shorts)
    short* As = smem;
    short* Bs = smem + 128 * LDW;

    int bm = blockIdx.y * 128, bn = blockIdx.x * 128;
    int tid = threadIdx.x;
    int lane = tid & 63, wave = tid >> 6;
    int wm = (wave & 1) * 64, wn = (wave >> 1) * 64;
    int fr = lane & 15;      // frag row (A) / col (B,D)
    int fq = lane >> 4;      // quad: k-offset fq*8 (A,B), row-offset fq*4 (D)

    bf16* co = Cout; int noff = 0;
    if (nsplit > 0 && bn >= nsplit) { co = Cout2; noff = nsplit; }

    f32x4v acc[4][4];
#pragma unroll
    for (int i = 0; i < 4; ++i)
#pragma unroll
        for (int j = 0; j < 4; ++j) acc[i][j] = (f32x4v){0.f, 0.f, 0.f, 0.f};

    if constexpr (WB16) {
        int srow = wave * 32 + (lane >> 2);
        int scol = (lane & 3) * 8;
        const bf16* aptr = A  + (size_t)(bm + srow) * K + scol;
        const bf16* bptr = Wb + (size_t)(bn + srow) * K + scol;
        const size_t row16 = (size_t)16 * K;
        short* asl = &As[wave * 1024];
        short* bsl = &Bs[wave * 1024];

        for (int k0 = 0; k0 < K; k0 += 32) {
            gl_lds16(aptr + k0,         asl);
            gl_lds16(aptr + row16 + k0, asl + 512);
            gl_lds16(bptr + k0,         bsl);
            gl_lds16(bptr + row16 + k0, bsl + 512);
            __syncthreads();            // drains vmcnt -> LDS tiles complete
            bf16x8v af[4], bfr[4];
#pragma unroll
            for (int mi = 0; mi < 4; ++mi) af[mi]  = *(bf16x8v*)&As[(wm + mi * 16 + fr) * 32 + fq * 8];
#pragma unroll
            for (int ni = 0; ni < 4; ++ni) bfr[ni] = *(bf16x8v*)&Bs[(wn + ni * 16 + fr) * 32 + fq * 8];
#pragma unroll
            for (int mi = 0; mi < 4; ++mi)
#pragma unroll
                for (int ni = 0; ni < 4; ++ni)
                    acc[mi][ni] = __builtin_amdgcn_mfma_f32_16x16x32_bf16(af[mi], bfr[ni], acc[mi][ni], 0, 0, 0);
            __syncthreads();
        }
    } else {
        for (int k0 = 0; k0 < K; k0 += 32) {
#pragma unroll
            for (int i = 0; i < 2; ++i) {
                int v = tid * 2 + i;                 // 0..511
                int m = v >> 2, kk = (v & 3) * 8;
                *(uint4*)&As[m * LDW + kk] = *(const uint4*)&A[(size_t)(bm + m) * K + k0 + kk];
                float4 w0 = *(const float4*)&Wf[(size_t)(bn + m) * K + k0 + kk];
                float4 w1 = *(const float4*)&Wf[(size_t)(bn + m) * K + k0 + kk + 4];
                union { bf16 h[8]; uint4 u; } t;
                t.h[0] = __float2bfloat16(w0.x); t.h[1] = __float2bfloat16(w0.y);
                t.h[2] = __float2bfloat16(w0.z); t.h[3] = __float2bfloat16(w0.w);
                t.h[4] = __float2bfloat16(w1.x); t.h[5] = __float2bfloat16(w1.y);
                t.h[6] = __float2bfloat16(w1.z); t.h[7] = __float2bfloat16(w1.w);
                *(uint4*)&Bs[m * LDW + kk] = t.u;
            }
            __syncthreads();
            bf16x8v af[4], bfr[4];
#pragma unroll
            for (int mi = 0; mi < 4; ++mi) af[mi]  = *(bf16x8v*)&As[(wm + mi * 16 + fr) * LDW + fq * 8];
#pragma unroll
            for (int ni = 0; ni < 4; ++ni) bfr[ni] = *(bf16x8v*)&Bs[(wn + ni * 16 + fr) * LDW + fq * 8];
#pragma unroll
            for (int mi = 0; mi < 4; ++mi)
#pragma unroll
                for (int ni = 0; ni < 4; ++ni)
                    acc[mi][ni] = __builtin_amdgcn_mfma_f32_16x16x32_bf16(af[mi], bfr[ni], acc[mi][ni], 0, 0, 0);
            __syncthreads();
        }
    }

#pragma unroll
    for (int mi = 0; mi < 4; ++mi)
#pragma unroll
        for (int ni = 0; ni < 4; ++ni)
#pragma unroll
            for (int r = 0; r < 4; ++r) {
                int m = bm + wm + mi * 16 + fq * 4 + r;
                int n = bn + wn + ni * 16 + fr;
                float v = acc[mi][ni][r] + bias[n];
                if constexpr (EPI == 1) {
                    v = (v - bnm[n]) * rsqrtf(bnv[n] + LNEPS) * bng[n] + bnb[n];
                    v = gelu_f(v);
                }
                if constexpr (EPI == 3) v = gelu_f(v);
                co[(size_t)m * Nc + (n - noff)] = __float2bfloat16(v);
            }
}

// ---------------- narrow-N MFMA GEMM: 128M x 64N tile, BK=32, WB16-only ----------------
// 4 waves stacked in M (wave owns 32 rows x 64 cols: 2x4 frags, 8 MFMA/K-step). LDS 12 KB.
template<int EPI>
__global__ __launch_bounds__(256) void k_mg64(const bf16* __restrict__ A, const bf16* __restrict__ Wb,
                                              const float* __restrict__ bias, bf16* __restrict__ Cout,
                                              int Nc, int K,
                                              const float* __restrict__ bng, const float* __restrict__ bnb,
                                              const float* __restrict__ bnm, const float* __restrict__ bnv)
{
    __shared__ short As[128 * 32];
    __shared__ short Bs[64 * 32];
    int bm = blockIdx.y * 128, bn = blockIdx.x * 64;
    int tid = threadIdx.x;
    int lane = tid & 63, wave = tid >> 6;
    int wm = wave * 32;
    int fr = lane & 15, fq = lane >> 4;

    f32x4v acc[2][4];
#pragma unroll
    for (int i = 0; i < 2; ++i)
#pragma unroll
        for (int j = 0; j < 4; ++j) acc[i][j] = (f32x4v){0.f, 0.f, 0.f, 0.f};

    // staging: slot = tid; row = slot>>2, col = (slot&3)*8; round 1 of A adds 64 rows
    const bf16* ap0 = A  + (size_t)(bm + (tid >> 2)) * K + (tid & 3) * 8;
    const bf16* ap1 = ap0 + (size_t)64 * K;
    const bf16* bp  = Wb + (size_t)(bn + (tid >> 2)) * K + (tid & 3) * 8;
    short* as0 = &As[wave * 512];
    short* as1 = &As[2048 + wave * 512];
    short* bs0 = &Bs[wave * 512];

    for (int k0 = 0; k0 < K; k0 += 32) {
        gl_lds16(ap0 + k0, as0);
        gl_lds16(ap1 + k0, as1);
        gl_lds16(bp  + k0, bs0);
        __syncthreads();
        bf16x8v af[2], bfr[4];
#pragma unroll
        for (int mi = 0; mi < 2; ++mi) af[mi]  = *(bf16x8v*)&As[(wm + mi * 16 + fr) * 32 + fq * 8];
#pragma unroll
        for (int ni = 0; ni < 4; ++ni) bfr[ni] = *(bf16x8v*)&Bs[(ni * 16 + fr) * 32 + fq * 8];
#pragma unroll
        for (int mi = 0; mi < 2; ++mi)
#pragma unroll
            for (int ni = 0; ni < 4; ++ni)
                acc[mi][ni] = __builtin_amdgcn_mfma_f32_16x16x32_bf16(af[mi], bfr[ni], acc[mi][ni], 0, 0, 0);
        __syncthreads();
    }

#pragma unroll
    for (int mi = 0; mi < 2; ++mi)
#pragma unroll
        for (int ni = 0; ni < 4; ++ni)
#pragma unroll
            for (int r = 0; r < 4; ++r) {
                int m = bm + wm + mi * 16 + fq * 4 + r;
                int n = bn + ni * 16 + fr;
                float v = acc[mi][ni][r] + bias[n];
                if constexpr (EPI == 1) {
                    v = (v - bnm[n]) * rsqrtf(bnv[n] + LNEPS) * bng[n] + bnb[n];
                    v = gelu_f(v);
                }
                if constexpr (EPI == 3) v = gelu_f(v);
                Cout[(size_t)m * Nc + n] = __float2bfloat16(v);
            }
}

// ---------------- scalar dwconv (fallback only) ----------------
__global__ __launch_bounds__(256) void k_dwc(const bf16* __restrict__ H1c, bf16* __restrict__ H2c,
                                             const float* __restrict__ dww, const float* __restrict__ dwb,
                                             const float* __restrict__ g2, const float* __restrict__ b2,
                                             const float* __restrict__ m2, const float* __restrict__ v2,
                                             int ntok)
{
    size_t id = (size_t)blockIdx.x * 256 + threadIdx.x;
    if (id >= (size_t)ntok * HIDN) return;
    int k = (int)(id & 2047);
    int lm = (int)(id >> 11);
    int p = lm >> 8, hw = lm & 255, h = hw >> 4, w = hw & 15;
    float a = dwb[k];
#pragma unroll
    for (int dh = -1; dh <= 1; ++dh) {
        int h2 = h + dh;
        if (h2 < 0 || h2 > 15) continue;
#pragma unroll
        for (int dw = -1; dw <= 1; ++dw) {
            int w2 = w + dw;
            if (w2 < 0 || w2 > 15) continue;
            a += (float)H1c[(((size_t)p * 16 + h2) * 16 + w2) * HIDN + k]
               * dww[k * 9 + (dh + 1) * 3 + (dw + 1)];
        }
    }
    float xn = (a - m2[k]) * rsqrtf(v2[k] + LNEPS) * g2[k] + b2[k];
    H2c[id] = __float2bfloat16(gelu_f(xn));
}

// ---------------- vectorized dwconv3x3 + BN2 + GELU: 8 channels/thread ----------------
// grid = ntok blocks of 256 (thread covers channel group kg = (tid)*8 of one token).
__global__ __launch_bounds__(256) void k_dwcv(const bf16* __restrict__ H1c, bf16* __restrict__ H2c,
                                              const float* __restrict__ dwb,
                                              const float* __restrict__ dwt,
                                              const float* __restrict__ sc2, const float* __restrict__ sb2)
{
    int lm = blockIdx.x;
    int kg = threadIdx.x * 8;
    int hw = lm & 255, h = hw >> 4, w = hw & 15;
    int p = lm >> 8;

    float a[8];
    {
        float4 b0 = *(const float4*)&dwb[kg];
        float4 b1 = *(const float4*)&dwb[kg + 4];
        a[0] = b0.x; a[1] = b0.y; a[2] = b0.z; a[3] = b0.w;
        a[4] = b1.x; a[5] = b1.y; a[6] = b1.z; a[7] = b1.w;
    }
#pragma unroll
    for (int dh = -1; dh <= 1; ++dh) {
        int h2 = h + dh;
        if (h2 < 0 || h2 > 15) continue;
#pragma unroll
        for (int dw = -1; dw <= 1; ++dw) {
            int w2 = w + dw;
            if (w2 < 0 || w2 > 15) continue;
            bf16x8v xv = *(const bf16x8v*)&H1c[(((size_t)p * 16 + h2) * 16 + w2) * HIDN + kg];
            const float* wp = &dwt[((dh + 1) * 3 + (dw + 1)) * 2048 + kg];
            float4 w0 = *(const float4*)wp;
            float4 w1 = *(const float4*)(wp + 4);
            a[0] += bf2f(xv[0]) * w0.x; a[1] += bf2f(xv[1]) * w0.y;
            a[2] += bf2f(xv[2]) * w0.z; a[3] += bf2f(xv[3]) * w0.w;
            a[4] += bf2f(xv[4]) * w1.x; a[5] += bf2f(xv[5]) * w1.y;
            a[6] += bf2f(xv[6]) * w1.z; a[7] += bf2f(xv[7]) * w1.w;
        }
    }
    float4 s0 = *(const float4*)&sc2[kg];
    float4 s1 = *(const float4*)&sc2[kg + 4];
    float4 o0 = *(const float4*)&sb2[kg];
    float4 o1 = *(const float4*)&sb2[kg + 4];
    float sc[8] = {s0.x, s0.y, s0.z, s0.w, s1.x, s1.y, s1.z, s1.w};
    float sb[8] = {o0.x, o0.y, o0.z, o0.w, o1.x, o1.y, o1.z, o1.w};
    union { ushort us[8]; uint4 u; } pk;
#pragma unroll
    for (int j = 0; j < 8; ++j) {
        float xn = a[j] * sc[j] + sb[j];
        union { bf16 hh; ushort uu; } cv;
        cv.hh = __float2bfloat16(gelu_f(xn));
        pk.us[j] = cv.uu;
    }
    *(uint4*)&H2c[(size_t)lm * HIDN + kg] = pk.u;
}

// ---------------- temporal attention, L=S=10, d=64, one (b,h) per wave ----------------
__global__ __launch_bounds__(256) void k_tattn(const bf16* __restrict__ Q, const bf16* __restrict__ K,
                                               const bf16* __restrict__ V, bf16* __restrict__ O)
{
    __shared__ short sQ[4][10][72];
    __shared__ short sK[4][10][72];
    __shared__ short sV[4][10][72];
    int tid = threadIdx.x, wv = tid >> 6, l = tid & 63;
    int p = blockIdx.x * 4 + wv;
    int b = p >> 3, h = p & 7;
    const size_t base = (size_t)b * CC + h * 64;      // row r at base + r*2048*CC

    int cr = l >> 3, ccx = (l & 7) * 8;
#pragma unroll
    for (int i = 0; i < 2; ++i) {
        int r = cr + i * 8;
        if (r < 10) {
            size_t g = base + (size_t)r * 2048 * CC + ccx;
            *(uint4*)&sQ[wv][r][ccx] = *(const uint4*)&Q[g];
            *(uint4*)&sK[wv][r][ccx] = *(const uint4*)&K[g];
            *(uint4*)&sV[wv][r][ccx] = *(const uint4*)&V[g];
        }
    }
    __syncthreads();

    int slot = l & 15, quad = l >> 4;
#pragma unroll
    for (int qo = 0; qo < 3; ++qo) {
        int q = qo * 4 + quad;                        // 0..11
        int qc = q < 10 ? q : 0;
        float acc = 0.f;
        int sc = slot < 10 ? slot : 0;
#pragma unroll
        for (int dd = 0; dd < 8; ++dd) {
            bf16x8v qv = *(bf16x8v*)&sQ[wv][qc][dd * 8];
            bf16x8v kv = *(bf16x8v*)&sK[wv][sc][dd * 8];
#pragma unroll
            for (int j = 0; j < 8; ++j) acc += bf2f(qv[j]) * bf2f(kv[j]);
        }
        float S = (slot < 10 && q < 10) ? acc * ATTSCALE : -1e30f;
        float mx = S;
#pragma unroll
        for (int msk = 1; msk < 16; msk <<= 1) mx = fmaxf(mx, __shfl_xor(mx, msk));
        float e = (slot < 10 && q < 10) ? __expf(S - mx) : 0.f;
        float sum = e;
#pragma unroll
        for (int msk = 1; msk < 16; msk <<= 1) sum += __shfl_xor(sum, msk);
        float inv = 1.f / fmaxf(sum, 1e-20f);

        float o0 = 0.f, o1 = 0.f, o2 = 0.f, o3 = 0.f;
#pragma unroll
        for (int s = 0; s < 10; ++s) {
            float ps = __shfl(e, (l & 48) | s);
            uint2 vv = *(uint2*)&sV[wv][s][slot * 4];
            const short* vs = (const short*)&vv;
            o0 += ps * bf2f(vs[0]);
            o1 += ps * bf2f(vs[1]);
            o2 += ps * bf2f(vs[2]);
            o3 += ps * bf2f(vs[3]);
        }
        if (q < 10) {
            union { ushort us[4]; uint2 u; } pk;
            union { bf16 hh; ushort uu; } cv;
            cv.hh = __float2bfloat16(o0 * inv); pk.us[0] = cv.uu;
            cv.hh = __float2bfloat16(o1 * inv); pk.us[1] = cv.uu;
            cv.hh = __float2bfloat16(o2 * inv); pk.us[2] = cv.uu;
            cv.hh = __float2bfloat16(o3 * inv); pk.us[3] = cv.uu;
            *(uint2*)&O[base + (size_t)q * 2048 * CC + slot * 4] = pk.u;
        }
    }
}

// ---------------- MFMA flash attention, swapped-QK^T + defer-max ----------------
// grid.x = L/64 (q-tile), grid.y = Bc*NHEAD (b*8+h) -- consecutive blocks share K/V (L2 reuse).
__global__ __launch_bounds__(256) void k_fattn(const bf16* __restrict__ Q, const bf16* __restrict__ K,
                                               const bf16* __restrict__ V, bf16* __restrict__ O,
                                               int L, int S, int Bc)
{
    __shared__ short sK[64][72];        // [s][d] bf16, stride 72
    __shared__ short sVt[64 * 64];      // [d][s] bf16, swizzled
    __shared__ short sP[4][16][40];     // per-wave P bounce: [wave][q][s]

    int b = (int)blockIdx.y >> 3;
    int h = (int)blockIdx.y & 7;
    int q0 = blockIdx.x * 64;
    int tid = threadIdx.x;
    int wv = tid >> 6;
    int lane = tid & 63;
    int fr = lane & 15;
    int fq = lane >> 4;

    const bf16* qp = Q + ((size_t)(q0 + wv * 16 + fr) * Bc + b) * CC + h * 64 + fq * 8;
    bf16x8v qf0 = *(const bf16x8v*)qp;
    bf16x8v qf1 = *(const bf16x8v*)(qp + 32);

    f32x4v oacc[4];
#pragma unroll
    for (int i = 0; i < 4; ++i) oacc[i] = (f32x4v){0.f, 0.f, 0.f, 0.f};
    float m_run = -1e30f, l_run = 0.f;   // for q-row = fr (replicated over fq groups)

    int ks = tid >> 2, kd0 = (tid & 3) * 16;
    int vd0 = (tid & 7) * 8, vs2 = (tid >> 3) * 2;

    for (int s0 = 0; s0 < S; s0 += 64) {
        __syncthreads();
        {
            const bf16* kp = K + ((size_t)(s0 + ks) * Bc + b) * CC + h * 64 + kd0;
            *(uint4*)&sK[ks][kd0]     = *(const uint4*)kp;
            *(uint4*)&sK[ks][kd0 + 8] = *(const uint4*)(kp + 8);
        }
        {
            const bf16* vp0 = V + ((size_t)(s0 + vs2) * Bc + b) * CC + h * 64 + vd0;
            const bf16* vp1 = vp0 + (size_t)Bc * CC;
            uint4 va = *(const uint4*)vp0;
            uint4 vb = *(const uint4*)vp1;
            const ushort* as = (const ushort*)&va;
            const ushort* bs = (const ushort*)&vb;
#pragma unroll
            for (int j = 0; j < 8; ++j) {
                int dd = vd0 + j;
                int sw = vs2 ^ (((( dd >> 3) ^ (dd & 7)) & 7) << 3);
                *(u32*)&sVt[dd * 64 + sw] = (u32)as[j] | ((u32)bs[j] << 16);
            }
        }
        __syncthreads();

        // QK^T swapped: sc[nt][r] = S_raw[s = nt*16+fq*4+r][q = fr]
        f32x4v sc[4];
#pragma unroll
        for (int nt = 0; nt < 4; ++nt) {
            bf16x8v k0 = *(bf16x8v*)&sK[nt * 16 + fr][fq * 8];
            bf16x8v k1 = *(bf16x8v*)&sK[nt * 16 + fr][32 + fq * 8];
            f32x4v z = (f32x4v){0.f, 0.f, 0.f, 0.f};
            z = __builtin_amdgcn_mfma_f32_16x16x32_bf16(k0, qf0, z, 0, 0, 0);
            z = __builtin_amdgcn_mfma_f32_16x16x32_bf16(k1, qf1, z, 0, 0, 0);
            sc[nt] = z;
        }

        // row max (q = fr): in-register + 2 shuffles across fq groups
        float pm = sc[0][0];
#pragma unroll
        for (int nt = 0; nt < 4; ++nt)
#pragma unroll
            for (int r = 0; r < 4; ++r) pm = fmaxf(pm, sc[nt][r]);
        pm *= ATTSCALE;
        pm = fmaxf(pm, __shfl_xor(pm, 16));
        pm = fmaxf(pm, __shfl_xor(pm, 32));

        if (__any(pm > m_run + 8.f)) {            // defer-max: rescale only on real growth
            float mnew = fmaxf(m_run, pm);
            float alpha = __expf(m_run - mnew);
            m_run = mnew;
            l_run *= alpha;
            float al0 = __shfl(alpha, (lane & 48) | (fq * 4 + 0));
            float al1 = __shfl(alpha, (lane & 48) | (fq * 4 + 1));
            float al2 = __shfl(alpha, (lane & 48) | (fq * 4 + 2));
            float al3 = __shfl(alpha, (lane & 48) | (fq * 4 + 3));
#pragma unroll
            for (int nt2 = 0; nt2 < 4; ++nt2) {
                oacc[nt2][0] *= al0; oacc[nt2][1] *= al1;
                oacc[nt2][2] *= al2; oacc[nt2][3] *= al3;
            }
        }

        short (*sPw)[40] = sP[wv];
        float rs = 0.f;
#pragma unroll
        for (int nt = 0; nt < 4; ++nt) {
#pragma unroll
            for (int rp = 0; rp < 2; ++rp) {
                float p0 = __expf(sc[nt][2 * rp]     * ATTSCALE - m_run);
                float p1 = __expf(sc[nt][2 * rp + 1] * ATTSCALE - m_run);
                union { bf16 hh; ushort uu; } c0, c1;
                c0.hh = __float2bfloat16(p0);
                c1.hh = __float2bfloat16(p1);
                *(u32*)&sPw[fr][nt * 16 + fq * 4 + 2 * rp] = (u32)c0.uu | ((u32)c1.uu << 16);
                rs += bf2f((short)c0.uu) + bf2f((short)c1.uu);   // denom matches bf16 P
            }
        }
        rs += __shfl_xor(rs, 16);
        rs += __shfl_xor(rs, 32);
        l_run += rs;
        __syncthreads();

        // PV: A = P[q][s], B' = V^T[d][s] -> oacc: row q = fq*4+r, col d = nt2*16+fr
        bf16x8v pa0 = *(bf16x8v*)&sPw[fr][fq * 8];
        bf16x8v pa1 = *(bf16x8v*)&sPw[fr][32 + fq * 8];
#pragma unroll
        for (int nt2 = 0; nt2 < 4; ++nt2) {
            int vr = nt2 * 16 + fr;
            int vx = (((vr >> 3) ^ (vr & 7)) & 7) << 3;
            bf16x8v v0 = *(bf16x8v*)&sVt[vr * 64 + ((fq * 8) ^ vx)];
            bf16x8v v1 = *(bf16x8v*)&sVt[vr * 64 + ((32 + fq * 8) ^ vx)];
            oacc[nt2] = __builtin_amdgcn_mfma_f32_16x16x32_bf16(pa0, v0, oacc[nt2], 0, 0, 0);
            oacc[nt2] = __builtin_amdgcn_mfma_f32_16x16x32_bf16(pa1, v1, oacc[nt2], 0, 0, 0);
        }
    }

    // epilogue: lane holds q = fq*4+r rows; l_run lives in lane (group)|q
    float linv[4];
#pragma unroll
    for (int r = 0; r < 4; ++r)
        linv[r] = __shfl(l_run, (lane & 48) | (fq * 4 + r));
#pragma unroll
    for (int r = 0; r < 4; ++r) {
        float inv = 1.f / fmaxf(linv[r], 1e-20f);
        bf16* op = O + ((size_t)(q0 + wv * 16 + fq * 4 + r) * Bc + b) * CC + h * 64 + fr;
#pragma unroll
        for (int nt2 = 0; nt2 < 4; ++nt2)
            op[nt2 * 16] = __float2bfloat16(oacc[nt2][r] * inv);
    }
}

// ---------------- host-side GEMM dispatcher ----------------
static void launch_gemm(int epi, bool wb16, dim3 grid,
                        const bf16* A, const float* Wf, const bf16* Wb,
                        const float* bias, bf16* C, bf16* C2, int nsplit, int Nc, int K,
                        const float* g, const float* b, const float* m, const float* v,
                        hipStream_t s)
{
    dim3 blk(256);
    if (wb16) {
        switch (epi) {
        case 0: k_mgemm<0, true><<<grid, blk, 0, s>>>(A, Wf, Wb, bias, C, C2, nsplit, Nc, K, g, b, m, v); break;
        case 1: k_mgemm<1, true><<<grid, blk, 0, s>>>(A, Wf, Wb, bias, C, C2, nsplit, Nc, K, g, b, m, v); break;
        default: k_mgemm<3, true><<<grid, blk, 0, s>>>(A, Wf, Wb, bias, C, C2, nsplit, Nc, K, g, b, m, v); break;
        }
    } else {
        switch (epi) {
        case 0: k_mgemm<0, false><<<grid, blk, 0, s>>>(A, Wf, Wb, bias, C, C2, nsplit, Nc, K, g, b, m, v); break;
        case 1: k_mgemm<1, false><<<grid, blk, 0, s>>>(A, Wf, Wb, bias, C, C2, nsplit, Nc, K, g, b, m, v); break;
        default: k_mgemm<3, false><<<grid, blk, 0, s>>>(A, Wf, Wb, bias, C, C2, nsplit, Nc, K, g, b, m, v); break;
        }
    }
}

extern "C" void kernel_launch(void* const* d_in, const int* in_sizes, int n_in,
                              void* d_out, int out_size, void* d_ws, size_t ws_size,
                              hipStream_t stream)
{
    const float* query        = (const float*)d_in[0];
    const float* memory       = (const float*)d_in[1];
    const float* pos_local    = (const float*)d_in[2];
    const float* pos_temporal = (const float*)d_in[3];
    const float* pos_ts       = (const float*)d_in[4];
    const float* ln_g[5] = {(const float*)d_in[5], (const float*)d_in[7], (const float*)d_in[9], (const float*)d_in[11], (const float*)d_in[13]};
    const float* ln_b[5] = {(const float*)d_in[6], (const float*)d_in[8], (const float*)d_in[10], (const float*)d_in[12], (const float*)d_in[14]};
    const float* sa_w_in  = (const float*)d_in[15]; const float* sa_b_in  = (const float*)d_in[16];
    const float* sa_w_out = (const float*)d_in[17]; const float* sa_b_out = (const float*)d_in[18];
    const float* ta_w_in  = (const float*)d_in[19]; const float* ta_b_in  = (const float*)d_in[20];
    const float* ta_w_out = (const float*)d_in[21]; const float* ta_b_out = (const float*)d_in[22];
    const float* ca_w_in  = (const float*)d_in[23]; const float* ca_b_in  = (const float*)d_in[24];
    const float* ca_w_out = (const float*)d_in[25]; const float* ca_b_out = (const float*)d_in[26];
    const float* fc1_w = (const float*)d_in[27]; const float* fc1_b = (const float*)d_in[28];
    const float* dw_w  = (const float*)d_in[29]; const float* dw_b  = (const float*)d_in[30];
    const float* fc2_w = (const float*)d_in[31]; const float* fc2_b = (const float*)d_in[32];
    const float* bn1g = (const float*)d_in[33], *bn1b = (const float*)d_in[34], *bn1m = (const float*)d_in[35], *bn1v = (const float*)d_in[36];
    const float* bn2g = (const float*)d_in[37], *bn2b = (const float*)d_in[38], *bn2m = (const float*)d_in[39], *bn2v = (const float*)d_in[40];
    const float* bn3g = (const float*)d_in[41], *bn3b = (const float*)d_in[42], *bn3m = (const float*)d_in[43], *bn3v = (const float*)d_in[44];
    const float* lin1_w = (const float*)d_in[45]; const float* lin1_b = (const float*)d_in[46];
    const float* lin2_w = (const float*)d_in[47]; const float* lin2_b = (const float*)d_in[48];

    dim3 blk(256);
    int gMC = (int)(MC / 256);

    size_t off_wb  = MC * 4 + 4 * MC * 2;
    size_t off_dwt = off_wb + WTOT * 2;
    size_t off_h   = off_dwt + 90112;            // dwt 72K + sc2 8K + sb2 8K (+pad)
    size_t need_small = off_wb;
    size_t need_big   = off_h;
    size_t need_tB    = off_h + (size_t)2 * 10240 * HIDN * 2;
    size_t need_tA    = off_h + (size_t)2 * MTOK  * HIDN * 2;
    if (ws_size < need_small) {
        k_fill<<<gMC, blk, 0, stream>>>((float*)d_out, 700.f, MC);
        return;
    }
    bool wb16 = (ws_size >= need_big);
    int  CH   = (ws_size >= need_tA) ? MTOK : ((ws_size >= need_tB) ? 10240 : 5120);

    float* X = (float*)d_ws;
    bf16* B0 = (bf16*)((char*)d_ws + MC * 4);
    bf16* B1 = B0 + MC;
    bf16* B2 = B1 + MC;
    bf16* B3 = B2 + MC;
    bf16* WB = (bf16*)((char*)d_ws + off_wb);
    float* DWT = (float*)((char*)d_ws + off_dwt);
    float* SC2 = DWT + 18432;
    float* SB2 = SC2 + 2048;
    bf16* H1 = (bf16*)((char*)d_ws + off_h);
    bf16* H2 = H1 + (size_t)CH * HIDN;
    const float* nulf = nullptr;
    bf16* nulm = nullptr;

    // bf16 weight views (valid only when wb16)
    bf16* wb_sa_in  = WB + 0;
    bf16* wb_sa_out = WB + 786432;
    bf16* wb_ta_in  = WB + 1048576;
    bf16* wb_ta_out = WB + 1835008;
    bf16* wb_ca_in  = WB + 2097152;
    bf16* wb_ca_out = WB + 2883584;
    bf16* wb_fc1    = WB + 3145728;
    bf16* wb_fc2    = WB + 4194304;
    bf16* wb_lin1   = WB + 5242880;
    bf16* wb_lin2   = WB + 6291456;

    if (wb16) {
        k_cvtw<<<(int)((WTOT + 255) / 256), blk, 0, stream>>>(WB,
            sa_w_in, sa_w_out, ta_w_in, ta_w_out, ca_w_in, ca_w_out,
            fc1_w, fc2_w, lin1_w, lin2_w);
        k_dwprep<<<8, blk, 0, stream>>>(dw_w, bn2g, bn2b, bn2m, bn2v, DWT, SC2, SB2);
    }

    // ---- stage 1: spatial window MHSA (L=S=64, Bc=320) ----
    k_ln2<<<MTOK, 64, 0, stream>>>(X, query, B0, B1, ln_g[0], ln_b[0], pos_local, 0, 1, nulm, 0);
    launch_gemm(0, wb16, dim3(8, 160), B1, sa_w_in, wb_sa_in, sa_b_in, B2, B3, 512, 512, 512, nulf, nulf, nulf, nulf, stream);
    launch_gemm(0, wb16, dim3(4, 160), B0, sa_w_in + 524288, wb_sa_in + 524288, sa_b_in + 1024, B1, nulm, 0, 512, 512, nulf, nulf, nulf, nulf, stream);
    k_fattn<<<dim3(1, 320 * NHEAD), blk, 0, stream>>>(B2, B3, B1, B0, 64, 64, 320);
    launch_gemm(0, wb16, dim3(4, 160), B0, sa_w_out, wb_sa_out, sa_b_out, B2, nulm, 0, 512, 512, nulf, nulf, nulf, nulf, stream);

    // ---- stage 2: MlpDWBN (residual of stage 1 fused into LN; X = query + resid) ----
    k_ln2<<<MTOK, 64, 0, stream>>>(X, query, B0, nulm, ln_g[1], ln_b[1], nulf, 0, 0, B2, 1);
    if (wb16) {
        int NCH = MTOK / CH;
        for (int c = 0; c < NCH; ++c) {
            int off = c * CH;
            launch_gemm(1, true, dim3(16, CH / 128), B0 + (size_t)off * CC, fc1_w, wb_fc1, fc1_b, H1, nulm, 0, 2048, 512,
                        bn1g, bn1b, bn1m, bn1v, stream);
            k_dwcv<<<CH, blk, 0, stream>>>(H1, H2, dw_b, DWT, SC2, SB2);
            k_mg64<1><<<dim3(8, CH / 128), blk, 0, stream>>>(H2, wb_fc2, fc2_b, B2 + (size_t)off * CC, 512, 2048,
                                                             bn3g, bn3b, bn3m, bn3v);
        }
    } else {
        for (int c = 0; c < 4; ++c) {
            int off = c * 5120;
            launch_gemm(1, false, dim3(16, 40), B0 + (size_t)off * CC, fc1_w, wb_fc1, fc1_b, B1, nulm, 0, 2048, 512,
                        bn1g, bn1b, bn1m, bn1v, stream);
            k_dwc<<<40960, blk, 0, stream>>>(B1, B3, fc1_w /*unused*/, dw_b, bn2g, bn2b, bn2m, bn2v, 5120);
            launch_gemm(1, false, dim3(4, 40), B3, fc2_w, wb_fc2, fc2_b, B2 + (size_t)off * CC, nulm, 0, 512, 2048,
                        bn3g, bn3b, bn3m, bn3v, stream);
        }
    }

    // ---- stage 3: temporal MHSA (T=10; stage-2 residual fused into LN) ----
    k_ln2<<<MTOK, 64, 0, stream>>>(X, X, B0, B1, ln_g[2], ln_b[2], pos_temporal, 0, 3, B2, 0);
    launch_gemm(0, wb16, dim3(8, 160), B1, ta_w_in, wb_ta_in, ta_b_in, B2, B3, 512, 512, 512, nulf, nulf, nulf, nulf, stream);
    launch_gemm(0, wb16, dim3(4, 160), B0, ta_w_in + 524288, wb_ta_in + 524288, ta_b_in + 1024, B1, nulm, 0, 512, 512, nulf, nulf, nulf, nulf, stream);
    k_tattn<<<4096, blk, 0, stream>>>(B2, B3, B1, B0);
    launch_gemm(0, wb16, dim3(4, 160), B0, ta_w_out, wb_ta_out, ta_b_out, B2, nulm, 0, 512, 512, nulf, nulf, nulf, nulf, stream);

    // ---- stage 4: temporal-spatial cross-attention (stage-3 residual fused into LN) ----
    k_ln2<<<MTOK, 64, 0, stream>>>(X, X, nulm, B1, ln_g[3], ln_b[3], pos_ts, 640, 4, B2, 3);
    launch_gemm(0, wb16, dim3(4, 160), B1, ca_w_in, wb_ca_in, ca_b_in, B2, nulm, 0, 512, 512, nulf, nulf, nulf, nulf, stream);
    if (wb16) {
        k_permmem<<<gMC, blk, 0, stream>>>(memory, B1, H1, pos_ts, 0);
        launch_gemm(0, true, dim3(4, 160), B1, ca_w_in + 262144, wb_ca_in + 262144, ca_b_in + 512, B3, nulm, 0, 512, 512, nulf, nulf, nulf, nulf, stream);
        launch_gemm(0, true, dim3(4, 160), H1, ca_w_in + 524288, wb_ca_in + 524288, ca_b_in + 1024, B0, nulm, 0, 512, 512, nulf, nulf, nulf, nulf, stream);
    } else {
        k_permmem<<<gMC, blk, 0, stream>>>(memory, B1, nulm, pos_ts, 0);
        launch_gemm(0, false, dim3(4, 160), B1, ca_w_in + 262144, wb_ca_in + 262144, ca_b_in + 512, B3, nulm, 0, 512, 512, nulf, nulf, nulf, nulf, stream);
        k_permmem<<<gMC, blk, 0, stream>>>(memory, B1, nulm, nulf, 0);
        launch_gemm(0, false, dim3(4, 160), B1, ca_w_in + 524288, wb_ca_in + 524288, ca_b_in + 1024, B0, nulm, 0, 512, 512, nulf, nulf, nulf, nulf, stream);
    }
    k_fattn<<<dim3(10, 32 * NHEAD), blk, 0, stream>>>(B2, B3, B0, B1, 640, 640, 32);
    launch_gemm(0, wb16, dim3(4, 160), B1, ca_w_out, wb_ca_out, ca_b_out, B2, nulm, 0, 512, 512, nulf, nulf, nulf, nulf, stream);

    // ---- stage 5: final FFN (stage-4 residual fused into LN) ----
    k_ln2<<<MTOK, 64, 0, stream>>>(X, X, B0, nulm, ln_g[4], ln_b[4], nulf, 0, 0, B2, 4);
    if (wb16) {
        int NCH = MTOK / CH;
        for (int c = 0; c < NCH; ++c) {
            int off = c * CH;
            launch_gemm(3, true, dim3(16, CH / 128), B0 + (size_t)off * CC, lin1_w, wb_lin1, lin1_b, H1, nulm, 0, 2048, 512,
                        nulf, nulf, nulf, nulf, stream);
            k_mg64<0><<<dim3(8, CH / 128), blk, 0, stream>>>(H1, wb_lin2, lin2_b, B2 + (size_t)off * CC, 512, 2048,
                                                             nulf, nulf, nulf, nulf);
        }
    } else {
        for (int c = 0; c < 4; ++c) {
            int off = c * 5120;
            launch_gemm(3, false, dim3(16, 40), B0 + (size_t)off * CC, lin1_w, wb_lin1, lin1_b, B1, nulm, 0, 2048, 512,
                        nulf, nulf, nulf, nulf, stream);
            launch_gemm(0, false, dim3(4, 40), B1, lin2_w, wb_lin2, lin2_b, B2 + (size_t)off * CC, nulm, 0, 512, 2048,
                        nulf, nulf, nulf, nulf, stream);
        }
    }
    k_final<<<gMC, blk, 0, stream>>>(X, B2, (float*)d_out, MC);
}

// Round 7
// 1340.923 us; speedup vs baseline: 3.9738x; 1.0332x over previous
//
#include <hip/hip_runtime.h>
#include <hip/hip_bf16.h>
#include <math.h>

typedef __hip_bfloat16 bf16;
typedef unsigned int u32;
typedef __attribute__((ext_vector_type(8))) short bf16x8v;
typedef __attribute__((ext_vector_type(4))) float f32x4v;

static constexpr int NB = 8, TT = 10, HH = 16, WW = 16, CC = 512;
static constexpr int NHEAD = 8, HIDN = 2048;
static constexpr int MTOK = NB * TT * HH * WW;          // 20480 tokens
static constexpr size_t MC = (size_t)MTOK * CC;         // 10485760
static constexpr float LNEPS = 1e-5f;
static constexpr float ATTSCALE = 0.125f;               // 1/sqrt(64)
static constexpr size_t WTOT = 7340032;                 // total weight elems pre-converted to bf16

static __device__ __forceinline__ float gelu_f(float x) {
    return 0.5f * x * (1.0f + erff(x * 0.70710678118654752f));
}

static __device__ __forceinline__ float bf2f(short s) {
    union { u32 u; float f; } c; c.u = ((u32)(unsigned short)s) << 16; return c.f;
}

// direct global->LDS async copy, 16B per lane; LDS dest = wave-uniform base + lane*16
static __device__ __forceinline__ void gl_lds16(const void* g, void* l)
{
    __builtin_amdgcn_global_load_lds((const __attribute__((address_space(1))) u32*)g,
                                     (__attribute__((address_space(3))) u32*)l, 16, 0, 0);
}

// end-of-phase fence: per-wave drain of in-flight global_load_lds, then block barrier.
// Raw s_barrier (no compiler vmcnt(0) mega-drain); sched_barrier pins ordering (rule #18).
static __device__ __forceinline__ void phase_fence()
{
    asm volatile("s_waitcnt vmcnt(0)" ::: "memory");
    __builtin_amdgcn_s_barrier();
    __builtin_amdgcn_sched_barrier(0);
}

// token index m -> permuted row (and pos-row pr) for each layout mode
static __device__ __forceinline__ int perm_row(int m, int mode, int* pr)
{
    if (mode == 1) {
        int nt = m >> 8, hw = m & 255, h = hw >> 4, w = hw & 15;
        int l = (h & 7) * 8 + (w & 7);
        *pr = l;
        return l * 320 + nt * 4 + (h >> 3) * 2 + (w >> 3);
    } else if (mode == 3) {
        int n = m / 2560, rem = m - n * 2560;
        int t = rem >> 8;
        *pr = t;
        return t * 2048 + n * 256 + (rem & 255);
    } else if (mode == 4) {
        int n = m / 2560, rem = m - n * 2560;
        int t = rem >> 8, hw = rem & 255, h = hw >> 4, w = hw & 15;
        int ij = (h & 7) * 8 + (w & 7);
        *pr = t * 64 + ij;
        return (t * 64 + ij) * 32 + n * 4 + (h >> 3) * 2 + (w >> 3);
    }
    *pr = 0;
    return m;
}

// ---------------- ws-too-small diagnostic ----------------
__global__ __launch_bounds__(256) void k_fill(float* __restrict__ out, float v, size_t n)
{
    size_t i = (size_t)blockIdx.x * 256 + threadIdx.x;
    if (i < n) out[i] = v;
}

// ---------------- one-shot fp32 -> bf16 weight conversion (28 segments of 262144) ----------------
__global__ __launch_bounds__(256) void k_cvtw(bf16* __restrict__ out,
    const float* __restrict__ p0, const float* __restrict__ p1, const float* __restrict__ p2,
    const float* __restrict__ p3, const float* __restrict__ p4, const float* __restrict__ p5,
    const float* __restrict__ p6, const float* __restrict__ p7, const float* __restrict__ p8,
    const float* __restrict__ p9)
{
    size_t id = (size_t)blockIdx.x * 256 + threadIdx.x;
    if (id >= WTOT) return;
    int sid = (int)(id >> 18);                 // /262144
    const float* base; size_t lo;
    if (sid < 3)       { base = p0; lo = id; }
    else if (sid < 4)  { base = p1; lo = id - (size_t)3  * 262144; }
    else if (sid < 7)  { base = p2; lo = id - (size_t)4  * 262144; }
    else if (sid < 8)  { base = p3; lo = id - (size_t)7  * 262144; }
    else if (sid < 11) { base = p4; lo = id - (size_t)8  * 262144; }
    else if (sid < 12) { base = p5; lo = id - (size_t)11 * 262144; }
    else if (sid < 16) { base = p6; lo = id - (size_t)12 * 262144; }
    else if (sid < 20) { base = p7; lo = id - (size_t)16 * 262144; }
    else if (sid < 24) { base = p8; lo = id - (size_t)20 * 262144; }
    else               { base = p9; lo = id - (size_t)24 * 262144; }
    out[id] = __float2bfloat16(base[lo]);
}

// ---------------- dwconv prep: transpose weights to [9][2048] fp32; fold BN2 ----------------
__global__ __launch_bounds__(256) void k_dwprep(const float* __restrict__ dww,
    const float* __restrict__ g2, const float* __restrict__ b2,
    const float* __restrict__ m2, const float* __restrict__ v2,
    float* __restrict__ dwt, float* __restrict__ sc2, float* __restrict__ sb2)
{
    int k = blockIdx.x * 256 + threadIdx.x;       // 0..2047
#pragma unroll
    for (int t = 0; t < 9; ++t) dwt[t * 2048 + k] = dww[k * 9 + t];
    float sc = g2[k] * rsqrtf(v2[k] + LNEPS);
    sc2[k] = sc;
    sb2[k] = b2[k] - m2[k] * sc;
}

// ---------------- fused [residual-add +] LayerNorm (+permute, +pos); reads Xin, dst bf16 ----------------
// resid (optional, bf16, permuted layout rmode): X[m] = Xin[m] + unperm(resid) (written back to X).
__global__ __launch_bounds__(64) void k_ln2(float* __restrict__ X, const float* __restrict__ Xin,
                                            bf16* __restrict__ dstA, bf16* __restrict__ dstB,
                                            const float* __restrict__ g, const float* __restrict__ b,
                                            const float* __restrict__ pos, int posoff, int mode,
                                            const bf16* __restrict__ resid, int rmode)
{
    int m = blockIdx.x;
    int lane = threadIdx.x;
    const float* row = Xin + (size_t)m * CC;
    float v[8], s = 0.f, s2 = 0.f;
    if (resid) {
        int du;
        int rr = perm_row(m, rmode, &du);
        const bf16* rp = resid + (size_t)rr * CC;
        float* xo = X + (size_t)m * CC;
#pragma unroll
        for (int i = 0; i < 8; ++i) {
            int c = lane + i * 64;
            float y = row[c] + (float)rp[c];
            xo[c] = y;
            v[i] = y; s += y; s2 += y * y;
        }
    } else {
#pragma unroll
        for (int i = 0; i < 8; ++i) { int c = lane + i * 64; v[i] = row[c]; s += v[i]; s2 += v[i] * v[i]; }
    }
#pragma unroll
    for (int msk = 1; msk < 64; msk <<= 1) { s += __shfl_xor(s, msk); s2 += __shfl_xor(s2, msk); }
    float mean = s * (1.f / 512.f);
    float var  = fmaxf(s2 * (1.f / 512.f) - mean * mean, 0.f);
    float rr2 = rsqrtf(var + LNEPS);

    int pr;
    int r = perm_row(m, mode, &pr);
#pragma unroll
    for (int i = 0; i < 8; ++i) {
        int c = lane + i * 64;
        float y = (v[i] - mean) * rr2 * g[c] + b[c];
        if (dstA) dstA[(size_t)r * CC + c] = __float2bfloat16(y);
        if (dstB) dstB[(size_t)r * CC + c] = __float2bfloat16(y + pos[(size_t)(posoff + pr) * CC + c]);
    }
}

// ---------------- gather-permute of fp32 `memory` into ts layout; out=(+pos), out2=plain ----------------
__global__ __launch_bounds__(256) void k_permmem(const float* __restrict__ in, bf16* __restrict__ out,
                                                 bf16* __restrict__ out2,
                                                 const float* __restrict__ pos, int posoff)
{
    size_t id = (size_t)blockIdx.x * 256 + threadIdx.x;
    if (id >= MC) return;
    int c = (int)(id & 511);
    int r = (int)(id >> 9);
    int b = r & 31, s = r >> 5;
    int t = s >> 6, ij = s & 63;
    int i = ij >> 3, j = ij & 7;
    int n = b >> 2, qh = (b >> 1) & 1, qw = b & 1;
    int m = (n * 10 + t) * 256 + (qh * 8 + i) * 16 + qw * 8 + j;
    float v = in[(size_t)m * CC + c];
    if (out2) out2[id] = __float2bfloat16(v);
    if (pos) v += pos[(size_t)(posoff + t * 64 + ij) * CC + c];
    out[id] = __float2bfloat16(v);
}

// ---------------- final residual add: FLOAT32 output ----------------
__global__ __launch_bounds__(256) void k_final(const float* __restrict__ X, const bf16* __restrict__ F,
                                               float* __restrict__ out, size_t n)
{
    size_t i = (size_t)blockIdx.x * 256 + threadIdx.x;
    if (i < n) out[i] = X[i] + (float)F[i];
}

// ---------------- MFMA GEMM: C = A(bf16, M x K) @ W(Nc_w x K)^T + bias; out bf16 ----------------
// 128x128 tile, BK=32, 4 waves each computing a 64x64 quadrant via 16 x mfma_f32_16x16x32_bf16.
// WB16=true: bf16 weights via global_load_lds; DOUBLE-BUFFERED 2-phase K-loop (one barrier/step,
//   next tile's loads overlap current tile's ds_read+MFMA; vmcnt(0)+raw s_barrier fence).
// WB16=false: fp32 weights, register staging + in-loop convert, padded [128][40] LDS (2 barriers).
// EPI 0: bias.  1: bias+BN+GELU.  3: bias+GELU.
// Split output: if nsplit>0, blocks with bn>=nsplit write to Cout2 at col n-nsplit (stride Nc).
template<int EPI, bool WB16>
__global__ __launch_bounds__(256) void k_mgemm(const bf16* __restrict__ A, const float* __restrict__ Wf,
                                               const bf16* __restrict__ Wb,
                                               const float* __restrict__ bias, bf16* __restrict__ Cout,
                                               bf16* __restrict__ Cout2, int nsplit,
                                               int Nc, int K,
                                               const float* __restrict__ bng, const float* __restrict__ bnb,
                                               const float* __restrict__ bnm, const float* __restrict__ bnv)
{
    __shared__ short smem[WB16 ? 2 * 8192 : 2 * 128 * 40];

    int bm = blockIdx.y * 128, bn = blockIdx.x * 128;
    int tid = threadIdx.x;
    int lane = tid & 63, wave = tid >> 6;
    int wm = (wave & 1) * 64, wn = (wave >> 1) * 64;
    int fr = lane & 15;      // frag row (A) / col (B,D)
    int fq = lane >> 4;      // quad: k-offset fq*8 (A,B), row-offset fq*4 (D)

    bf16* co = Cout; int noff = 0;
    if (nsplit > 0 && bn >= nsplit) { co = Cout2; noff = nsplit; }

    f32x4v acc[4][4];
#pragma unroll
    for (int i = 0; i < 4; ++i)
#pragma unroll
        for (int j = 0; j < 4; ++j) acc[i][j] = (f32x4v){0.f, 0.f, 0.f, 0.f};

    if constexpr (WB16) {
        // buffer layout: [buf][As 4096 | Bs 4096] shorts. Wave w stages rows w*32..w*32+31.
        int srow = wave * 32 + (lane >> 2);
        int scol = (lane & 3) * 8;
        const bf16* aptr = A  + (size_t)(bm + srow) * K + scol;
        const bf16* bptr = Wb + (size_t)(bn + srow) * K + scol;
        const size_t row16 = (size_t)16 * K;
        const int wl = wave * 1024;

        // prologue: stage tile 0
        {
            short* base = &smem[0];
            gl_lds16(aptr, base + wl);
            gl_lds16(aptr + row16, base + wl + 512);
            gl_lds16(bptr, base + 4096 + wl);
            gl_lds16(bptr + row16, base + 4096 + wl + 512);
        }
        phase_fence();
        int cur = 0;
        for (int k0 = 0; k0 < K; k0 += 32) {
            if (k0 + 32 < K) {          // issue next-tile loads into other buffer
                short* base = &smem[(cur ^ 1) * 8192];
                gl_lds16(aptr + k0 + 32,         base + wl);
                gl_lds16(aptr + row16 + k0 + 32, base + wl + 512);
                gl_lds16(bptr + k0 + 32,         base + 4096 + wl);
                gl_lds16(bptr + row16 + k0 + 32, base + 4096 + wl + 512);
            }
            const short* As = &smem[cur * 8192];
            const short* Bs = As + 4096;
            bf16x8v af[4], bfr[4];
#pragma unroll
            for (int mi = 0; mi < 4; ++mi) af[mi]  = *(const bf16x8v*)&As[(wm + mi * 16 + fr) * 32 + fq * 8];
#pragma unroll
            for (int ni = 0; ni < 4; ++ni) bfr[ni] = *(const bf16x8v*)&Bs[(wn + ni * 16 + fr) * 32 + fq * 8];
#pragma unroll
            for (int mi = 0; mi < 4; ++mi)
#pragma unroll
                for (int ni = 0; ni < 4; ++ni)
                    acc[mi][ni] = __builtin_amdgcn_mfma_f32_16x16x32_bf16(af[mi], bfr[ni], acc[mi][ni], 0, 0, 0);
            phase_fence();              // next tile landed (all waves); reads of cur done
            cur ^= 1;
        }
    } else {
        constexpr int LDW = 40;
        short* As = smem;
        short* Bs = smem + 128 * LDW;
        for (int k0 = 0; k0 < K; k0 += 32) {
#pragma unroll
            for (int i = 0; i < 2; ++i) {
                int v = tid * 2 + i;                 // 0..511
                int m = v >> 2, kk = (v & 3) * 8;
                *(uint4*)&As[m * LDW + kk] = *(const uint4*)&A[(size_t)(bm + m) * K + k0 + kk];
                float4 w0 = *(const float4*)&Wf[(size_t)(bn + m) * K + k0 + kk];
                float4 w1 = *(const float4*)&Wf[(size_t)(bn + m) * K + k0 + kk + 4];
                union { bf16 h[8]; uint4 u; } t;
                t.h[0] = __float2bfloat16(w0.x); t.h[1] = __float2bfloat16(w0.y);
                t.h[2] = __float2bfloat16(w0.z); t.h[3] = __float2bfloat16(w0.w);
                t.h[4] = __float2bfloat16(w1.x); t.h[5] = __float2bfloat16(w1.y);
                t.h[6] = __float2bfloat16(w1.z); t.h[7] = __float2bfloat16(w1.w);
                *(uint4*)&Bs[m * LDW + kk] = t.u;
            }
            __syncthreads();
            bf16x8v af[4], bfr[4];
#pragma unroll
            for (int mi = 0; mi < 4; ++mi) af[mi]  = *(bf16x8v*)&As[(wm + mi * 16 + fr) * LDW + fq * 8];
#pragma unroll
            for (int ni = 0; ni < 4; ++ni) bfr[ni] = *(bf16x8v*)&Bs[(wn + ni * 16 + fr) * LDW + fq * 8];
#pragma unroll
            for (int mi = 0; mi < 4; ++mi)
#pragma unroll
                for (int ni = 0; ni < 4; ++ni)
                    acc[mi][ni] = __builtin_amdgcn_mfma_f32_16x16x32_bf16(af[mi], bfr[ni], acc[mi][ni], 0, 0, 0);
            __syncthreads();
        }
    }

#pragma unroll
    for (int mi = 0; mi < 4; ++mi)
#pragma unroll
        for (int ni = 0; ni < 4; ++ni)
#pragma unroll
            for (int r = 0; r < 4; ++r) {
                int m = bm + wm + mi * 16 + fq * 4 + r;
                int n = bn + wn + ni * 16 + fr;
                float v = acc[mi][ni][r] + bias[n];
                if constexpr (EPI == 1) {
                    v = (v - bnm[n]) * rsqrtf(bnv[n] + LNEPS) * bng[n] + bnb[n];
                    v = gelu_f(v);
                }
                if constexpr (EPI == 3) v = gelu_f(v);
                co[(size_t)m * Nc + (n - noff)] = __float2bfloat16(v);
            }
}

// ---------------- narrow-N MFMA GEMM: 128M x 64N tile, BK=32, WB16-only, double-buffered ----------------
// 4 waves stacked in M (wave owns 32 rows x 64 cols: 2x4 frags, 8 MFMA/K-step). LDS 24 KB.
template<int EPI>
__global__ __launch_bounds__(256) void k_mg64(const bf16* __restrict__ A, const bf16* __restrict__ Wb,
                                              const float* __restrict__ bias, bf16* __restrict__ Cout,
                                              int Nc, int K,
                                              const float* __restrict__ bng, const float* __restrict__ bnb,
                                              const float* __restrict__ bnm, const float* __restrict__ bnv)
{
    __shared__ short smem[2 * 6144];    // [buf][As 4096 | Bs 2048]
    int bm = blockIdx.y * 128, bn = blockIdx.x * 64;
    int tid = threadIdx.x;
    int lane = tid & 63, wave = tid >> 6;
    int wm = wave * 32;
    int fr = lane & 15, fq = lane >> 4;

    f32x4v acc[2][4];
#pragma unroll
    for (int i = 0; i < 2; ++i)
#pragma unroll
        for (int j = 0; j < 4; ++j) acc[i][j] = (f32x4v){0.f, 0.f, 0.f, 0.f};

    const bf16* ap0 = A  + (size_t)(bm + (tid >> 2)) * K + (tid & 3) * 8;
    const bf16* ap1 = ap0 + (size_t)64 * K;
    const bf16* bp  = Wb + (size_t)(bn + (tid >> 2)) * K + (tid & 3) * 8;
    const int wl = wave * 512;

    {
        short* base = &smem[0];
        gl_lds16(ap0, base + wl);
        gl_lds16(ap1, base + 2048 + wl);
        gl_lds16(bp,  base + 4096 + wl);
    }
    phase_fence();
    int cur = 0;
    for (int k0 = 0; k0 < K; k0 += 32) {
        if (k0 + 32 < K) {
            short* base = &smem[(cur ^ 1) * 6144];
            gl_lds16(ap0 + k0 + 32, base + wl);
            gl_lds16(ap1 + k0 + 32, base + 2048 + wl);
            gl_lds16(bp  + k0 + 32, base + 4096 + wl);
        }
        const short* As = &smem[cur * 6144];
        const short* Bs = As + 4096;
        bf16x8v af[2], bfr[4];
#pragma unroll
        for (int mi = 0; mi < 2; ++mi) af[mi]  = *(const bf16x8v*)&As[(wm + mi * 16 + fr) * 32 + fq * 8];
#pragma unroll
        for (int ni = 0; ni < 4; ++ni) bfr[ni] = *(const bf16x8v*)&Bs[(ni * 16 + fr) * 32 + fq * 8];
#pragma unroll
        for (int mi = 0; mi < 2; ++mi)
#pragma unroll
            for (int ni = 0; ni < 4; ++ni)
                acc[mi][ni] = __builtin_amdgcn_mfma_f32_16x16x32_bf16(af[mi], bfr[ni], acc[mi][ni], 0, 0, 0);
        phase_fence();
        cur ^= 1;
    }

#pragma unroll
    for (int mi = 0; mi < 2; ++mi)
#pragma unroll
        for (int ni = 0; ni < 4; ++ni)
#pragma unroll
            for (int r = 0; r < 4; ++r) {
                int m = bm + wm + mi * 16 + fq * 4 + r;
                int n = bn + ni * 16 + fr;
                float v = acc[mi][ni][r] + bias[n];
                if constexpr (EPI == 1) {
                    v = (v - bnm[n]) * rsqrtf(bnv[n] + LNEPS) * bng[n] + bnb[n];
                    v = gelu_f(v);
                }
                if constexpr (EPI == 3) v = gelu_f(v);
                Cout[(size_t)m * Nc + n] = __float2bfloat16(v);
            }
}

// ---------------- scalar dwconv (fallback only) ----------------
__global__ __launch_bounds__(256) void k_dwc(const bf16* __restrict__ H1c, bf16* __restrict__ H2c,
                                             const float* __restrict__ dww, const float* __restrict__ dwb,
                                             const float* __restrict__ g2, const float* __restrict__ b2,
                                             const float* __restrict__ m2, const float* __restrict__ v2,
                                             int ntok)
{
    size_t id = (size_t)blockIdx.x * 256 + threadIdx.x;
    if (id >= (size_t)ntok * HIDN) return;
    int k = (int)(id & 2047);
    int lm = (int)(id >> 11);
    int p = lm >> 8, hw = lm & 255, h = hw >> 4, w = hw & 15;
    float a = dwb[k];
#pragma unroll
    for (int dh = -1; dh <= 1; ++dh) {
        int h2 = h + dh;
        if (h2 < 0 || h2 > 15) continue;
#pragma unroll
        for (int dw = -1; dw <= 1; ++dw) {
            int w2 = w + dw;
            if (w2 < 0 || w2 > 15) continue;
            a += (float)H1c[(((size_t)p * 16 + h2) * 16 + w2) * HIDN + k]
               * dww[k * 9 + (dh + 1) * 3 + (dw + 1)];
        }
    }
    float xn = (a - m2[k]) * rsqrtf(v2[k] + LNEPS) * g2[k] + b2[k];
    H2c[id] = __float2bfloat16(gelu_f(xn));
}

// ---------------- vectorized dwconv3x3 + BN2 + GELU: 8 channels/thread ----------------
__global__ __launch_bounds__(256) void k_dwcv(const bf16* __restrict__ H1c, bf16* __restrict__ H2c,
                                              const float* __restrict__ dwb,
                                              const float* __restrict__ dwt,
                                              const float* __restrict__ sc2, const float* __restrict__ sb2)
{
    int lm = blockIdx.x;
    int kg = threadIdx.x * 8;
    int hw = lm & 255, h = hw >> 4, w = hw & 15;
    int p = lm >> 8;

    float a[8];
    {
        float4 b0 = *(const float4*)&dwb[kg];
        float4 b1 = *(const float4*)&dwb[kg + 4];
        a[0] = b0.x; a[1] = b0.y; a[2] = b0.z; a[3] = b0.w;
        a[4] = b1.x; a[5] = b1.y; a[6] = b1.z; a[7] = b1.w;
    }
#pragma unroll
    for (int dh = -1; dh <= 1; ++dh) {
        int h2 = h + dh;
        if (h2 < 0 || h2 > 15) continue;
#pragma unroll
        for (int dw = -1; dw <= 1; ++dw) {
            int w2 = w + dw;
            if (w2 < 0 || w2 > 15) continue;
            bf16x8v xv = *(const bf16x8v*)&H1c[(((size_t)p * 16 + h2) * 16 + w2) * HIDN + kg];
            const float* wp = &dwt[((dh + 1) * 3 + (dw + 1)) * 2048 + kg];
            float4 w0 = *(const float4*)wp;
            float4 w1 = *(const float4*)(wp + 4);
            a[0] += bf2f(xv[0]) * w0.x; a[1] += bf2f(xv[1]) * w0.y;
            a[2] += bf2f(xv[2]) * w0.z; a[3] += bf2f(xv[3]) * w0.w;
            a[4] += bf2f(xv[4]) * w1.x; a[5] += bf2f(xv[5]) * w1.y;
            a[6] += bf2f(xv[6]) * w1.z; a[7] += bf2f(xv[7]) * w1.w;
        }
    }
    float4 s0 = *(const float4*)&sc2[kg];
    float4 s1 = *(const float4*)&sc2[kg + 4];
    float4 o0 = *(const float4*)&sb2[kg];
    float4 o1 = *(const float4*)&sb2[kg + 4];
    float sc[8] = {s0.x, s0.y, s0.z, s0.w, s1.x, s1.y, s1.z, s1.w};
    float sb[8] = {o0.x, o0.y, o0.z, o0.w, o1.x, o1.y, o1.z, o1.w};
    union { ushort us[8]; uint4 u; } pk;
#pragma unroll
    for (int j = 0; j < 8; ++j) {
        float xn = a[j] * sc[j] + sb[j];
        union { bf16 hh; ushort uu; } cv;
        cv.hh = __float2bfloat16(gelu_f(xn));
        pk.us[j] = cv.uu;
    }
    *(uint4*)&H2c[(size_t)lm * HIDN + kg] = pk.u;
}

// ---------------- temporal attention, L=S=10, d=64, one (b,h) per wave ----------------
__global__ __launch_bounds__(256) void k_tattn(const bf16* __restrict__ Q, const bf16* __restrict__ K,
                                               const bf16* __restrict__ V, bf16* __restrict__ O)
{
    __shared__ short sQ[4][10][72];
    __shared__ short sK[4][10][72];
    __shared__ short sV[4][10][72];
    int tid = threadIdx.x, wv = tid >> 6, l = tid & 63;
    int p = blockIdx.x * 4 + wv;
    int b = p >> 3, h = p & 7;
    const size_t base = (size_t)b * CC + h * 64;      // row r at base + r*2048*CC

    int cr = l >> 3, ccx = (l & 7) * 8;
#pragma unroll
    for (int i = 0; i < 2; ++i) {
        int r = cr + i * 8;
        if (r < 10) {
            size_t g = base + (size_t)r * 2048 * CC + ccx;
            *(uint4*)&sQ[wv][r][ccx] = *(const uint4*)&Q[g];
            *(uint4*)&sK[wv][r][ccx] = *(const uint4*)&K[g];
            *(uint4*)&sV[wv][r][ccx] = *(const uint4*)&V[g];
        }
    }
    __syncthreads();

    int slot = l & 15, quad = l >> 4;
#pragma unroll
    for (int qo = 0; qo < 3; ++qo) {
        int q = qo * 4 + quad;                        // 0..11
        int qc = q < 10 ? q : 0;
        float acc = 0.f;
        int sc = slot < 10 ? slot : 0;
#pragma unroll
        for (int dd = 0; dd < 8; ++dd) {
            bf16x8v qv = *(bf16x8v*)&sQ[wv][qc][dd * 8];
            bf16x8v kv = *(bf16x8v*)&sK[wv][sc][dd * 8];
#pragma unroll
            for (int j = 0; j < 8; ++j) acc += bf2f(qv[j]) * bf2f(kv[j]);
        }
        float S = (slot < 10 && q < 10) ? acc * ATTSCALE : -1e30f;
        float mx = S;
#pragma unroll
        for (int msk = 1; msk < 16; msk <<= 1) mx = fmaxf(mx, __shfl_xor(mx, msk));
        float e = (slot < 10 && q < 10) ? __expf(S - mx) : 0.f;
        float sum = e;
#pragma unroll
        for (int msk = 1; msk < 16; msk <<= 1) sum += __shfl_xor(sum, msk);
        float inv = 1.f / fmaxf(sum, 1e-20f);

        float o0 = 0.f, o1 = 0.f, o2 = 0.f, o3 = 0.f;
#pragma unroll
        for (int s = 0; s < 10; ++s) {
            float ps = __shfl(e, (l & 48) | s);
            uint2 vv = *(uint2*)&sV[wv][s][slot * 4];
            const short* vs = (const short*)&vv;
            o0 += ps * bf2f(vs[0]);
            o1 += ps * bf2f(vs[1]);
            o2 += ps * bf2f(vs[2]);
            o3 += ps * bf2f(vs[3]);
        }
        if (q < 10) {
            union { ushort us[4]; uint2 u; } pk;
            union { bf16 hh; ushort uu; } cv;
            cv.hh = __float2bfloat16(o0 * inv); pk.us[0] = cv.uu;
            cv.hh = __float2bfloat16(o1 * inv); pk.us[1] = cv.uu;
            cv.hh = __float2bfloat16(o2 * inv); pk.us[2] = cv.uu;
            cv.hh = __float2bfloat16(o3 * inv); pk.us[3] = cv.uu;
            *(uint2*)&O[base + (size_t)q * 2048 * CC + slot * 4] = pk.u;
        }
    }
}

// ---------------- MFMA flash attention, swapped-QK^T + defer-max ----------------
// grid.x = L/64 (q-tile), grid.y = Bc*NHEAD (b*8+h) -- consecutive blocks share K/V (L2 reuse).
__global__ __launch_bounds__(256) void k_fattn(const bf16* __restrict__ Q, const bf16* __restrict__ K,
                                               const bf16* __restrict__ V, bf16* __restrict__ O,
                                               int L, int S, int Bc)
{
    __shared__ short sK[64][72];        // [s][d] bf16, stride 72
    __shared__ short sVt[64 * 64];      // [d][s] bf16, swizzled
    __shared__ short sP[4][16][40];     // per-wave P bounce: [wave][q][s]

    int b = (int)blockIdx.y >> 3;
    int h = (int)blockIdx.y & 7;
    int q0 = blockIdx.x * 64;
    int tid = threadIdx.x;
    int wv = tid >> 6;
    int lane = tid & 63;
    int fr = lane & 15;
    int fq = lane >> 4;

    const bf16* qp = Q + ((size_t)(q0 + wv * 16 + fr) * Bc + b) * CC + h * 64 + fq * 8;
    bf16x8v qf0 = *(const bf16x8v*)qp;
    bf16x8v qf1 = *(const bf16x8v*)(qp + 32);

    f32x4v oacc[4];
#pragma unroll
    for (int i = 0; i < 4; ++i) oacc[i] = (f32x4v){0.f, 0.f, 0.f, 0.f};
    float m_run = -1e30f, l_run = 0.f;   // for q-row = fr (replicated over fq groups)

    int ks = tid >> 2, kd0 = (tid & 3) * 16;
    int vd0 = (tid & 7) * 8, vs2 = (tid >> 3) * 2;

    for (int s0 = 0; s0 < S; s0 += 64) {
        __syncthreads();
        {
            const bf16* kp = K + ((size_t)(s0 + ks) * Bc + b) * CC + h * 64 + kd0;
            *(uint4*)&sK[ks][kd0]     = *(const uint4*)kp;
            *(uint4*)&sK[ks][kd0 + 8] = *(const uint4*)(kp + 8);
        }
        {
            const bf16* vp0 = V + ((size_t)(s0 + vs2) * Bc + b) * CC + h * 64 + vd0;
            const bf16* vp1 = vp0 + (size_t)Bc * CC;
            uint4 va = *(const uint4*)vp0;
            uint4 vb = *(const uint4*)vp1;
            const ushort* as = (const ushort*)&va;
            const ushort* bs = (const ushort*)&vb;
#pragma unroll
            for (int j = 0; j < 8; ++j) {
                int dd = vd0 + j;
                int sw = vs2 ^ (((( dd >> 3) ^ (dd & 7)) & 7) << 3);
                *(u32*)&sVt[dd * 64 + sw] = (u32)as[j] | ((u32)bs[j] << 16);
            }
        }
        __syncthreads();

        // QK^T swapped: sc[nt][r] = S_raw[s = nt*16+fq*4+r][q = fr]
        f32x4v sc[4];
#pragma unroll
        for (int nt = 0; nt < 4; ++nt) {
            bf16x8v k0 = *(bf16x8v*)&sK[nt * 16 + fr][fq * 8];
            bf16x8v k1 = *(bf16x8v*)&sK[nt * 16 + fr][32 + fq * 8];
            f32x4v z = (f32x4v){0.f, 0.f, 0.f, 0.f};
            z = __builtin_amdgcn_mfma_f32_16x16x32_bf16(k0, qf0, z, 0, 0, 0);
            z = __builtin_amdgcn_mfma_f32_16x16x32_bf16(k1, qf1, z, 0, 0, 0);
            sc[nt] = z;
        }

        // row max (q = fr): in-register + 2 shuffles across fq groups
        float pm = sc[0][0];
#pragma unroll
        for (int nt = 0; nt < 4; ++nt)
#pragma unroll
            for (int r = 0; r < 4; ++r) pm = fmaxf(pm, sc[nt][r]);
        pm *= ATTSCALE;
        pm = fmaxf(pm, __shfl_xor(pm, 16));
        pm = fmaxf(pm, __shfl_xor(pm, 32));

        if (__any(pm > m_run + 8.f)) {            // defer-max: rescale only on real growth
            float mnew = fmaxf(m_run, pm);
            float alpha = __expf(m_run - mnew);
            m_run = mnew;
            l_run *= alpha;
            float al0 = __shfl(alpha, (lane & 48) | (fq * 4 + 0));
            float al1 = __shfl(alpha, (lane & 48) | (fq * 4 + 1));
            float al2 = __shfl(alpha, (lane & 48) | (fq * 4 + 2));
            float al3 = __shfl(alpha, (lane & 48) | (fq * 4 + 3));
#pragma unroll
            for (int nt2 = 0; nt2 < 4; ++nt2) {
                oacc[nt2][0] *= al0; oacc[nt2][1] *= al1;
                oacc[nt2][2] *= al2; oacc[nt2][3] *= al3;
            }
        }

        short (*sPw)[40] = sP[wv];
        float rs = 0.f;
#pragma unroll
        for (int nt = 0; nt < 4; ++nt) {
#pragma unroll
            for (int rp = 0; rp < 2; ++rp) {
                float p0 = __expf(sc[nt][2 * rp]     * ATTSCALE - m_run);
                float p1 = __expf(sc[nt][2 * rp + 1] * ATTSCALE - m_run);
                union { bf16 hh; ushort uu; } c0, c1;
                c0.hh = __float2bfloat16(p0);
                c1.hh = __float2bfloat16(p1);
                *(u32*)&sPw[fr][nt * 16 + fq * 4 + 2 * rp] = (u32)c0.uu | ((u32)c1.uu << 16);
                rs += bf2f((short)c0.uu) + bf2f((short)c1.uu);   // denom matches bf16 P
            }
        }
        rs += __shfl_xor(rs, 16);
        rs += __shfl_xor(rs, 32);
        l_run += rs;
        __syncthreads();

        // PV: A = P[q][s], B' = V^T[d][s] -> oacc: row q = fq*4+r, col d = nt2*16+fr
        bf16x8v pa0 = *(bf16x8v*)&sPw[fr][fq * 8];
        bf16x8v pa1 = *(bf16x8v*)&sPw[fr][32 + fq * 8];
#pragma unroll
        for (int nt2 = 0; nt2 < 4; ++nt2) {
            int vr = nt2 * 16 + fr;
            int vx = (((vr >> 3) ^ (vr & 7)) & 7) << 3;
            bf16x8v v0 = *(bf16x8v*)&sVt[vr * 64 + ((fq * 8) ^ vx)];
            bf16x8v v1 = *(bf16x8v*)&sVt[vr * 64 + ((32 + fq * 8) ^ vx)];
            oacc[nt2] = __builtin_amdgcn_mfma_f32_16x16x32_bf16(pa0, v0, oacc[nt2], 0, 0, 0);
            oacc[nt2] = __builtin_amdgcn_mfma_f32_16x16x32_bf16(pa1, v1, oacc[nt2], 0, 0, 0);
        }
    }

    // epilogue: lane holds q = fq*4+r rows; l_run lives in lane (group)|q
    float linv[4];
#pragma unroll
    for (int r = 0; r < 4; ++r)
        linv[r] = __shfl(l_run, (lane & 48) | (fq * 4 + r));
#pragma unroll
    for (int r = 0; r < 4; ++r) {
        float inv = 1.f / fmaxf(linv[r], 1e-20f);
        bf16* op = O + ((size_t)(q0 + wv * 16 + fq * 4 + r) * Bc + b) * CC + h * 64 + fr;
#pragma unroll
        for (int nt2 = 0; nt2 < 4; ++nt2)
            op[nt2 * 16] = __float2bfloat16(oacc[nt2][r] * inv);
    }
}

// ---------------- host-side GEMM dispatcher ----------------
static void launch_gemm(int epi, bool wb16, dim3 grid,
                        const bf16* A, const float* Wf, const bf16* Wb,
                        const float* bias, bf16* C, bf16* C2, int nsplit, int Nc, int K,
                        const float* g, const float* b, const float* m, const float* v,
                        hipStream_t s)
{
    dim3 blk(256);
    if (wb16) {
        switch (epi) {
        case 0: k_mgemm<0, true><<<grid, blk, 0, s>>>(A, Wf, Wb, bias, C, C2, nsplit, Nc, K, g, b, m, v); break;
        case 1: k_mgemm<1, true><<<grid, blk, 0, s>>>(A, Wf, Wb, bias, C, C2, nsplit, Nc, K, g, b, m, v); break;
        default: k_mgemm<3, true><<<grid, blk, 0, s>>>(A, Wf, Wb, bias, C, C2, nsplit, Nc, K, g, b, m, v); break;
        }
    } else {
        switch (epi) {
        case 0: k_mgemm<0, false><<<grid, blk, 0, s>>>(A, Wf, Wb, bias, C, C2, nsplit, Nc, K, g, b, m, v); break;
        case 1: k_mgemm<1, false><<<grid, blk, 0, s>>>(A, Wf, Wb, bias, C, C2, nsplit, Nc, K, g, b, m, v); break;
        default: k_mgemm<3, false><<<grid, blk, 0, s>>>(A, Wf, Wb, bias, C, C2, nsplit, Nc, K, g, b, m, v); break;
        }
    }
}

extern "C" void kernel_launch(void* const* d_in, const int* in_sizes, int n_in,
                              void* d_out, int out_size, void* d_ws, size_t ws_size,
                              hipStream_t stream)
{
    const float* query        = (const float*)d_in[0];
    const float* memory       = (const float*)d_in[1];
    const float* pos_local    = (const float*)d_in[2];
    const float* pos_temporal = (const float*)d_in[3];
    const float* pos_ts       = (const float*)d_in[4];
    const float* ln_g[5] = {(const float*)d_in[5], (const float*)d_in[7], (const float*)d_in[9], (const float*)d_in[11], (const float*)d_in[13]};
    const float* ln_b[5] = {(const float*)d_in[6], (const float*)d_in[8], (const float*)d_in[10], (const float*)d_in[12], (const float*)d_in[14]};
    const float* sa_w_in  = (const float*)d_in[15]; const float* sa_b_in  = (const float*)d_in[16];
    const float* sa_w_out = (const float*)d_in[17]; const float* sa_b_out = (const float*)d_in[18];
    const float* ta_w_in  = (const float*)d_in[19]; const float* ta_b_in  = (const float*)d_in[20];
    const float* ta_w_out = (const float*)d_in[21]; const float* ta_b_out = (const float*)d_in[22];
    const float* ca_w_in  = (const float*)d_in[23]; const float* ca_b_in  = (const float*)d_in[24];
    const float* ca_w_out = (const float*)d_in[25]; const float* ca_b_out = (const float*)d_in[26];
    const float* fc1_w = (const float*)d_in[27]; const float* fc1_b = (const float*)d_in[28];
    const float* dw_w  = (const float*)d_in[29]; const float* dw_b  = (const float*)d_in[30];
    const float* fc2_w = (const float*)d_in[31]; const float* fc2_b = (const float*)d_in[32];
    const float* bn1g = (const float*)d_in[33], *bn1b = (const float*)d_in[34], *bn1m = (const float*)d_in[35], *bn1v = (const float*)d_in[36];
    const float* bn2g = (const float*)d_in[37], *bn2b = (const float*)d_in[38], *bn2m = (const float*)d_in[39], *bn2v = (const float*)d_in[40];
    const float* bn3g = (const float*)d_in[41], *bn3b = (const float*)d_in[42], *bn3m = (const float*)d_in[43], *bn3v = (const float*)d_in[44];
    const float* lin1_w = (const float*)d_in[45]; const float* lin1_b = (const float*)d_in[46];
    const float* lin2_w = (const float*)d_in[47]; const float* lin2_b = (const float*)d_in[48];

    dim3 blk(256);
    int gMC = (int)(MC / 256);

    size_t off_wb  = MC * 4 + 4 * MC * 2;
    size_t off_dwt = off_wb + WTOT * 2;
    size_t off_h   = off_dwt + 90112;            // dwt 72K + sc2 8K + sb2 8K (+pad)
    size_t need_small = off_wb;
    size_t need_big   = off_h;
    size_t need_tB    = off_h + (size_t)2 * 10240 * HIDN * 2;
    size_t need_tA    = off_h + (size_t)2 * MTOK  * HIDN * 2;
    if (ws_size < need_small) {
        k_fill<<<gMC, blk, 0, stream>>>((float*)d_out, 700.f, MC);
        return;
    }
    bool wb16 = (ws_size >= need_big);
    int  CH   = (ws_size >= need_tA) ? MTOK : ((ws_size >= need_tB) ? 10240 : 5120);

    float* X = (float*)d_ws;
    bf16* B0 = (bf16*)((char*)d_ws + MC * 4);
    bf16* B1 = B0 + MC;
    bf16* B2 = B1 + MC;
    bf16* B3 = B2 + MC;
    bf16* WB = (bf16*)((char*)d_ws + off_wb);
    float* DWT = (float*)((char*)d_ws + off_dwt);
    float* SC2 = DWT + 18432;
    float* SB2 = SC2 + 2048;
    bf16* H1 = (bf16*)((char*)d_ws + off_h);
    bf16* H2 = H1 + (size_t)CH * HIDN;
    const float* nulf = nullptr;
    bf16* nulm = nullptr;

    // bf16 weight views (valid only when wb16)
    bf16* wb_sa_in  = WB + 0;
    bf16* wb_sa_out = WB + 786432;
    bf16* wb_ta_in  = WB + 1048576;
    bf16* wb_ta_out = WB + 1835008;
    bf16* wb_ca_in  = WB + 2097152;
    bf16* wb_ca_out = WB + 2883584;
    bf16* wb_fc1    = WB + 3145728;
    bf16* wb_fc2    = WB + 4194304;
    bf16* wb_lin1   = WB + 5242880;
    bf16* wb_lin2   = WB + 6291456;

    if (wb16) {
        k_cvtw<<<(int)((WTOT + 255) / 256), blk, 0, stream>>>(WB,
            sa_w_in, sa_w_out, ta_w_in, ta_w_out, ca_w_in, ca_w_out,
            fc1_w, fc2_w, lin1_w, lin2_w);
        k_dwprep<<<8, blk, 0, stream>>>(dw_w, bn2g, bn2b, bn2m, bn2v, DWT, SC2, SB2);
    }

    // ---- stage 1: spatial window MHSA (L=S=64, Bc=320) ----
    k_ln2<<<MTOK, 64, 0, stream>>>(X, query, B0, B1, ln_g[0], ln_b[0], pos_local, 0, 1, nulm, 0);
    launch_gemm(0, wb16, dim3(8, 160), B1, sa_w_in, wb_sa_in, sa_b_in, B2, B3, 512, 512, 512, nulf, nulf, nulf, nulf, stream);
    launch_gemm(0, wb16, dim3(4, 160), B0, sa_w_in + 524288, wb_sa_in + 524288, sa_b_in + 1024, B1, nulm, 0, 512, 512, nulf, nulf, nulf, nulf, stream);
    k_fattn<<<dim3(1, 320 * NHEAD), blk, 0, stream>>>(B2, B3, B1, B0, 64, 64, 320);
    launch_gemm(0, wb16, dim3(4, 160), B0, sa_w_out, wb_sa_out, sa_b_out, B2, nulm, 0, 512, 512, nulf, nulf, nulf, nulf, stream);

    // ---- stage 2: MlpDWBN (residual of stage 1 fused into LN; X = query + resid) ----
    k_ln2<<<MTOK, 64, 0, stream>>>(X, query, B0, nulm, ln_g[1], ln_b[1], nulf, 0, 0, B2, 1);
    if (wb16) {
        int NCH = MTOK / CH;
        for (int c = 0; c < NCH; ++c) {
            int off = c * CH;
            launch_gemm(1, true, dim3(16, CH / 128), B0 + (size_t)off * CC, fc1_w, wb_fc1, fc1_b, H1, nulm, 0, 2048, 512,
                        bn1g, bn1b, bn1m, bn1v, stream);
            k_dwcv<<<CH, blk, 0, stream>>>(H1, H2, dw_b, DWT, SC2, SB2);
            k_mg64<1><<<dim3(8, CH / 128), blk, 0, stream>>>(H2, wb_fc2, fc2_b, B2 + (size_t)off * CC, 512, 2048,
                                                             bn3g, bn3b, bn3m, bn3v);
        }
    } else {
        for (int c = 0; c < 4; ++c) {
            int off = c * 5120;
            launch_gemm(1, false, dim3(16, 40), B0 + (size_t)off * CC, fc1_w, wb_fc1, fc1_b, B1, nulm, 0, 2048, 512,
                        bn1g, bn1b, bn1m, bn1v, stream);
            k_dwc<<<40960, blk, 0, stream>>>(B1, B3, dw_w, dw_b, bn2g, bn2b, bn2m, bn2v, 5120);
            launch_gemm(1, false, dim3(4, 40), B3, fc2_w, wb_fc2, fc2_b, B2 + (size_t)off * CC, nulm, 0, 512, 2048,
                        bn3g, bn3b, bn3m, bn3v, stream);
        }
    }

    // ---- stage 3: temporal MHSA (T=10; stage-2 residual fused into LN) ----
    k_ln2<<<MTOK, 64, 0, stream>>>(X, X, B0, B1, ln_g[2], ln_b[2], pos_temporal, 0, 3, B2, 0);
    launch_gemm(0, wb16, dim3(8, 160), B1, ta_w_in, wb_ta_in, ta_b_in, B2, B3, 512, 512, 512, nulf, nulf, nulf, nulf, stream);
    launch_gemm(0, wb16, dim3(4, 160), B0, ta_w_in + 524288, wb_ta_in + 524288, ta_b_in + 1024, B1, nulm, 0, 512, 512, nulf, nulf, nulf, nulf, stream);
    k_tattn<<<4096, blk, 0, stream>>>(B2, B3, B1, B0);
    launch_gemm(0, wb16, dim3(4, 160), B0, ta_w_out, wb_ta_out, ta_b_out, B2, nulm, 0, 512, 512, nulf, nulf, nulf, nulf, stream);

    // ---- stage 4: temporal-spatial cross-attention (stage-3 residual fused into LN) ----
    k_ln2<<<MTOK, 64, 0, stream>>>(X, X, nulm, B1, ln_g[3], ln_b[3], pos_ts, 640, 4, B2, 3);
    launch_gemm(0, wb16, dim3(4, 160), B1, ca_w_in, wb_ca_in, ca_b_in, B2, nulm, 0, 512, 512, nulf, nulf, nulf, nulf, stream);
    if (wb16) {
        k_permmem<<<gMC, blk, 0, stream>>>(memory, B1, H1, pos_ts, 0);
        launch_gemm(0, true, dim3(4, 160), B1, ca_w_in + 262144, wb_ca_in + 262144, ca_b_in + 512, B3, nulm, 0, 512, 512, nulf, nulf, nulf, nulf, stream);
        launch_gemm(0, true, dim3(4, 160), H1, ca_w_in + 524288, wb_ca_in + 524288, ca_b_in + 1024, B0, nulm, 0, 512, 512, nulf, nulf, nulf, nulf, stream);
    } else {
        k_permmem<<<gMC, blk, 0, stream>>>(memory, B1, nulm, pos_ts, 0);
        launch_gemm(0, false, dim3(4, 160), B1, ca_w_in + 262144, wb_ca_in + 262144, ca_b_in + 512, B3, nulm, 0, 512, 512, nulf, nulf, nulf, nulf, stream);
        k_permmem<<<gMC, blk, 0, stream>>>(memory, B1, nulm, nulf, 0);
        launch_gemm(0, false, dim3(4, 160), B1, ca_w_in + 524288, wb_ca_in + 524288, ca_b_in + 1024, B0, nulm, 0, 512, 512, nulf, nulf, nulf, nulf, stream);
    }
    k_fattn<<<dim3(10, 32 * NHEAD), blk, 0, stream>>>(B2, B3, B0, B1, 640, 640, 32);
    launch_gemm(0, wb16, dim3(4, 160), B1, ca_w_out, wb_ca_out, ca_b_out, B2, nulm, 0, 512, 512, nulf, nulf, nulf, nulf, stream);

    // ---- stage 5: final FFN (stage-4 residual fused into LN) ----
    k_ln2<<<MTOK, 64, 0, stream>>>(X, X, B0, nulm, ln_g[4], ln_b[4], nulf, 0, 0, B2, 4);
    if (wb16) {
        int NCH = MTOK / CH;
        for (int c = 0; c < NCH; ++c) {
            int off = c * CH;
            launch_gemm(3, true, dim3(16, CH / 128), B0 + (size_t)off * CC, lin1_w, wb_lin1, lin1_b, H1, nulm, 0, 2048, 512,
                        nulf, nulf, nulf, nulf, stream);
            k_mg64<0><<<dim3(8, CH / 128), blk, 0, stream>>>(H1, wb_lin2, lin2_b, B2 + (size_t)off * CC, 512, 2048,
                                                             nulf, nulf, nulf, nulf);
        }
    } else {
        for (int c = 0; c < 4; ++c) {
            int off = c * 5120;
            launch_gemm(3, false, dim3(16, 40), B0 + (size_t)off * CC, lin1_w, wb_lin1, lin1_b, B1, nulm, 0, 2048, 512,
                        nulf, nulf, nulf, nulf, stream);
            launch_gemm(0, false, dim3(4, 40), B1, lin2_w, wb_lin2, lin2_b, B2 + (size_t)off * CC, nulm, 0, 512, 2048,
                        nulf, nulf, nulf, nulf, stream);
        }
    }
    k_final<<<gMC, blk, 0, stream>>>(X, B2, (float*)d_out, MC);
}